// Round 21
// baseline (1679.216 us; speedup 1.0000x reference)
//
#include <hip/hip_runtime.h>
#include <cstddef>
#include <cstdint>

#define TPB 256

typedef unsigned int u32;
typedef unsigned short u16;
typedef __bf16 bf16x8 __attribute__((ext_vector_type(8)));
typedef float f32x4 __attribute__((ext_vector_type(4)));

__device__ __forceinline__ float act_rt(float v, int a) {
  if (a == 1) return v >= 0.f ? v : 0.1f * v;
  if (a == 2) return 1.f / (1.f + expf(-v));
  return v;
}

__device__ __forceinline__ u16 f2bf(float f) {
  __bf16 h = (__bf16)f;
  return __builtin_bit_cast(u16, h);
}
__device__ __forceinline__ float bf2f(u16 h) {
  return __uint_as_float(((u32)h) << 16);
}
__device__ __forceinline__ u32 pk2bf(float a, float b) {
  return (u32)f2bf(a) | ((u32)f2bf(b) << 16);
}

// ---------------------------------------------------------------------------
// Weight prep (one launch, 22 convs)
// ---------------------------------------------------------------------------
struct WPrepArgs {
  const float* src[22];
  u16* dst[22];
  int cin[22], cout[22], coutpad[22], total[22];
};

__global__ void k_wprep_all(WPrepArgs a)
{
  const int seg = blockIdx.y;
  const int idx = blockIdx.x * TPB + threadIdx.x;
  if (idx >= a.total[seg]) return;
  const int Cin = a.cin[seg], Cout = a.cout[seg], Coutpad = a.coutpad[seg];
  int kk = idx % 40; int t = idx / 40;
  int co = t % Coutpad; t /= Coutpad;
  int tap = t % 9; int kc = t / 9;
  u16 v = 0;
  if (kk < 32 && co < Cout)
    v = f2bf(a.src[seg][((size_t)co * Cin + kc * 32 + kk) * 9 + tap]);
  a.dst[seg][idx] = v;
}

// ---------------------------------------------------------------------------
// Input prep
// ---------------------------------------------------------------------------
struct ToBfArgs {
  const float* src[9];
  u16* dst[9];
  int hw[9];
};

__global__ void k_tobf_all(ToBfArgs a)
{
  const int seg = blockIdx.y;
  const int hw = a.hw[seg];
  const int total = 2 * hw * 8;
  int idx = blockIdx.x * TPB + threadIdx.x;
  if (idx >= total) return;
  const int g8 = idx & 7;
  int t = idx >> 3;
  const int pos = t % hw, b = t / hw;
  const float* s = a.src[seg] + ((size_t)b * 64 + g8 * 8) * hw + pos;
  u32 w0 = pk2bf(s[0], s[(size_t)hw]);
  u32 w1 = pk2bf(s[(size_t)2 * hw], s[(size_t)3 * hw]);
  u32 w2 = pk2bf(s[(size_t)4 * hw], s[(size_t)5 * hw]);
  u32 w3 = pk2bf(s[(size_t)6 * hw], s[(size_t)7 * hw]);
  *(uint4*)&a.dst[seg][((size_t)b * hw + pos) * 64 + g8 * 8] = make_uint4(w0, w1, w2, w3);
}

// ---------------------------------------------------------------------------
// Staging helper (NPOS=180 fixed). modes: 0 fp32 planar | 1 chlast |
// 3 chlast half-res up2 | 4 fp32 planar half-res up2
// ---------------------------------------------------------------------------
__device__ __forceinline__ void stage_act(u16* s_act, int mode,
                                          const void* in1v, int c1,
                                          const void* in2v, int c2,
                                          bool use1, int kc, int nk1,
                                          int b, int by0, int bx0, int Hh, int Ww, int tid)
{
  constexpr int NPOS = 180;
  const int HW = Hh * Ww;
  if (mode == 0) {
    const float* sp = use1
      ? (const float*)in1v + ((size_t)b * c1 + (kc << 5)) * HW
      : (const float*)in2v + ((size_t)b * c2 + ((kc - nk1) << 5)) * HW;
#pragma unroll 1
    for (int u = tid; u < NPOS; u += TPB) {
      int y = u / 18, x = u - y * 18;
      int gy = by0 - 1 + y, gx = bx0 - 1 + x;
      bool inb = ((unsigned)gy < (unsigned)Hh) & ((unsigned)gx < (unsigned)Ww);
      const float msk = inb ? 1.f : 0.f;
      const size_t poff = inb ? ((size_t)gy * Ww + gx) : 0;
      const float* s0 = sp + poff;
      u16* dp = &s_act[u * 40];
#pragma unroll
      for (int c8 = 0; c8 < 4; ++c8) {
        u32 hb[4];
#pragma unroll
        for (int j = 0; j < 4; ++j)
          hb[j] = pk2bf(s0[(size_t)(c8 * 8 + 2 * j) * HW] * msk,
                        s0[(size_t)(c8 * 8 + 2 * j + 1) * HW] * msk);
        *(uint4*)&dp[c8 * 8] = make_uint4(hb[0], hb[1], hb[2], hb[3]);
      }
    }
  } else if (mode == 3) {
    const u16* b2 = (const u16*)in2v;
    const int hh = Hh >> 1, hw = Ww >> 1;
    const int cofs = (kc - nk1) << 5;
#pragma unroll 1
    for (int u = tid; u < NPOS; u += TPB) {
      int y = u / 18, x = u - y * 18;
      int gy = by0 - 1 + y, gx = bx0 - 1 + x;
      u16* dp = &s_act[u * 40];
      if ((unsigned)gy < (unsigned)Hh && (unsigned)gx < (unsigned)Ww) {
        int iy0, iy1, ix0, ix1; float wy0, wy1, wx0, wx1;
        if (gy & 1) { iy0 = gy >> 1; iy1 = min(iy0 + 1, hh - 1); wy0 = 0.75f; wy1 = 0.25f; }
        else        { iy1 = gy >> 1; iy0 = max(iy1 - 1, 0);      wy0 = 0.25f; wy1 = 0.75f; }
        if (gx & 1) { ix0 = gx >> 1; ix1 = min(ix0 + 1, hw - 1); wx0 = 0.75f; wx1 = 0.25f; }
        else        { ix1 = gx >> 1; ix0 = max(ix1 - 1, 0);      wx0 = 0.25f; wx1 = 0.75f; }
        const u16* pb = b2 + (size_t)b * hh * hw * 64 + cofs;
#pragma unroll
        for (int q = 0; q < 4; ++q) {
          const bf16x8 a00 = *(const bf16x8*)&pb[(size_t)(iy0 * hw + ix0) * 64 + q * 8];
          const bf16x8 a01 = *(const bf16x8*)&pb[(size_t)(iy0 * hw + ix1) * 64 + q * 8];
          const bf16x8 a10 = *(const bf16x8*)&pb[(size_t)(iy1 * hw + ix0) * 64 + q * 8];
          const bf16x8 a11 = *(const bf16x8*)&pb[(size_t)(iy1 * hw + ix1) * 64 + q * 8];
          u32 r[4];
#pragma unroll
          for (int j = 0; j < 4; ++j) {
            float v0 = wy0 * (wx0 * (float)a00[2 * j] + wx1 * (float)a01[2 * j])
                     + wy1 * (wx0 * (float)a10[2 * j] + wx1 * (float)a11[2 * j]);
            float v1 = wy0 * (wx0 * (float)a00[2 * j + 1] + wx1 * (float)a01[2 * j + 1])
                     + wy1 * (wx0 * (float)a10[2 * j + 1] + wx1 * (float)a11[2 * j + 1]);
            r[j] = pk2bf(v0, v1);
          }
          *(uint4*)&dp[q * 8] = make_uint4(r[0], r[1], r[2], r[3]);
        }
      } else {
#pragma unroll
        for (int q = 0; q < 4; ++q)
          *(uint4*)&dp[q * 8] = make_uint4(0u, 0u, 0u, 0u);
      }
    }
  } else if (mode == 4) {
    const float* f2 = (const float*)in2v;
    const int hh = Hh >> 1, hw = Ww >> 1;
    const int cofs = (kc - nk1) << 5;
    const int hhw = hh * hw;
#pragma unroll 1
    for (int u = tid; u < NPOS; u += TPB) {
      int y = u / 18, x = u - y * 18;
      int gy = by0 - 1 + y, gx = bx0 - 1 + x;
      u16* dp = &s_act[u * 40];
      if ((unsigned)gy < (unsigned)Hh && (unsigned)gx < (unsigned)Ww) {
        int iy0, iy1, ix0, ix1; float wy0, wy1, wx0, wx1;
        if (gy & 1) { iy0 = gy >> 1; iy1 = min(iy0 + 1, hh - 1); wy0 = 0.75f; wy1 = 0.25f; }
        else        { iy1 = gy >> 1; iy0 = max(iy1 - 1, 0);      wy0 = 0.25f; wy1 = 0.75f; }
        if (gx & 1) { ix0 = gx >> 1; ix1 = min(ix0 + 1, hw - 1); wx0 = 0.75f; wx1 = 0.25f; }
        else        { ix1 = gx >> 1; ix0 = max(ix1 - 1, 0);      wx0 = 0.25f; wx1 = 0.75f; }
        const float* pb = f2 + ((size_t)b * 64 + cofs) * hhw;
        const int i00 = iy0 * hw + ix0, i01 = iy0 * hw + ix1;
        const int i10 = iy1 * hw + ix0, i11 = iy1 * hw + ix1;
#pragma unroll
        for (int q = 0; q < 4; ++q) {
          u32 r[4];
#pragma unroll
          for (int j = 0; j < 4; ++j) {
            const float* p0 = pb + (size_t)(q * 8 + 2 * j) * hhw;
            const float* p1 = pb + (size_t)(q * 8 + 2 * j + 1) * hhw;
            float v0 = wy0 * (wx0 * p0[i00] + wx1 * p0[i01])
                     + wy1 * (wx0 * p0[i10] + wx1 * p0[i11]);
            float v1 = wy0 * (wx0 * p1[i00] + wx1 * p1[i01])
                     + wy1 * (wx0 * p1[i10] + wx1 * p1[i11]);
            r[j] = pk2bf(v0, v1);
          }
          *(uint4*)&dp[q * 8] = make_uint4(r[0], r[1], r[2], r[3]);
        }
      } else {
#pragma unroll
        for (int q = 0; q < 4; ++q)
          *(uint4*)&dp[q * 8] = make_uint4(0u, 0u, 0u, 0u);
      }
    }
  } else {
    const u16* src; int cofs, cst;
    if (use1) { src = (const u16*)in1v + (size_t)b * HW * c1; cofs = kc << 5; cst = c1; }
    else      { src = (const u16*)in2v + (size_t)b * HW * c2; cofs = (kc - nk1) << 5; cst = c2; }
#pragma unroll 1
    for (int i = tid; i < NPOS * 4; i += TPB) {
      int u = i >> 2, q = i & 3;
      int y = u / 18, x = u - y * 18;
      int gy = by0 - 1 + y, gx = bx0 - 1 + x;
      uint4 v = make_uint4(0u, 0u, 0u, 0u);
      if ((unsigned)gy < (unsigned)Hh && (unsigned)gx < (unsigned)Ww)
        v = *(const uint4*)&src[(size_t)(gy * Ww + gx) * cst + cofs + q * 8];
      *(uint4*)&s_act[u * 40 + q * 8] = v;
    }
  }
}

// ---------------------------------------------------------------------------
// Batch-merged conv core (TH=8, both batches per block, weights staged once).
// LDS: act 2x(180*40) + w 3*64*40 = 22080 u16 (~44KB) -> 3 blocks/CU.
// ---------------------------------------------------------------------------
struct CJob {
  const void* in1; const void* in2; int c1, c2, m1, m2;
  const u16* w; const float* bias;
  float* outf; u16* outb; int outmode, act, Cout, Coutpad, h;
};

__device__ __forceinline__ void conv_core_b2(const CJob& j, int cb, u16* s_mem)
{
  u16* s_act = s_mem;             // 2 * 7200
  u16* s_w   = s_mem + 14400;     // 7680
  const int Hh = j.h, Ww = j.h;
  const int xt = Ww >> 4;
  const int by0 = ((int)blockIdx.x / xt) * 8;
  const int bx0 = ((int)blockIdx.x % xt) << 4;
  const int tid = threadIdx.x;
  const int lx = tid & 15, slot = (tid >> 4) & 3, wv = tid >> 6;
  const int c1 = j.c1, c2 = j.c2;
  const int nkc = (c1 + c2) >> 5, nk1 = c1 >> 5;
  const int HW = Hh * Ww;

  f32x4 acc[2][4][2];
#pragma unroll
  for (int b = 0; b < 2; ++b)
#pragma unroll
    for (int i = 0; i < 4; ++i)
#pragma unroll
      for (int g = 0; g < 2; ++g) acc[b][i][g] = (f32x4){0.f, 0.f, 0.f, 0.f};

#pragma unroll 1
  for (int kc = 0; kc < nkc; ++kc) {
    __syncthreads();
    const bool use1 = kc < nk1;
    const int mode = use1 ? j.m1 : j.m2;
    stage_act(s_act,        mode, j.in1, c1, j.in2, c2, use1, kc, nk1, 0, by0, bx0, Hh, Ww, tid);
    stage_act(s_act + 7200, mode, j.in1, c1, j.in2, c2, use1, kc, nk1, 1, by0, bx0, Hh, Ww, tid);
#pragma unroll 1
    for (int ky = 0; ky < 3; ++ky) {
      __syncthreads();
      {
        const size_t base = ((size_t)(kc * 9 + ky * 3) * j.Coutpad + cb) * 40;
        const size_t tapstride = (size_t)j.Coutpad * 40;
#pragma unroll 1
        for (int i = tid; i < 960; i += TPB) {
          int kxl = i / 320, jj = i - kxl * 320;
          const uint4 v = *(const uint4*)&j.w[base + (size_t)kxl * tapstride + jj * 8];
          *(uint4*)&s_w[kxl * 2560 + jj * 8] = v;
        }
      }
      __syncthreads();
#pragma unroll
      for (int kx = 0; kx < 3; ++kx) {
        bf16x8 Af[4];
#pragma unroll
        for (int ct = 0; ct < 4; ++ct)
          Af[ct] = *(const bf16x8*)&s_w[(kx * 64 + ct * 16 + lx) * 40 + slot * 8];
        bf16x8 Bf[2][2];
#pragma unroll
        for (int b = 0; b < 2; ++b)
#pragma unroll
          for (int pg = 0; pg < 2; ++pg)
            Bf[b][pg] = *(const bf16x8*)&s_act[b * 7200 + ((wv * 2 + pg + ky) * 18 + lx + kx) * 40 + slot * 8];
#pragma unroll
        for (int ct = 0; ct < 4; ++ct)
#pragma unroll
          for (int b = 0; b < 2; ++b)
#pragma unroll
            for (int pg = 0; pg < 2; ++pg)
              acc[b][ct][pg] = __builtin_amdgcn_mfma_f32_16x16x32_bf16(Af[ct], Bf[b][pg], acc[b][ct][pg], 0, 0, 0);
      }
    }
  }
  const int ox = bx0 + lx;
  const int jact = j.act;
  if (j.outmode == 1) {
#pragma unroll 1
    for (int b = 0; b < 2; ++b) {
      __syncthreads();
#pragma unroll
      for (int ct = 0; ct < 4; ++ct) {
        const int co0 = ct * 16 + slot * 4;
        const float b0 = j.bias[co0], b1 = j.bias[co0 + 1], b2 = j.bias[co0 + 2], b3 = j.bias[co0 + 3];
#pragma unroll
        for (int pg = 0; pg < 2; ++pg) {
          const int px = (wv * 2 + pg) * 16 + lx;
          *(u32*)&s_mem[px * 72 + co0]     = pk2bf(act_rt(acc[b][ct][pg][0] + b0, jact),
                                                   act_rt(acc[b][ct][pg][1] + b1, jact));
          *(u32*)&s_mem[px * 72 + co0 + 2] = pk2bf(act_rt(acc[b][ct][pg][2] + b2, jact),
                                                   act_rt(acc[b][ct][pg][3] + b3, jact));
        }
      }
      __syncthreads();
#pragma unroll 1
      for (int l = tid; l < 1024; l += TPB) {
        const int px = l >> 3, ch = (l & 7) * 8;
        const int row = px >> 4, col = px & 15;
        const uint4 v = *(const uint4*)&s_mem[px * 72 + ch];
        *(uint4*)&j.outb[(((size_t)b * HW + (size_t)(by0 + row) * Ww + bx0 + col) << 6) + ch] = v;
      }
    }
  } else if (j.outmode == 2) {
#pragma unroll 1
    for (int b = 0; b < 2; ++b) {
#pragma unroll
      for (int ct = 0; ct < 4; ++ct) {
        const int co0 = cb + ct * 16 + slot * 4;
#pragma unroll
        for (int r = 0; r < 4; ++r) {
          const int co = co0 + r;
          if (co < j.Cout) {
            const float bv = j.bias[co];
            u16* op = j.outb + ((size_t)b * j.Cout + co) * HW + (size_t)(by0 + wv * 2) * Ww + ox;
#pragma unroll
            for (int pg = 0; pg < 2; ++pg)
              op[pg * Ww] = f2bf(act_rt(acc[b][ct][pg][r] + bv, jact));
          }
        }
      }
    }
  } else {
#pragma unroll 1
    for (int b = 0; b < 2; ++b) {
#pragma unroll
      for (int ct = 0; ct < 4; ++ct) {
        const int co0 = cb + ct * 16 + slot * 4;
#pragma unroll
        for (int r = 0; r < 4; ++r) {
          const int co = co0 + r;
          if (co < j.Cout) {
            const float bv = j.bias[co];
            float* op = j.outf + ((size_t)b * j.Cout + co) * HW + (size_t)(by0 + wv * 2) * Ww + ox;
#pragma unroll
            for (int pg = 0; pg < 2; ++pg)
              op[pg * Ww] = act_rt(acc[b][ct][pg][r] + bv, jact);
          }
        }
      }
    }
  }
}

__global__ __launch_bounds__(TPB, 3)
void k_conv_b2_1(CJob A)
{
  __shared__ __align__(16) u16 s_mem[22080];
  conv_core_b2(A, (int)blockIdx.y << 6, s_mem);
}

__global__ __launch_bounds__(TPB, 3)
void k_conv_b2_2(CJob A, CJob B, int ny0)
{
  __shared__ __align__(16) u16 s_mem[22080];
  const bool isA = (int)blockIdx.y < ny0;
  const CJob& j = isA ? A : B;
  const int nbx = (j.h >> 3) * (j.h >> 4);
  if ((int)blockIdx.x >= nbx) return;
  const int cb = (isA ? blockIdx.y : blockIdx.y - ny0) << 6;
  conv_core_b2(j, cb, s_mem);
}

__global__ __launch_bounds__(TPB, 3)
void k_conv_b2_tri(CJob A0, CJob B0, CJob A1, CJob B1, CJob A2, CJob B2)
{
  __shared__ __align__(16) u16 s_mem[22080];
  const int lvl = blockIdx.y / 5, sub = blockIdx.y % 5;
  const CJob& j = (lvl == 0) ? (sub == 0 ? A0 : B0)
                : (lvl == 1) ? (sub == 0 ? A1 : B1)
                             : (sub == 0 ? A2 : B2);
  const int nbx = (j.h >> 3) * (j.h >> 4);
  if ((int)blockIdx.x >= nbx) return;
  const int cb = (sub == 0) ? 0 : ((sub - 1) << 6);
  conv_core_b2(j, cb, s_mem);
}

// ---------------------------------------------------------------------------
// Deformable conv (round-17 structure, unchanged)
// ---------------------------------------------------------------------------
struct DJob {
  const u16* xbf; const u16* off; const u16* mask;
  int maskC, maskBase;
  const float* wgt; const float* bias; float* out;
  int sigm, act;
};

__device__ __forceinline__ void dconv_core(const DJob& j, int gs, int Hh, int Ww,
                                           u16 (*s_x)[40], float* s_w, float* s_b)
{
  const int b   = blockIdx.z;
  const int xt  = Ww >> 4;
  const int ty0 = (blockIdx.x / xt) << 3;
  const int tx0 = (blockIdx.x % xt) << 4;
  const int tid = threadIdx.x;
  const int HW  = Hh * Ww;

  for (int i = tid; i < 2304; i += TPB) {
    int o = i & 7, c = (i >> 3) & 7, k = (i >> 6) % 9, gl = i / 576;
    s_w[i] = j.wgt[(((size_t)((gs * 4 + gl) * 8 + o)) * 8 + c) * 9 + k];
  }
  if (tid < 32) s_b[tid] = j.bias[gs * 32 + tid];
  {
    const u16* xb = j.xbf + (size_t)b * HW * 64 + gs * 32;
#pragma unroll 1
    for (int i = tid; i < 960; i += TPB) {
      int px = i >> 2, q = i & 3;
      int r = px / 20, cx = px - r * 20;
      int gy = ty0 - 2 + r, gx = tx0 - 2 + cx;
      uint4 v = make_uint4(0u, 0u, 0u, 0u);
      if ((unsigned)gy < (unsigned)Hh && (unsigned)gx < (unsigned)Ww)
        v = *(const uint4*)&xb[(size_t)(gy * Ww + gx) * 64 + q * 8];
      *(uint4*)&s_x[px][q * 8] = v;
    }
  }
  __syncthreads();

  const int pin = tid & 127;
  const int ghalf = tid >> 7;
  const int py_ = pin >> 4, px_ = pin & 15;
  const int gy = ty0 + py_, gx = tx0 + px_;
  const int p  = gy * Ww + gx;
  const int sigm = j.sigm, act = j.act;

#pragma unroll
  for (int jj = 0; jj < 2; ++jj) {
    const int gl = ghalf * 2 + jj;
    const int g  = gs * 4 + gl;
    const u16* ob = j.off  + ((size_t)b * 216 + g * 18) * HW + p;
    const u16* mb = j.mask + ((size_t)b * j.maskC + j.maskBase + g * 9) * HW + p;
    const u16* xg = j.xbf  + (size_t)b * HW * 64 + g * 8;
    float*     og = j.out  + ((size_t)b * 64 + g * 8) * HW + p;
    const float* wg = &s_w[gl * 9 * 64];

    float acc[8];
#pragma unroll
    for (int o = 0; o < 8; ++o) acc[o] = s_b[gl * 8 + o];

#pragma unroll
    for (int k = 0; k < 9; ++k) {
      const float oyk = bf2f(ob[(size_t)(2 * k) * HW]);
      const float oxk = bf2f(ob[(size_t)(2 * k + 1) * HW]);
      float m = bf2f(mb[(size_t)k * HW]);
      if (sigm) m = 1.f / (1.f + expf(-m));
      const float py = (float)(gy + k / 3 - 1) + oyk;
      const float px = (float)(gx + k % 3 - 1) + oxk;
      const float y0f = floorf(py), x0f = floorf(px);
      const float fy = py - y0f, fx = px - x0f;
      const int y0 = (int)y0f, x0 = (int)x0f;
      const int y1 = y0 + 1, x1 = x0 + 1;
      const float vy0 = (y0 >= 0 && y0 < Hh) ? 1.f : 0.f;
      const float vy1 = (y1 >= 0 && y1 < Hh) ? 1.f : 0.f;
      const float vx0 = (x0 >= 0 && x0 < Ww) ? 1.f : 0.f;
      const float vx1 = (x1 >= 0 && x1 < Ww) ? 1.f : 0.f;
      const float w00 = (1.f - fy) * (1.f - fx) * vy0 * vx0 * m;
      const float w01 = (1.f - fy) * fx * vy0 * vx1 * m;
      const float w10 = fy * (1.f - fx) * vy1 * vx0 * m;
      const float w11 = fy * fx * vy1 * vx1 * m;
      const float* wk = &wg[k * 64];
      const int ly = y0 - ty0 + 2, lxw = x0 - tx0 + 2;
      if ((unsigned)ly < 11u && (unsigned)lxw < 19u) {
        const u16* base = &s_x[ly * 20 + lxw][gl * 8];
        const bf16x8 c00 = *(const bf16x8*)base;
        const bf16x8 c01 = *(const bf16x8*)(base + 40);
        const bf16x8 c10 = *(const bf16x8*)(base + 800);
        const bf16x8 c11 = *(const bf16x8*)(base + 840);
#pragma unroll
        for (int c = 0; c < 8; ++c) {
          const float s = w00 * (float)c00[c] + w01 * (float)c01[c]
                        + w10 * (float)c10[c] + w11 * (float)c11[c];
          const float4 wv0 = *(const float4*)&wk[c * 8];
          const float4 wv1 = *(const float4*)&wk[c * 8 + 4];
          acc[0] = fmaf(s, wv0.x, acc[0]); acc[1] = fmaf(s, wv0.y, acc[1]);
          acc[2] = fmaf(s, wv0.z, acc[2]); acc[3] = fmaf(s, wv0.w, acc[3]);
          acc[4] = fmaf(s, wv1.x, acc[4]); acc[5] = fmaf(s, wv1.y, acc[5]);
          acc[6] = fmaf(s, wv1.z, acc[6]); acc[7] = fmaf(s, wv1.w, acc[7]);
        }
      } else {
        const int cy0 = min(max(y0, 0), Hh - 1), cy1 = min(max(y1, 0), Hh - 1);
        const int cx0 = min(max(x0, 0), Ww - 1), cx1 = min(max(x1, 0), Ww - 1);
        const int i00 = (cy0 * Ww + cx0) * 64, i01 = (cy0 * Ww + cx1) * 64;
        const int i10 = (cy1 * Ww + cx0) * 64, i11 = (cy1 * Ww + cx1) * 64;
#pragma unroll
        for (int c = 0; c < 8; ++c) {
          const float s = w00 * bf2f(xg[i00 + c]) + w01 * bf2f(xg[i01 + c])
                        + w10 * bf2f(xg[i10 + c]) + w11 * bf2f(xg[i11 + c]);
          const float4 wv0 = *(const float4*)&wk[c * 8];
          const float4 wv1 = *(const float4*)&wk[c * 8 + 4];
          acc[0] = fmaf(s, wv0.x, acc[0]); acc[1] = fmaf(s, wv0.y, acc[1]);
          acc[2] = fmaf(s, wv0.z, acc[2]); acc[3] = fmaf(s, wv0.w, acc[3]);
          acc[4] = fmaf(s, wv1.x, acc[4]); acc[5] = fmaf(s, wv1.y, acc[5]);
          acc[6] = fmaf(s, wv1.z, acc[6]); acc[7] = fmaf(s, wv1.w, acc[7]);
        }
      }
    }
#pragma unroll
    for (int o = 0; o < 8; ++o) {
      float v = acc[o];
      if (act) v = v >= 0.f ? v : 0.1f * v;
      og[(size_t)o * HW] = v;
    }
  }
}

__global__ __launch_bounds__(TPB, 4)
void k_dconv_one(DJob j, int Hh, int Ww)
{
  __shared__ __align__(16) u16 s_x[240][40];
  __shared__ __align__(16) float s_w[4 * 9 * 64];
  __shared__ float s_b[32];
  dconv_core(j, blockIdx.y, Hh, Ww, s_x, s_w, s_b);
}

__global__ __launch_bounds__(TPB, 4)
void k_dconv_dual(DJob a, DJob b, int Hh, int Ww)
{
  __shared__ __align__(16) u16 s_x[240][40];
  __shared__ __align__(16) float s_w[4 * 9 * 64];
  __shared__ float s_b[32];
  const DJob& j = (blockIdx.y & 1) ? b : a;
  dconv_core(j, blockIdx.y >> 1, Hh, Ww, s_x, s_w, s_b);
}

// ---------------------------------------------------------------------------
// host helpers
// ---------------------------------------------------------------------------
static CJob mkcjob(const void* i1, const void* i2, int c1, int c2, int m1, int m2,
                   const u16* w, const float* bias, float* outf, u16* outb,
                   int outmode, int act, int Cout, int h)
{
  CJob j; j.in1 = i1; j.in2 = i2; j.c1 = c1; j.c2 = c2; j.m1 = m1; j.m2 = m2;
  j.w = w; j.bias = bias; j.outf = outf; j.outb = outb; j.outmode = outmode;
  j.act = act; j.Cout = Cout; j.Coutpad = ((Cout + 63) / 64) * 64; j.h = h;
  return j;
}

static void conv1(hipStream_t st, CJob a)
{
  dim3 grid((a.h / 8) * (a.h / 16), a.Coutpad / 64, 1);
  k_conv_b2_1<<<grid, TPB, 0, st>>>(a);
}

static void conv2(hipStream_t st, CJob a, CJob b)
{
  int ny0 = a.Coutpad / 64, ny1 = b.Coutpad / 64;
  int nbx0 = (a.h / 8) * (a.h / 16), nbx1 = (b.h / 8) * (b.h / 16);
  dim3 grid(max(nbx0, nbx1), ny0 + ny1, 1);
  k_conv_b2_2<<<grid, TPB, 0, st>>>(a, b, ny0);
}

static DJob mkdjob(const u16* xbf, const u16* off, const u16* mask, int maskC, int maskBase,
                   const float* w, const float* b, float* out, int sigm, int act)
{
  DJob j; j.xbf = xbf; j.off = off; j.mask = mask; j.maskC = maskC; j.maskBase = maskBase;
  j.wgt = w; j.bias = b; j.out = out; j.sigm = sigm; j.act = act;
  return j;
}

static void dconv_dual(hipStream_t st, DJob a, DJob b, int h, int wd)
{
  dim3 grid((h / 8) * (wd / 16), 4, 2);
  k_dconv_dual<<<grid, TPB, 0, st>>>(a, b, h, wd);
}

static void dconv_one(hipStream_t st, DJob a, int h, int wd)
{
  dim3 grid((h / 8) * (wd / 16), 2, 2);
  k_dconv_one<<<grid, TPB, 0, st>>>(a, h, wd);
}

extern "C" void kernel_launch(void* const* d_in, const int* in_sizes, int n_in,
                              void* d_out, int out_size, void* d_ws, size_t ws_size,
                              hipStream_t stream)
{
  const float* const* in = (const float* const*)d_in;

  const int HW0 = 192 * 192, HW1 = 96 * 96, HW2 = 48 * 48;
  const size_t N0 = (size_t)2 * HW0 * 64, N1 = (size_t)2 * HW1 * 64, N2 = (size_t)2 * HW2 * 64;

  // ---- workspace layout ----
  u16* p = (u16*)d_ws;
  u16* nrf0b = p; p += N0;
  u16* rf0b  = p; p += N0;
  u16* swf0b = p; p += N0;
  u16* nrf1b = p; p += N1;
  u16* rf1b  = p; p += N1;
  u16* swf1b = p; p += N1;
  u16* nrf2b = p; p += N2;
  u16* rf2b  = p; p += N2;
  u16* swf2b = p; p += N2;
  u16* A0bf  = p; p += N0;
  u16* A1bf  = p; p += N1;
  u16* A2bf  = p; p += N2;
  u16* OM0   = p; p += (size_t)2 * 216 * HW0;
  u16* OM1   = p; p += (size_t)2 * 216 * HW1;
  u16* OM2   = p; p += (size_t)2 * 216 * HW2;
  u16* EM    = p; p += (size_t)2 * 72 * HW0;
  u16* OF0bf = p; p += N0;
  u16* DN0bf = p; p += N0;
  p = (u16*)(((uintptr_t)p + 15) & ~(uintptr_t)15);
  float* XD   = (float*)p;
  float* DN1  = XD + (size_t)2 * 64 * HW0;
  u16* wp = (u16*)(DN1 + (size_t)2 * 64 * HW1);

  float* dout = (float*)d_out;
  const size_t L0 = (size_t)2 * 64 * HW0;
  float* out0 = dout;
  float* sh0  = dout + L0;
  float* sh1  = sh0  + L0;
  float* sh2  = sh1  + L0 / 4;
  // d_out dead-region aliases:
  u16*   Bbf   = (u16*)out0;                                 // overwritten by final dconv
  u16*   OF1bf = (u16*)sh0;                                  // dead before dual0 writes sh0
  u16*   OF2bf = OF1bf + N1;
  float* DN2   = (float*)(OF2bf + N2);

  // ---- input conversion ----
  {
    ToBfArgs ta;
    const float* srcs[9] = {in[0], in[1], in[2], in[3], in[4], in[5], in[6], in[7], in[8]};
    u16* dsts[9] = {nrf0b, rf0b, swf0b, nrf1b, rf1b, swf1b, nrf2b, rf2b, swf2b};
    const int hws[9] = {HW0, HW0, HW0, HW1, HW1, HW1, HW2, HW2, HW2};
    for (int i = 0; i < 9; ++i) { ta.src[i] = srcs[i]; ta.dst[i] = dsts[i]; ta.hw[i] = hws[i]; }
    int maxtot = 2 * HW0 * 8;
    k_tobf_all<<<dim3((maxtot + TPB - 1) / TPB, 9), TPB, 0, stream>>>(ta);
  }

  // ---- weight prep ----
  struct { int arg, cin, cout; } plist[22] = {
    {9,128,64},{11,64,64},{13,64,216},{15,128,64},{17,64,72},
    {21,128,64},{23,64,64},{25,64,216},{27,128,64},{29,64,72},
    {33,128,64},{35,64,64},{37,64,216},{39,128,64},{41,64,72},
    {45,128,64},{47,128,64},{49,128,64},{51,128,64},
    {53,128,64},{55,64,64},{57,64,216}};
  WPrepArgs wa;
  u16* wptr[22];
  int maxtot = 0;
  for (int i = 0; i < 22; ++i) {
    int cin = plist[i].cin, cout = plist[i].cout;
    int cpad = ((cout + 63) / 64) * 64;
    int tot = (cin / 32) * 9 * cpad * 40;
    wa.src[i] = in[plist[i].arg]; wa.dst[i] = wp;
    wa.cin[i] = cin; wa.cout[i] = cout; wa.coutpad[i] = cpad; wa.total[i] = tot;
    wptr[i] = wp; wp += tot;
    if (tot > maxtot) maxtot = tot;
  }
  k_wprep_all<<<dim3((maxtot + TPB - 1) / TPB, 22), TPB, 0, stream>>>(wa);

  u16* w_ocf0 = wptr[0];  u16* w_ocl0 = wptr[1];  u16* w_com0 = wptr[2];
  u16* w_em10 = wptr[3];  u16* w_em20 = wptr[4];
  u16* w_ocf1 = wptr[5];  u16* w_ocl1 = wptr[6];  u16* w_com1 = wptr[7];
  u16* w_em11 = wptr[8];  u16* w_em21 = wptr[9];
  u16* w_ocf2 = wptr[10]; u16* w_ocl2 = wptr[11]; u16* w_com2 = wptr[12];
  u16* w_em12 = wptr[13]; u16* w_em22 = wptr[14];
  u16* w_occ0 = wptr[15]; u16* w_fcc0 = wptr[16];
  u16* w_occ1 = wptr[17]; u16* w_fcc1 = wptr[18];
  u16* w_cas1 = wptr[19]; u16* w_cas2 = wptr[20]; u16* w_casc = wptr[21];

  const int h2 = 48, h1 = 96, h0 = 192;

  // ---- tri-level mega-pair (b2): all ocf_i + com_i ----
  {
    CJob a0 = mkcjob(nrf0b, rf0b,  64, 64, 1, 1, w_ocf0, in[10], nullptr, A0bf, 1, 1, 64,  h0);
    CJob b0 = mkcjob(swf0b, nullptr,64, 0, 1, 1, w_com0, in[14], nullptr, OM0,  2, 0, 216, h0);
    CJob a1 = mkcjob(nrf1b, rf1b,  64, 64, 1, 1, w_ocf1, in[22], nullptr, A1bf, 1, 1, 64,  h1);
    CJob b1 = mkcjob(swf1b, nullptr,64, 0, 1, 1, w_com1, in[26], nullptr, OM1,  2, 0, 216, h1);
    CJob a2 = mkcjob(nrf2b, rf2b,  64, 64, 1, 1, w_ocf2, in[34], nullptr, A2bf, 1, 1, 64,  h2);
    CJob b2 = mkcjob(swf2b, nullptr,64, 0, 1, 1, w_com2, in[38], nullptr, OM2,  2, 0, 216, h2);
    dim3 grid(288, 15, 1);
    k_conv_b2_tri<<<grid, TPB, 0, stream>>>(a0, b0, a1, b1, a2, b2);
  }

  // ocl2 (48²)
  conv1(stream, mkcjob(A2bf, nullptr, 64, 0, 1, 1, w_ocl2, in[36], nullptr, OF2bf, 1, 1, 64, h2));
  // p1: em12(48) + occ1(96, fused chlast up2)
  conv2(stream,
    mkcjob(OF2bf, swf2b, 64, 64, 1, 1, w_em12, in[40], nullptr, A2bf, 1, 1, 64, h2),
    mkcjob(A1bf,  OF2bf, 64, 64, 1, 3, w_occ1, in[50], nullptr, Bbf,  1, 1, 64, h1));
  // p2: em22(48, sigmoid->EM planar) + ocl1(96)
  conv2(stream,
    mkcjob(A2bf, nullptr, 64, 0, 1, 1, w_em22, in[42], nullptr, EM,    2, 2, 72, h2),
    mkcjob(Bbf,  nullptr, 64, 0, 1, 1, w_ocl1, in[24], nullptr, OF1bf, 1, 1, 64, h1));
  // dual2: sh2 + xd2
  dconv_dual(stream,
             mkdjob(OF2bf, OM2, EM,  72, 0,   in[43], in[44], sh2, 0, 0),
             mkdjob(nrf2b, OM2, OM2, 216, 144, in[43], in[44], DN2, 1, 1), h2, h2);
  // p3: em11(96) + occ0(192, fused chlast up2)
  conv2(stream,
    mkcjob(OF1bf, swf1b, 64, 64, 1, 1, w_em11, in[28], nullptr, A1bf, 1, 1, 64, h1),
    mkcjob(A0bf,  OF1bf, 64, 64, 1, 3, w_occ0, in[46], nullptr, Bbf,  1, 1, 64, h0));
  // p4: em21(96, sigmoid->EM) + ocl0(192)
  conv2(stream,
    mkcjob(A1bf, nullptr, 64, 0, 1, 1, w_em21, in[30], nullptr, EM,    2, 2, 72, h1),
    mkcjob(Bbf,  nullptr, 64, 0, 1, 1, w_ocl0, in[12], nullptr, OF0bf, 1, 1, 64, h0));
  // dual1: sh1 + xd1
  dconv_dual(stream,
             mkdjob(OF1bf, OM1, EM,  72, 0,   in[31], in[32], sh1, 0, 0),
             mkdjob(nrf1b, OM1, OM1, 216, 144, in[31], in[32], XD, 1, 0), h1, h1);
  // p5: em10(192) + fcc1(96, fp32 + fp32-up2 -> fp32)
  conv2(stream,
    mkcjob(OF0bf, swf0b, 64, 64, 1, 1, w_em10, in[16], nullptr, Bbf, 1, 1, 64, h0),
    mkcjob(XD,    DN2,   64, 64, 0, 4, w_fcc1, in[52], DN1, nullptr, 0, 1, 64, h1));
  // em20 (192, sigmoid->EM)
  conv1(stream, mkcjob(Bbf, nullptr, 64, 0, 1, 1, w_em20, in[18], nullptr, EM, 2, 2, 72, h0));
  // dual0: sh0 + xd0
  dconv_dual(stream,
             mkdjob(OF0bf, OM0, EM,  72, 0,   in[19], in[20], sh0, 0, 0),
             mkdjob(nrf0b, OM0, OM0, 216, 144, in[19], in[20], XD, 1, 0), h0, h0);
  // fcc0 (fp32 + fp32-up2 -> chlast)
  conv1(stream, mkcjob(XD, DN1, 64, 64, 0, 4, w_fcc0, in[48], nullptr, DN0bf, 1, 0, 64, h0));
  // cascade
  conv1(stream, mkcjob(DN0bf, rf0b, 64, 64, 1, 1, w_cas1, in[54], nullptr, A0bf, 1, 1, 64, h0));
  conv1(stream, mkcjob(A0bf, nullptr, 64, 0, 1, 1, w_cas2, in[56], nullptr, Bbf, 1, 1, 64, h0));
  conv1(stream, mkcjob(Bbf, nullptr, 64, 0, 1, 1, w_casc, in[58], nullptr, OM0, 2, 0, 216, h0));
  dconv_one(stream,
            mkdjob(DN0bf, OM0, OM0, 216, 144, in[59], in[60], out0, 1, 1), h0, h0);
}

// Round 22
// 1344.877 us; speedup vs baseline: 1.2486x; 1.2486x over previous
//
#include <hip/hip_runtime.h>
#include <cstddef>
#include <cstdint>

#define TPB 256

typedef unsigned int u32;
typedef unsigned short u16;
typedef __bf16 bf16x8 __attribute__((ext_vector_type(8)));
typedef float f32x4 __attribute__((ext_vector_type(4)));

__device__ __forceinline__ float act_rt(float v, int a) {
  if (a == 1) return v >= 0.f ? v : 0.1f * v;
  if (a == 2) return 1.f / (1.f + expf(-v));
  return v;
}

__device__ __forceinline__ u16 f2bf(float f) {
  __bf16 h = (__bf16)f;
  return __builtin_bit_cast(u16, h);
}
__device__ __forceinline__ float bf2f(u16 h) {
  return __uint_as_float(((u32)h) << 16);
}
__device__ __forceinline__ u32 pk2bf(float a, float b) {
  return (u32)f2bf(a) | ((u32)f2bf(b) << 16);
}

// ---------------------------------------------------------------------------
// Weight prep (one launch, 22 convs)
// ---------------------------------------------------------------------------
struct WPrepArgs {
  const float* src[22];
  u16* dst[22];
  int cin[22], cout[22], coutpad[22], total[22];
};

__global__ void k_wprep_all(WPrepArgs a)
{
  const int seg = blockIdx.y;
  const int idx = blockIdx.x * TPB + threadIdx.x;
  if (idx >= a.total[seg]) return;
  const int Cin = a.cin[seg], Cout = a.cout[seg], Coutpad = a.coutpad[seg];
  int kk = idx % 40; int t = idx / 40;
  int co = t % Coutpad; t /= Coutpad;
  int tap = t % 9; int kc = t / 9;
  u16 v = 0;
  if (kk < 32 && co < Cout)
    v = f2bf(a.src[seg][((size_t)co * Cin + kc * 32 + kk) * 9 + tap]);
  a.dst[seg][idx] = v;
}

// ---------------------------------------------------------------------------
// Input prep
// ---------------------------------------------------------------------------
struct ToBfArgs {
  const float* src[9];
  u16* dst[9];
  int hw[9];
};

__global__ void k_tobf_all(ToBfArgs a)
{
  const int seg = blockIdx.y;
  const int hw = a.hw[seg];
  const int total = 2 * hw * 8;
  int idx = blockIdx.x * TPB + threadIdx.x;
  if (idx >= total) return;
  const int g8 = idx & 7;
  int t = idx >> 3;
  const int pos = t % hw, b = t / hw;
  const float* s = a.src[seg] + ((size_t)b * 64 + g8 * 8) * hw + pos;
  u32 w0 = pk2bf(s[0], s[(size_t)hw]);
  u32 w1 = pk2bf(s[(size_t)2 * hw], s[(size_t)3 * hw]);
  u32 w2 = pk2bf(s[(size_t)4 * hw], s[(size_t)5 * hw]);
  u32 w3 = pk2bf(s[(size_t)6 * hw], s[(size_t)7 * hw]);
  *(uint4*)&a.dst[seg][((size_t)b * hw + pos) * 64 + g8 * 8] = make_uint4(w0, w1, w2, w3);
}

// ---------------------------------------------------------------------------
// Staging helper (NPOS=180 fixed). modes: 0 fp32 planar | 1 chlast |
// 3 chlast half-res up2 | 4 fp32 planar half-res up2
// ---------------------------------------------------------------------------
__device__ __forceinline__ void stage_act(u16* s_act, int mode,
                                          const void* in1v, int c1,
                                          const void* in2v, int c2,
                                          bool use1, int kc, int nk1,
                                          int b, int by0, int bx0, int Hh, int Ww, int tid)
{
  constexpr int NPOS = 180;
  const int HW = Hh * Ww;
  if (mode == 0) {
    const float* sp = use1
      ? (const float*)in1v + ((size_t)b * c1 + (kc << 5)) * HW
      : (const float*)in2v + ((size_t)b * c2 + ((kc - nk1) << 5)) * HW;
#pragma unroll 1
    for (int u = tid; u < NPOS; u += TPB) {
      int y = u / 18, x = u - y * 18;
      int gy = by0 - 1 + y, gx = bx0 - 1 + x;
      bool inb = ((unsigned)gy < (unsigned)Hh) & ((unsigned)gx < (unsigned)Ww);
      const float msk = inb ? 1.f : 0.f;
      const size_t poff = inb ? ((size_t)gy * Ww + gx) : 0;
      const float* s0 = sp + poff;
      u16* dp = &s_act[u * 40];
#pragma unroll
      for (int c8 = 0; c8 < 4; ++c8) {
        u32 hb[4];
#pragma unroll
        for (int j = 0; j < 4; ++j)
          hb[j] = pk2bf(s0[(size_t)(c8 * 8 + 2 * j) * HW] * msk,
                        s0[(size_t)(c8 * 8 + 2 * j + 1) * HW] * msk);
        *(uint4*)&dp[c8 * 8] = make_uint4(hb[0], hb[1], hb[2], hb[3]);
      }
    }
  } else if (mode == 3) {
    const u16* b2 = (const u16*)in2v;
    const int hh = Hh >> 1, hw = Ww >> 1;
    const int cofs = (kc - nk1) << 5;
#pragma unroll 1
    for (int u = tid; u < NPOS; u += TPB) {
      int y = u / 18, x = u - y * 18;
      int gy = by0 - 1 + y, gx = bx0 - 1 + x;
      u16* dp = &s_act[u * 40];
      if ((unsigned)gy < (unsigned)Hh && (unsigned)gx < (unsigned)Ww) {
        int iy0, iy1, ix0, ix1; float wy0, wy1, wx0, wx1;
        if (gy & 1) { iy0 = gy >> 1; iy1 = min(iy0 + 1, hh - 1); wy0 = 0.75f; wy1 = 0.25f; }
        else        { iy1 = gy >> 1; iy0 = max(iy1 - 1, 0);      wy0 = 0.25f; wy1 = 0.75f; }
        if (gx & 1) { ix0 = gx >> 1; ix1 = min(ix0 + 1, hw - 1); wx0 = 0.75f; wx1 = 0.25f; }
        else        { ix1 = gx >> 1; ix0 = max(ix1 - 1, 0);      wx0 = 0.25f; wx1 = 0.75f; }
        const u16* pb = b2 + (size_t)b * hh * hw * 64 + cofs;
#pragma unroll
        for (int q = 0; q < 4; ++q) {
          const bf16x8 a00 = *(const bf16x8*)&pb[(size_t)(iy0 * hw + ix0) * 64 + q * 8];
          const bf16x8 a01 = *(const bf16x8*)&pb[(size_t)(iy0 * hw + ix1) * 64 + q * 8];
          const bf16x8 a10 = *(const bf16x8*)&pb[(size_t)(iy1 * hw + ix0) * 64 + q * 8];
          const bf16x8 a11 = *(const bf16x8*)&pb[(size_t)(iy1 * hw + ix1) * 64 + q * 8];
          u32 r[4];
#pragma unroll
          for (int j = 0; j < 4; ++j) {
            float v0 = wy0 * (wx0 * (float)a00[2 * j] + wx1 * (float)a01[2 * j])
                     + wy1 * (wx0 * (float)a10[2 * j] + wx1 * (float)a11[2 * j]);
            float v1 = wy0 * (wx0 * (float)a00[2 * j + 1] + wx1 * (float)a01[2 * j + 1])
                     + wy1 * (wx0 * (float)a10[2 * j + 1] + wx1 * (float)a11[2 * j + 1]);
            r[j] = pk2bf(v0, v1);
          }
          *(uint4*)&dp[q * 8] = make_uint4(r[0], r[1], r[2], r[3]);
        }
      } else {
#pragma unroll
        for (int q = 0; q < 4; ++q)
          *(uint4*)&dp[q * 8] = make_uint4(0u, 0u, 0u, 0u);
      }
    }
  } else if (mode == 4) {
    const float* f2 = (const float*)in2v;
    const int hh = Hh >> 1, hw = Ww >> 1;
    const int cofs = (kc - nk1) << 5;
    const int hhw = hh * hw;
#pragma unroll 1
    for (int u = tid; u < NPOS; u += TPB) {
      int y = u / 18, x = u - y * 18;
      int gy = by0 - 1 + y, gx = bx0 - 1 + x;
      u16* dp = &s_act[u * 40];
      if ((unsigned)gy < (unsigned)Hh && (unsigned)gx < (unsigned)Ww) {
        int iy0, iy1, ix0, ix1; float wy0, wy1, wx0, wx1;
        if (gy & 1) { iy0 = gy >> 1; iy1 = min(iy0 + 1, hh - 1); wy0 = 0.75f; wy1 = 0.25f; }
        else        { iy1 = gy >> 1; iy0 = max(iy1 - 1, 0);      wy0 = 0.25f; wy1 = 0.75f; }
        if (gx & 1) { ix0 = gx >> 1; ix1 = min(ix0 + 1, hw - 1); wx0 = 0.75f; wx1 = 0.25f; }
        else        { ix1 = gx >> 1; ix0 = max(ix1 - 1, 0);      wx0 = 0.25f; wx1 = 0.75f; }
        const float* pb = f2 + ((size_t)b * 64 + cofs) * hhw;
        const int i00 = iy0 * hw + ix0, i01 = iy0 * hw + ix1;
        const int i10 = iy1 * hw + ix0, i11 = iy1 * hw + ix1;
#pragma unroll
        for (int q = 0; q < 4; ++q) {
          u32 r[4];
#pragma unroll
          for (int j = 0; j < 4; ++j) {
            const float* p0 = pb + (size_t)(q * 8 + 2 * j) * hhw;
            const float* p1 = pb + (size_t)(q * 8 + 2 * j + 1) * hhw;
            float v0 = wy0 * (wx0 * p0[i00] + wx1 * p0[i01])
                     + wy1 * (wx0 * p0[i10] + wx1 * p0[i11]);
            float v1 = wy0 * (wx0 * p1[i00] + wx1 * p1[i01])
                     + wy1 * (wx0 * p1[i10] + wx1 * p1[i11]);
            r[j] = pk2bf(v0, v1);
          }
          *(uint4*)&dp[q * 8] = make_uint4(r[0], r[1], r[2], r[3]);
        }
      } else {
#pragma unroll
        for (int q = 0; q < 4; ++q)
          *(uint4*)&dp[q * 8] = make_uint4(0u, 0u, 0u, 0u);
      }
    }
  } else {
    const u16* src; int cofs, cst;
    if (use1) { src = (const u16*)in1v + (size_t)b * HW * c1; cofs = kc << 5; cst = c1; }
    else      { src = (const u16*)in2v + (size_t)b * HW * c2; cofs = (kc - nk1) << 5; cst = c2; }
#pragma unroll 1
    for (int i = tid; i < NPOS * 4; i += TPB) {
      int u = i >> 2, q = i & 3;
      int y = u / 18, x = u - y * 18;
      int gy = by0 - 1 + y, gx = bx0 - 1 + x;
      uint4 v = make_uint4(0u, 0u, 0u, 0u);
      if ((unsigned)gy < (unsigned)Hh && (unsigned)gx < (unsigned)Ww)
        v = *(const uint4*)&src[(size_t)(gy * Ww + gx) * cst + cofs + q * 8];
      *(uint4*)&s_act[u * 40 + q * 8] = v;
    }
  }
}

// ---------------------------------------------------------------------------
// Batch-merged conv core (TH=8, both batches per block, weights staged once).
// NOTE: CJob passed BY VALUE — reference-selecting kernel params spills them
// to scratch (round-21 lesson).
// ---------------------------------------------------------------------------
struct CJob {
  const void* in1; const void* in2; int c1, c2, m1, m2;
  const u16* w; const float* bias;
  float* outf; u16* outb; int outmode, act, Cout, Coutpad, h;
};

__device__ __forceinline__ void conv_core_b2(const CJob j, int cb, u16* s_mem)
{
  u16* s_act = s_mem;             // 2 * 7200
  u16* s_w   = s_mem + 14400;     // 7680
  const int Hh = j.h, Ww = j.h;
  const int xt = Ww >> 4;
  const int by0 = ((int)blockIdx.x / xt) * 8;
  const int bx0 = ((int)blockIdx.x % xt) << 4;
  const int tid = threadIdx.x;
  const int lx = tid & 15, slot = (tid >> 4) & 3, wv = tid >> 6;
  const int c1 = j.c1, c2 = j.c2;
  const int nkc = (c1 + c2) >> 5, nk1 = c1 >> 5;
  const int HW = Hh * Ww;

  f32x4 acc[2][4][2];
#pragma unroll
  for (int b = 0; b < 2; ++b)
#pragma unroll
    for (int i = 0; i < 4; ++i)
#pragma unroll
      for (int g = 0; g < 2; ++g) acc[b][i][g] = (f32x4){0.f, 0.f, 0.f, 0.f};

#pragma unroll 1
  for (int kc = 0; kc < nkc; ++kc) {
    __syncthreads();
    const bool use1 = kc < nk1;
    const int mode = use1 ? j.m1 : j.m2;
    stage_act(s_act,        mode, j.in1, c1, j.in2, c2, use1, kc, nk1, 0, by0, bx0, Hh, Ww, tid);
    stage_act(s_act + 7200, mode, j.in1, c1, j.in2, c2, use1, kc, nk1, 1, by0, bx0, Hh, Ww, tid);
#pragma unroll 1
    for (int ky = 0; ky < 3; ++ky) {
      __syncthreads();
      {
        const size_t base = ((size_t)(kc * 9 + ky * 3) * j.Coutpad + cb) * 40;
        const size_t tapstride = (size_t)j.Coutpad * 40;
#pragma unroll 1
        for (int i = tid; i < 960; i += TPB) {
          int kxl = i / 320, jj = i - kxl * 320;
          const uint4 v = *(const uint4*)&j.w[base + (size_t)kxl * tapstride + jj * 8];
          *(uint4*)&s_w[kxl * 2560 + jj * 8] = v;
        }
      }
      __syncthreads();
#pragma unroll
      for (int kx = 0; kx < 3; ++kx) {
        bf16x8 Af[4];
#pragma unroll
        for (int ct = 0; ct < 4; ++ct)
          Af[ct] = *(const bf16x8*)&s_w[(kx * 64 + ct * 16 + lx) * 40 + slot * 8];
        bf16x8 Bf[2][2];
#pragma unroll
        for (int b = 0; b < 2; ++b)
#pragma unroll
          for (int pg = 0; pg < 2; ++pg)
            Bf[b][pg] = *(const bf16x8*)&s_act[b * 7200 + ((wv * 2 + pg + ky) * 18 + lx + kx) * 40 + slot * 8];
#pragma unroll
        for (int ct = 0; ct < 4; ++ct)
#pragma unroll
          for (int b = 0; b < 2; ++b)
#pragma unroll
            for (int pg = 0; pg < 2; ++pg)
              acc[b][ct][pg] = __builtin_amdgcn_mfma_f32_16x16x32_bf16(Af[ct], Bf[b][pg], acc[b][ct][pg], 0, 0, 0);
      }
    }
  }
  const int ox = bx0 + lx;
  const int jact = j.act;
  if (j.outmode == 1) {
#pragma unroll 1
    for (int b = 0; b < 2; ++b) {
      __syncthreads();
#pragma unroll
      for (int ct = 0; ct < 4; ++ct) {
        const int co0 = ct * 16 + slot * 4;
        const float b0 = j.bias[co0], b1 = j.bias[co0 + 1], b2 = j.bias[co0 + 2], b3 = j.bias[co0 + 3];
#pragma unroll
        for (int pg = 0; pg < 2; ++pg) {
          const int px = (wv * 2 + pg) * 16 + lx;
          *(u32*)&s_mem[px * 72 + co0]     = pk2bf(act_rt(acc[b][ct][pg][0] + b0, jact),
                                                   act_rt(acc[b][ct][pg][1] + b1, jact));
          *(u32*)&s_mem[px * 72 + co0 + 2] = pk2bf(act_rt(acc[b][ct][pg][2] + b2, jact),
                                                   act_rt(acc[b][ct][pg][3] + b3, jact));
        }
      }
      __syncthreads();
#pragma unroll 1
      for (int l = tid; l < 1024; l += TPB) {
        const int px = l >> 3, ch = (l & 7) * 8;
        const int row = px >> 4, col = px & 15;
        const uint4 v = *(const uint4*)&s_mem[px * 72 + ch];
        *(uint4*)&j.outb[(((size_t)b * HW + (size_t)(by0 + row) * Ww + bx0 + col) << 6) + ch] = v;
      }
    }
  } else if (j.outmode == 2) {
#pragma unroll 1
    for (int b = 0; b < 2; ++b) {
#pragma unroll
      for (int ct = 0; ct < 4; ++ct) {
        const int co0 = cb + ct * 16 + slot * 4;
#pragma unroll
        for (int r = 0; r < 4; ++r) {
          const int co = co0 + r;
          if (co < j.Cout) {
            const float bv = j.bias[co];
            u16* op = j.outb + ((size_t)b * j.Cout + co) * HW + (size_t)(by0 + wv * 2) * Ww + ox;
#pragma unroll
            for (int pg = 0; pg < 2; ++pg)
              op[pg * Ww] = f2bf(act_rt(acc[b][ct][pg][r] + bv, jact));
          }
        }
      }
    }
  } else {
#pragma unroll 1
    for (int b = 0; b < 2; ++b) {
#pragma unroll
      for (int ct = 0; ct < 4; ++ct) {
        const int co0 = cb + ct * 16 + slot * 4;
#pragma unroll
        for (int r = 0; r < 4; ++r) {
          const int co = co0 + r;
          if (co < j.Cout) {
            const float bv = j.bias[co];
            float* op = j.outf + ((size_t)b * j.Cout + co) * HW + (size_t)(by0 + wv * 2) * Ww + ox;
#pragma unroll
            for (int pg = 0; pg < 2; ++pg)
              op[pg * Ww] = act_rt(acc[b][ct][pg][r] + bv, jact);
          }
        }
      }
    }
  }
}

__global__ __launch_bounds__(TPB, 3)
void k_conv_b2_1(CJob A)
{
  __shared__ __align__(16) u16 s_mem[22080];
  conv_core_b2(A, (int)blockIdx.y << 6, s_mem);
}

__global__ __launch_bounds__(TPB, 3)
void k_conv_b2_2(CJob A, CJob B, int ny0)
{
  __shared__ __align__(16) u16 s_mem[22080];
  const bool isA = (int)blockIdx.y < ny0;
  const CJob j = isA ? A : B;            // by VALUE
  const int nbx = (j.h >> 3) * (j.h >> 4);
  if ((int)blockIdx.x >= nbx) return;
  const int cb = (isA ? blockIdx.y : blockIdx.y - ny0) << 6;
  conv_core_b2(j, cb, s_mem);
}

__global__ __launch_bounds__(TPB, 3)
void k_conv_b2_tri(CJob A0, CJob B0, CJob A1, CJob B1, CJob A2, CJob B2)
{
  __shared__ __align__(16) u16 s_mem[22080];
  const int lvl = blockIdx.y / 5, sub = blockIdx.y % 5;
  CJob j;                                 // by VALUE selection
  if (lvl == 0)      j = (sub == 0) ? A0 : B0;
  else if (lvl == 1) j = (sub == 0) ? A1 : B1;
  else               j = (sub == 0) ? A2 : B2;
  const int nbx = (j.h >> 3) * (j.h >> 4);
  if ((int)blockIdx.x >= nbx) return;
  const int cb = (sub == 0) ? 0 : ((sub - 1) << 6);
  conv_core_b2(j, cb, s_mem);
}

// ---------------------------------------------------------------------------
// Deformable conv (round-17 structure, unchanged)
// ---------------------------------------------------------------------------
struct DJob {
  const u16* xbf; const u16* off; const u16* mask;
  int maskC, maskBase;
  const float* wgt; const float* bias; float* out;
  int sigm, act;
};

__device__ __forceinline__ void dconv_core(const DJob j, int gs, int Hh, int Ww,
                                           u16 (*s_x)[40], float* s_w, float* s_b)
{
  const int b   = blockIdx.z;
  const int xt  = Ww >> 4;
  const int ty0 = (blockIdx.x / xt) << 3;
  const int tx0 = (blockIdx.x % xt) << 4;
  const int tid = threadIdx.x;
  const int HW  = Hh * Ww;

  for (int i = tid; i < 2304; i += TPB) {
    int o = i & 7, c = (i >> 3) & 7, k = (i >> 6) % 9, gl = i / 576;
    s_w[i] = j.wgt[(((size_t)((gs * 4 + gl) * 8 + o)) * 8 + c) * 9 + k];
  }
  if (tid < 32) s_b[tid] = j.bias[gs * 32 + tid];
  {
    const u16* xb = j.xbf + (size_t)b * HW * 64 + gs * 32;
#pragma unroll 1
    for (int i = tid; i < 960; i += TPB) {
      int px = i >> 2, q = i & 3;
      int r = px / 20, cx = px - r * 20;
      int gy = ty0 - 2 + r, gx = tx0 - 2 + cx;
      uint4 v = make_uint4(0u, 0u, 0u, 0u);
      if ((unsigned)gy < (unsigned)Hh && (unsigned)gx < (unsigned)Ww)
        v = *(const uint4*)&xb[(size_t)(gy * Ww + gx) * 64 + q * 8];
      *(uint4*)&s_x[px][q * 8] = v;
    }
  }
  __syncthreads();

  const int pin = tid & 127;
  const int ghalf = tid >> 7;
  const int py_ = pin >> 4, px_ = pin & 15;
  const int gy = ty0 + py_, gx = tx0 + px_;
  const int p  = gy * Ww + gx;
  const int sigm = j.sigm, act = j.act;

#pragma unroll
  for (int jj = 0; jj < 2; ++jj) {
    const int gl = ghalf * 2 + jj;
    const int g  = gs * 4 + gl;
    const u16* ob = j.off  + ((size_t)b * 216 + g * 18) * HW + p;
    const u16* mb = j.mask + ((size_t)b * j.maskC + j.maskBase + g * 9) * HW + p;
    const u16* xg = j.xbf  + (size_t)b * HW * 64 + g * 8;
    float*     og = j.out  + ((size_t)b * 64 + g * 8) * HW + p;
    const float* wg = &s_w[gl * 9 * 64];

    float acc[8];
#pragma unroll
    for (int o = 0; o < 8; ++o) acc[o] = s_b[gl * 8 + o];

#pragma unroll
    for (int k = 0; k < 9; ++k) {
      const float oyk = bf2f(ob[(size_t)(2 * k) * HW]);
      const float oxk = bf2f(ob[(size_t)(2 * k + 1) * HW]);
      float m = bf2f(mb[(size_t)k * HW]);
      if (sigm) m = 1.f / (1.f + expf(-m));
      const float py = (float)(gy + k / 3 - 1) + oyk;
      const float px = (float)(gx + k % 3 - 1) + oxk;
      const float y0f = floorf(py), x0f = floorf(px);
      const float fy = py - y0f, fx = px - x0f;
      const int y0 = (int)y0f, x0 = (int)x0f;
      const int y1 = y0 + 1, x1 = x0 + 1;
      const float vy0 = (y0 >= 0 && y0 < Hh) ? 1.f : 0.f;
      const float vy1 = (y1 >= 0 && y1 < Hh) ? 1.f : 0.f;
      const float vx0 = (x0 >= 0 && x0 < Ww) ? 1.f : 0.f;
      const float vx1 = (x1 >= 0 && x1 < Ww) ? 1.f : 0.f;
      const float w00 = (1.f - fy) * (1.f - fx) * vy0 * vx0 * m;
      const float w01 = (1.f - fy) * fx * vy0 * vx1 * m;
      const float w10 = fy * (1.f - fx) * vy1 * vx0 * m;
      const float w11 = fy * fx * vy1 * vx1 * m;
      const float* wk = &wg[k * 64];
      const int ly = y0 - ty0 + 2, lxw = x0 - tx0 + 2;
      if ((unsigned)ly < 11u && (unsigned)lxw < 19u) {
        const u16* base = &s_x[ly * 20 + lxw][gl * 8];
        const bf16x8 c00 = *(const bf16x8*)base;
        const bf16x8 c01 = *(const bf16x8*)(base + 40);
        const bf16x8 c10 = *(const bf16x8*)(base + 800);
        const bf16x8 c11 = *(const bf16x8*)(base + 840);
#pragma unroll
        for (int c = 0; c < 8; ++c) {
          const float s = w00 * (float)c00[c] + w01 * (float)c01[c]
                        + w10 * (float)c10[c] + w11 * (float)c11[c];
          const float4 wv0 = *(const float4*)&wk[c * 8];
          const float4 wv1 = *(const float4*)&wk[c * 8 + 4];
          acc[0] = fmaf(s, wv0.x, acc[0]); acc[1] = fmaf(s, wv0.y, acc[1]);
          acc[2] = fmaf(s, wv0.z, acc[2]); acc[3] = fmaf(s, wv0.w, acc[3]);
          acc[4] = fmaf(s, wv1.x, acc[4]); acc[5] = fmaf(s, wv1.y, acc[5]);
          acc[6] = fmaf(s, wv1.z, acc[6]); acc[7] = fmaf(s, wv1.w, acc[7]);
        }
      } else {
        const int cy0 = min(max(y0, 0), Hh - 1), cy1 = min(max(y1, 0), Hh - 1);
        const int cx0 = min(max(x0, 0), Ww - 1), cx1 = min(max(x1, 0), Ww - 1);
        const int i00 = (cy0 * Ww + cx0) * 64, i01 = (cy0 * Ww + cx1) * 64;
        const int i10 = (cy1 * Ww + cx0) * 64, i11 = (cy1 * Ww + cx1) * 64;
#pragma unroll
        for (int c = 0; c < 8; ++c) {
          const float s = w00 * bf2f(xg[i00 + c]) + w01 * bf2f(xg[i01 + c])
                        + w10 * bf2f(xg[i10 + c]) + w11 * bf2f(xg[i11 + c]);
          const float4 wv0 = *(const float4*)&wk[c * 8];
          const float4 wv1 = *(const float4*)&wk[c * 8 + 4];
          acc[0] = fmaf(s, wv0.x, acc[0]); acc[1] = fmaf(s, wv0.y, acc[1]);
          acc[2] = fmaf(s, wv0.z, acc[2]); acc[3] = fmaf(s, wv0.w, acc[3]);
          acc[4] = fmaf(s, wv1.x, acc[4]); acc[5] = fmaf(s, wv1.y, acc[5]);
          acc[6] = fmaf(s, wv1.z, acc[6]); acc[7] = fmaf(s, wv1.w, acc[7]);
        }
      }
    }
#pragma unroll
    for (int o = 0; o < 8; ++o) {
      float v = acc[o];
      if (act) v = v >= 0.f ? v : 0.1f * v;
      og[(size_t)o * HW] = v;
    }
  }
}

__global__ __launch_bounds__(TPB, 4)
void k_dconv_one(DJob j, int Hh, int Ww)
{
  __shared__ __align__(16) u16 s_x[240][40];
  __shared__ __align__(16) float s_w[4 * 9 * 64];
  __shared__ float s_b[32];
  dconv_core(j, blockIdx.y, Hh, Ww, s_x, s_w, s_b);
}

__global__ __launch_bounds__(TPB, 4)
void k_dconv_dual(DJob a, DJob b, int Hh, int Ww)
{
  __shared__ __align__(16) u16 s_x[240][40];
  __shared__ __align__(16) float s_w[4 * 9 * 64];
  __shared__ float s_b[32];
  const DJob j = (blockIdx.y & 1) ? b : a;   // by VALUE
  dconv_core(j, blockIdx.y >> 1, Hh, Ww, s_x, s_w, s_b);
}

// ---------------------------------------------------------------------------
// host helpers
// ---------------------------------------------------------------------------
static CJob mkcjob(const void* i1, const void* i2, int c1, int c2, int m1, int m2,
                   const u16* w, const float* bias, float* outf, u16* outb,
                   int outmode, int act, int Cout, int h)
{
  CJob j; j.in1 = i1; j.in2 = i2; j.c1 = c1; j.c2 = c2; j.m1 = m1; j.m2 = m2;
  j.w = w; j.bias = bias; j.outf = outf; j.outb = outb; j.outmode = outmode;
  j.act = act; j.Cout = Cout; j.Coutpad = ((Cout + 63) / 64) * 64; j.h = h;
  return j;
}

static void conv1(hipStream_t st, CJob a)
{
  dim3 grid((a.h / 8) * (a.h / 16), a.Coutpad / 64, 1);
  k_conv_b2_1<<<grid, TPB, 0, st>>>(a);
}

static void conv2(hipStream_t st, CJob a, CJob b)
{
  int ny0 = a.Coutpad / 64, ny1 = b.Coutpad / 64;
  int nbx0 = (a.h / 8) * (a.h / 16), nbx1 = (b.h / 8) * (b.h / 16);
  dim3 grid(max(nbx0, nbx1), ny0 + ny1, 1);
  k_conv_b2_2<<<grid, TPB, 0, st>>>(a, b, ny0);
}

static DJob mkdjob(const u16* xbf, const u16* off, const u16* mask, int maskC, int maskBase,
                   const float* w, const float* b, float* out, int sigm, int act)
{
  DJob j; j.xbf = xbf; j.off = off; j.mask = mask; j.maskC = maskC; j.maskBase = maskBase;
  j.wgt = w; j.bias = b; j.out = out; j.sigm = sigm; j.act = act;
  return j;
}

static void dconv_dual(hipStream_t st, DJob a, DJob b, int h, int wd)
{
  dim3 grid((h / 8) * (wd / 16), 4, 2);
  k_dconv_dual<<<grid, TPB, 0, st>>>(a, b, h, wd);
}

static void dconv_one(hipStream_t st, DJob a, int h, int wd)
{
  dim3 grid((h / 8) * (wd / 16), 2, 2);
  k_dconv_one<<<grid, TPB, 0, st>>>(a, h, wd);
}

extern "C" void kernel_launch(void* const* d_in, const int* in_sizes, int n_in,
                              void* d_out, int out_size, void* d_ws, size_t ws_size,
                              hipStream_t stream)
{
  const float* const* in = (const float* const*)d_in;

  const int HW0 = 192 * 192, HW1 = 96 * 96, HW2 = 48 * 48;
  const size_t N0 = (size_t)2 * HW0 * 64, N1 = (size_t)2 * HW1 * 64, N2 = (size_t)2 * HW2 * 64;

  // ---- workspace layout ----
  u16* p = (u16*)d_ws;
  u16* nrf0b = p; p += N0;
  u16* rf0b  = p; p += N0;
  u16* swf0b = p; p += N0;
  u16* nrf1b = p; p += N1;
  u16* rf1b  = p; p += N1;
  u16* swf1b = p; p += N1;
  u16* nrf2b = p; p += N2;
  u16* rf2b  = p; p += N2;
  u16* swf2b = p; p += N2;
  u16* A0bf  = p; p += N0;
  u16* A1bf  = p; p += N1;
  u16* A2bf  = p; p += N2;
  u16* OM0   = p; p += (size_t)2 * 216 * HW0;
  u16* OM1   = p; p += (size_t)2 * 216 * HW1;
  u16* OM2   = p; p += (size_t)2 * 216 * HW2;
  u16* EM    = p; p += (size_t)2 * 72 * HW0;
  u16* OF0bf = p; p += N0;
  u16* DN0bf = p; p += N0;
  p = (u16*)(((uintptr_t)p + 15) & ~(uintptr_t)15);
  float* XD   = (float*)p;
  float* DN1  = XD + (size_t)2 * 64 * HW0;
  u16* wp = (u16*)(DN1 + (size_t)2 * 64 * HW1);

  float* dout = (float*)d_out;
  const size_t L0 = (size_t)2 * 64 * HW0;
  float* out0 = dout;
  float* sh0  = dout + L0;
  float* sh1  = sh0  + L0;
  float* sh2  = sh1  + L0 / 4;
  // d_out dead-region aliases:
  u16*   Bbf   = (u16*)out0;                                 // overwritten by final dconv
  u16*   OF1bf = (u16*)sh0;                                  // dead before dual0 writes sh0
  u16*   OF2bf = OF1bf + N1;
  float* DN2   = (float*)(OF2bf + N2);

  // ---- input conversion ----
  {
    ToBfArgs ta;
    const float* srcs[9] = {in[0], in[1], in[2], in[3], in[4], in[5], in[6], in[7], in[8]};
    u16* dsts[9] = {nrf0b, rf0b, swf0b, nrf1b, rf1b, swf1b, nrf2b, rf2b, swf2b};
    const int hws[9] = {HW0, HW0, HW0, HW1, HW1, HW1, HW2, HW2, HW2};
    for (int i = 0; i < 9; ++i) { ta.src[i] = srcs[i]; ta.dst[i] = dsts[i]; ta.hw[i] = hws[i]; }
    int maxtot = 2 * HW0 * 8;
    k_tobf_all<<<dim3((maxtot + TPB - 1) / TPB, 9), TPB, 0, stream>>>(ta);
  }

  // ---- weight prep ----
  struct { int arg, cin, cout; } plist[22] = {
    {9,128,64},{11,64,64},{13,64,216},{15,128,64},{17,64,72},
    {21,128,64},{23,64,64},{25,64,216},{27,128,64},{29,64,72},
    {33,128,64},{35,64,64},{37,64,216},{39,128,64},{41,64,72},
    {45,128,64},{47,128,64},{49,128,64},{51,128,64},
    {53,128,64},{55,64,64},{57,64,216}};
  WPrepArgs wa;
  u16* wptr[22];
  int maxtot = 0;
  for (int i = 0; i < 22; ++i) {
    int cin = plist[i].cin, cout = plist[i].cout;
    int cpad = ((cout + 63) / 64) * 64;
    int tot = (cin / 32) * 9 * cpad * 40;
    wa.src[i] = in[plist[i].arg]; wa.dst[i] = wp;
    wa.cin[i] = cin; wa.cout[i] = cout; wa.coutpad[i] = cpad; wa.total[i] = tot;
    wptr[i] = wp; wp += tot;
    if (tot > maxtot) maxtot = tot;
  }
  k_wprep_all<<<dim3((maxtot + TPB - 1) / TPB, 22), TPB, 0, stream>>>(wa);

  u16* w_ocf0 = wptr[0];  u16* w_ocl0 = wptr[1];  u16* w_com0 = wptr[2];
  u16* w_em10 = wptr[3];  u16* w_em20 = wptr[4];
  u16* w_ocf1 = wptr[5];  u16* w_ocl1 = wptr[6];  u16* w_com1 = wptr[7];
  u16* w_em11 = wptr[8];  u16* w_em21 = wptr[9];
  u16* w_ocf2 = wptr[10]; u16* w_ocl2 = wptr[11]; u16* w_com2 = wptr[12];
  u16* w_em12 = wptr[13]; u16* w_em22 = wptr[14];
  u16* w_occ0 = wptr[15]; u16* w_fcc0 = wptr[16];
  u16* w_occ1 = wptr[17]; u16* w_fcc1 = wptr[18];
  u16* w_cas1 = wptr[19]; u16* w_cas2 = wptr[20]; u16* w_casc = wptr[21];

  const int h2 = 48, h1 = 96, h0 = 192;

  // ---- tri-level mega-pair (b2): all ocf_i + com_i ----
  {
    CJob a0 = mkcjob(nrf0b, rf0b,  64, 64, 1, 1, w_ocf0, in[10], nullptr, A0bf, 1, 1, 64,  h0);
    CJob b0 = mkcjob(swf0b, nullptr,64, 0, 1, 1, w_com0, in[14], nullptr, OM0,  2, 0, 216, h0);
    CJob a1 = mkcjob(nrf1b, rf1b,  64, 64, 1, 1, w_ocf1, in[22], nullptr, A1bf, 1, 1, 64,  h1);
    CJob b1 = mkcjob(swf1b, nullptr,64, 0, 1, 1, w_com1, in[26], nullptr, OM1,  2, 0, 216, h1);
    CJob a2 = mkcjob(nrf2b, rf2b,  64, 64, 1, 1, w_ocf2, in[34], nullptr, A2bf, 1, 1, 64,  h2);
    CJob b2 = mkcjob(swf2b, nullptr,64, 0, 1, 1, w_com2, in[38], nullptr, OM2,  2, 0, 216, h2);
    dim3 grid(288, 15, 1);
    k_conv_b2_tri<<<grid, TPB, 0, stream>>>(a0, b0, a1, b1, a2, b2);
  }

  // ocl2 (48²)
  conv1(stream, mkcjob(A2bf, nullptr, 64, 0, 1, 1, w_ocl2, in[36], nullptr, OF2bf, 1, 1, 64, h2));
  // p1: em12(48) + occ1(96, fused chlast up2)
  conv2(stream,
    mkcjob(OF2bf, swf2b, 64, 64, 1, 1, w_em12, in[40], nullptr, A2bf, 1, 1, 64, h2),
    mkcjob(A1bf,  OF2bf, 64, 64, 1, 3, w_occ1, in[50], nullptr, Bbf,  1, 1, 64, h1));
  // p2: em22(48, sigmoid->EM planar) + ocl1(96)
  conv2(stream,
    mkcjob(A2bf, nullptr, 64, 0, 1, 1, w_em22, in[42], nullptr, EM,    2, 2, 72, h2),
    mkcjob(Bbf,  nullptr, 64, 0, 1, 1, w_ocl1, in[24], nullptr, OF1bf, 1, 1, 64, h1));
  // dual2: sh2 + xd2
  dconv_dual(stream,
             mkdjob(OF2bf, OM2, EM,  72, 0,   in[43], in[44], sh2, 0, 0),
             mkdjob(nrf2b, OM2, OM2, 216, 144, in[43], in[44], DN2, 1, 1), h2, h2);
  // p3: em11(96) + occ0(192, fused chlast up2)
  conv2(stream,
    mkcjob(OF1bf, swf1b, 64, 64, 1, 1, w_em11, in[28], nullptr, A1bf, 1, 1, 64, h1),
    mkcjob(A0bf,  OF1bf, 64, 64, 1, 3, w_occ0, in[46], nullptr, Bbf,  1, 1, 64, h0));
  // p4: em21(96, sigmoid->EM) + ocl0(192)
  conv2(stream,
    mkcjob(A1bf, nullptr, 64, 0, 1, 1, w_em21, in[30], nullptr, EM,    2, 2, 72, h1),
    mkcjob(Bbf,  nullptr, 64, 0, 1, 1, w_ocl0, in[12], nullptr, OF0bf, 1, 1, 64, h0));
  // dual1: sh1 + xd1
  dconv_dual(stream,
             mkdjob(OF1bf, OM1, EM,  72, 0,   in[31], in[32], sh1, 0, 0),
             mkdjob(nrf1b, OM1, OM1, 216, 144, in[31], in[32], XD, 1, 0), h1, h1);
  // p5: em10(192) + fcc1(96, fp32 + fp32-up2 -> fp32)
  conv2(stream,
    mkcjob(OF0bf, swf0b, 64, 64, 1, 1, w_em10, in[16], nullptr, Bbf, 1, 1, 64, h0),
    mkcjob(XD,    DN2,   64, 64, 0, 4, w_fcc1, in[52], DN1, nullptr, 0, 1, 64, h1));
  // em20 (192, sigmoid->EM)
  conv1(stream, mkcjob(Bbf, nullptr, 64, 0, 1, 1, w_em20, in[18], nullptr, EM, 2, 2, 72, h0));
  // dual0: sh0 + xd0
  dconv_dual(stream,
             mkdjob(OF0bf, OM0, EM,  72, 0,   in[19], in[20], sh0, 0, 0),
             mkdjob(nrf0b, OM0, OM0, 216, 144, in[19], in[20], XD, 1, 0), h0, h0);
  // fcc0 (fp32 + fp32-up2 -> chlast)
  conv1(stream, mkcjob(XD, DN1, 64, 64, 0, 4, w_fcc0, in[48], nullptr, DN0bf, 1, 0, 64, h0));
  // cascade
  conv1(stream, mkcjob(DN0bf, rf0b, 64, 64, 1, 1, w_cas1, in[54], nullptr, A0bf, 1, 1, 64, h0));
  conv1(stream, mkcjob(A0bf, nullptr, 64, 0, 1, 1, w_cas2, in[56], nullptr, Bbf, 1, 1, 64, h0));
  conv1(stream, mkcjob(Bbf, nullptr, 64, 0, 1, 1, w_casc, in[58], nullptr, OM0, 2, 0, 216, h0));
  dconv_one(stream,
            mkdjob(DN0bf, OM0, OM0, 216, 144, in[59], in[60], out0, 1, 1), h0, h0);
}

// Round 23
// 730.926 us; speedup vs baseline: 2.2974x; 1.8400x over previous
//
#include <hip/hip_runtime.h>
#include <cstddef>
#include <cstdint>

#define TPB 256

typedef unsigned int u32;
typedef unsigned short u16;
typedef __bf16 bf16x8 __attribute__((ext_vector_type(8)));
typedef float f32x4 __attribute__((ext_vector_type(4)));

__device__ __forceinline__ float act_rt(float v, int a) {
  if (a == 1) return v >= 0.f ? v : 0.1f * v;
  if (a == 2) return 1.f / (1.f + expf(-v));
  return v;
}

__device__ __forceinline__ u16 f2bf(float f) {
  __bf16 h = (__bf16)f;
  return __builtin_bit_cast(u16, h);
}
__device__ __forceinline__ float bf2f(u16 h) {
  return __uint_as_float(((u32)h) << 16);
}
__device__ __forceinline__ u32 pk2bf(float a, float b) {
  return (u32)f2bf(a) | ((u32)f2bf(b) << 16);
}

// ---------------------------------------------------------------------------
// Weight prep (one launch, 22 convs)
// ---------------------------------------------------------------------------
struct WPrepArgs {
  const float* src[22];
  u16* dst[22];
  int cin[22], cout[22], coutpad[22], total[22];
};

__global__ void k_wprep_all(WPrepArgs a)
{
  const int seg = blockIdx.y;
  const int idx = blockIdx.x * TPB + threadIdx.x;
  if (idx >= a.total[seg]) return;
  const int Cin = a.cin[seg], Cout = a.cout[seg], Coutpad = a.coutpad[seg];
  int kk = idx % 40; int t = idx / 40;
  int co = t % Coutpad; t /= Coutpad;
  int tap = t % 9; int kc = t / 9;
  u16 v = 0;
  if (kk < 32 && co < Cout)
    v = f2bf(a.src[seg][((size_t)co * Cin + kc * 32 + kk) * 9 + tap]);
  a.dst[seg][idx] = v;
}

// ---------------------------------------------------------------------------
// Input prep
// ---------------------------------------------------------------------------
struct ToBfArgs {
  const float* src[9];
  u16* dst[9];
  int hw[9];
};

__global__ void k_tobf_all(ToBfArgs a)
{
  const int seg = blockIdx.y;
  const int hw = a.hw[seg];
  const int total = 2 * hw * 8;
  int idx = blockIdx.x * TPB + threadIdx.x;
  if (idx >= total) return;
  const int g8 = idx & 7;
  int t = idx >> 3;
  const int pos = t % hw, b = t / hw;
  const float* s = a.src[seg] + ((size_t)b * 64 + g8 * 8) * hw + pos;
  u32 w0 = pk2bf(s[0], s[(size_t)hw]);
  u32 w1 = pk2bf(s[(size_t)2 * hw], s[(size_t)3 * hw]);
  u32 w2 = pk2bf(s[(size_t)4 * hw], s[(size_t)5 * hw]);
  u32 w3 = pk2bf(s[(size_t)6 * hw], s[(size_t)7 * hw]);
  *(uint4*)&a.dst[seg][((size_t)b * hw + pos) * 64 + g8 * 8] = make_uint4(w0, w1, w2, w3);
}

// ---------------------------------------------------------------------------
// Staging helper (NPOS=180 fixed). modes: 0 fp32 planar | 1 chlast |
// 3 chlast half-res up2 | 4 fp32 planar half-res up2
// ---------------------------------------------------------------------------
__device__ __forceinline__ void stage_act(u16* s_act, int mode,
                                          const void* in1v, int c1,
                                          const void* in2v, int c2,
                                          bool use1, int kc, int nk1,
                                          int b, int by0, int bx0, int Hh, int Ww, int tid)
{
  constexpr int NPOS = 180;
  const int HW = Hh * Ww;
  if (mode == 0) {
    const float* sp = use1
      ? (const float*)in1v + ((size_t)b * c1 + (kc << 5)) * HW
      : (const float*)in2v + ((size_t)b * c2 + ((kc - nk1) << 5)) * HW;
#pragma unroll 1
    for (int u = tid; u < NPOS; u += TPB) {
      int y = u / 18, x = u - y * 18;
      int gy = by0 - 1 + y, gx = bx0 - 1 + x;
      bool inb = ((unsigned)gy < (unsigned)Hh) & ((unsigned)gx < (unsigned)Ww);
      const float msk = inb ? 1.f : 0.f;
      const size_t poff = inb ? ((size_t)gy * Ww + gx) : 0;
      const float* s0 = sp + poff;
      u16* dp = &s_act[u * 40];
#pragma unroll
      for (int c8 = 0; c8 < 4; ++c8) {
        u32 hb[4];
#pragma unroll
        for (int j = 0; j < 4; ++j)
          hb[j] = pk2bf(s0[(size_t)(c8 * 8 + 2 * j) * HW] * msk,
                        s0[(size_t)(c8 * 8 + 2 * j + 1) * HW] * msk);
        *(uint4*)&dp[c8 * 8] = make_uint4(hb[0], hb[1], hb[2], hb[3]);
      }
    }
  } else if (mode == 3) {
    const u16* b2 = (const u16*)in2v;
    const int hh = Hh >> 1, hw = Ww >> 1;
    const int cofs = (kc - nk1) << 5;
#pragma unroll 1
    for (int u = tid; u < NPOS; u += TPB) {
      int y = u / 18, x = u - y * 18;
      int gy = by0 - 1 + y, gx = bx0 - 1 + x;
      u16* dp = &s_act[u * 40];
      if ((unsigned)gy < (unsigned)Hh && (unsigned)gx < (unsigned)Ww) {
        int iy0, iy1, ix0, ix1; float wy0, wy1, wx0, wx1;
        if (gy & 1) { iy0 = gy >> 1; iy1 = min(iy0 + 1, hh - 1); wy0 = 0.75f; wy1 = 0.25f; }
        else        { iy1 = gy >> 1; iy0 = max(iy1 - 1, 0);      wy0 = 0.25f; wy1 = 0.75f; }
        if (gx & 1) { ix0 = gx >> 1; ix1 = min(ix0 + 1, hw - 1); wx0 = 0.75f; wx1 = 0.25f; }
        else        { ix1 = gx >> 1; ix0 = max(ix1 - 1, 0);      wx0 = 0.25f; wx1 = 0.75f; }
        const u16* pb = b2 + (size_t)b * hh * hw * 64 + cofs;
#pragma unroll
        for (int q = 0; q < 4; ++q) {
          const bf16x8 a00 = *(const bf16x8*)&pb[(size_t)(iy0 * hw + ix0) * 64 + q * 8];
          const bf16x8 a01 = *(const bf16x8*)&pb[(size_t)(iy0 * hw + ix1) * 64 + q * 8];
          const bf16x8 a10 = *(const bf16x8*)&pb[(size_t)(iy1 * hw + ix0) * 64 + q * 8];
          const bf16x8 a11 = *(const bf16x8*)&pb[(size_t)(iy1 * hw + ix1) * 64 + q * 8];
          u32 r[4];
#pragma unroll
          for (int j = 0; j < 4; ++j) {
            float v0 = wy0 * (wx0 * (float)a00[2 * j] + wx1 * (float)a01[2 * j])
                     + wy1 * (wx0 * (float)a10[2 * j] + wx1 * (float)a11[2 * j]);
            float v1 = wy0 * (wx0 * (float)a00[2 * j + 1] + wx1 * (float)a01[2 * j + 1])
                     + wy1 * (wx0 * (float)a10[2 * j + 1] + wx1 * (float)a11[2 * j + 1]);
            r[j] = pk2bf(v0, v1);
          }
          *(uint4*)&dp[q * 8] = make_uint4(r[0], r[1], r[2], r[3]);
        }
      } else {
#pragma unroll
        for (int q = 0; q < 4; ++q)
          *(uint4*)&dp[q * 8] = make_uint4(0u, 0u, 0u, 0u);
      }
    }
  } else if (mode == 4) {
    const float* f2 = (const float*)in2v;
    const int hh = Hh >> 1, hw = Ww >> 1;
    const int cofs = (kc - nk1) << 5;
    const int hhw = hh * hw;
#pragma unroll 1
    for (int u = tid; u < NPOS; u += TPB) {
      int y = u / 18, x = u - y * 18;
      int gy = by0 - 1 + y, gx = bx0 - 1 + x;
      u16* dp = &s_act[u * 40];
      if ((unsigned)gy < (unsigned)Hh && (unsigned)gx < (unsigned)Ww) {
        int iy0, iy1, ix0, ix1; float wy0, wy1, wx0, wx1;
        if (gy & 1) { iy0 = gy >> 1; iy1 = min(iy0 + 1, hh - 1); wy0 = 0.75f; wy1 = 0.25f; }
        else        { iy1 = gy >> 1; iy0 = max(iy1 - 1, 0);      wy0 = 0.25f; wy1 = 0.75f; }
        if (gx & 1) { ix0 = gx >> 1; ix1 = min(ix0 + 1, hw - 1); wx0 = 0.75f; wx1 = 0.25f; }
        else        { ix1 = gx >> 1; ix0 = max(ix1 - 1, 0);      wx0 = 0.25f; wx1 = 0.75f; }
        const float* pb = f2 + ((size_t)b * 64 + cofs) * hhw;
        const int i00 = iy0 * hw + ix0, i01 = iy0 * hw + ix1;
        const int i10 = iy1 * hw + ix0, i11 = iy1 * hw + ix1;
#pragma unroll
        for (int q = 0; q < 4; ++q) {
          u32 r[4];
#pragma unroll
          for (int j = 0; j < 4; ++j) {
            const float* p0 = pb + (size_t)(q * 8 + 2 * j) * hhw;
            const float* p1 = pb + (size_t)(q * 8 + 2 * j + 1) * hhw;
            float v0 = wy0 * (wx0 * p0[i00] + wx1 * p0[i01])
                     + wy1 * (wx0 * p0[i10] + wx1 * p0[i11]);
            float v1 = wy0 * (wx0 * p1[i00] + wx1 * p1[i01])
                     + wy1 * (wx0 * p1[i10] + wx1 * p1[i11]);
            r[j] = pk2bf(v0, v1);
          }
          *(uint4*)&dp[q * 8] = make_uint4(r[0], r[1], r[2], r[3]);
        }
      } else {
#pragma unroll
        for (int q = 0; q < 4; ++q)
          *(uint4*)&dp[q * 8] = make_uint4(0u, 0u, 0u, 0u);
      }
    }
  } else {
    const u16* src; int cofs, cst;
    if (use1) { src = (const u16*)in1v + (size_t)b * HW * c1; cofs = kc << 5; cst = c1; }
    else      { src = (const u16*)in2v + (size_t)b * HW * c2; cofs = (kc - nk1) << 5; cst = c2; }
#pragma unroll 1
    for (int i = tid; i < NPOS * 4; i += TPB) {
      int u = i >> 2, q = i & 3;
      int y = u / 18, x = u - y * 18;
      int gy = by0 - 1 + y, gx = bx0 - 1 + x;
      uint4 v = make_uint4(0u, 0u, 0u, 0u);
      if ((unsigned)gy < (unsigned)Hh && (unsigned)gx < (unsigned)Ww)
        v = *(const uint4*)&src[(size_t)(gy * Ww + gx) * cst + cofs + q * 8];
      *(uint4*)&s_act[u * 40 + q * 8] = v;
    }
  }
}

// ---------------------------------------------------------------------------
// Batch-merged conv core (TH=8, both batches per block, weights staged once).
// All acc accesses STATICALLY indexed (epilogue b-loops fully unrolled —
// round-22 lesson: runtime-indexed acc => scratch).
// ---------------------------------------------------------------------------
struct CJob {
  const void* in1; const void* in2; int c1, c2, m1, m2;
  const u16* w; const float* bias;
  float* outf; u16* outb; int outmode, act, Cout, Coutpad, h;
};

__device__ __forceinline__ void conv_core_b2(const CJob j, int cb, u16* s_mem)
{
  u16* s_act = s_mem;             // 2 * 7200
  u16* s_w   = s_mem + 14400;     // 7680
  const int Hh = j.h, Ww = j.h;
  const int xt = Ww >> 4;
  const int by0 = ((int)blockIdx.x / xt) * 8;
  const int bx0 = ((int)blockIdx.x % xt) << 4;
  const int tid = threadIdx.x;
  const int lx = tid & 15, slot = (tid >> 4) & 3, wv = tid >> 6;
  const int c1 = j.c1, c2 = j.c2;
  const int nkc = (c1 + c2) >> 5, nk1 = c1 >> 5;
  const int HW = Hh * Ww;

  f32x4 acc[2][4][2];
#pragma unroll
  for (int b = 0; b < 2; ++b)
#pragma unroll
    for (int i = 0; i < 4; ++i)
#pragma unroll
      for (int g = 0; g < 2; ++g) acc[b][i][g] = (f32x4){0.f, 0.f, 0.f, 0.f};

#pragma unroll 1
  for (int kc = 0; kc < nkc; ++kc) {
    __syncthreads();
    const bool use1 = kc < nk1;
    const int mode = use1 ? j.m1 : j.m2;
    stage_act(s_act,        mode, j.in1, c1, j.in2, c2, use1, kc, nk1, 0, by0, bx0, Hh, Ww, tid);
    stage_act(s_act + 7200, mode, j.in1, c1, j.in2, c2, use1, kc, nk1, 1, by0, bx0, Hh, Ww, tid);
#pragma unroll 1
    for (int ky = 0; ky < 3; ++ky) {
      __syncthreads();
      {
        const size_t base = ((size_t)(kc * 9 + ky * 3) * j.Coutpad + cb) * 40;
        const size_t tapstride = (size_t)j.Coutpad * 40;
#pragma unroll 1
        for (int i = tid; i < 960; i += TPB) {
          int kxl = i / 320, jj = i - kxl * 320;
          const uint4 v = *(const uint4*)&j.w[base + (size_t)kxl * tapstride + jj * 8];
          *(uint4*)&s_w[kxl * 2560 + jj * 8] = v;
        }
      }
      __syncthreads();
#pragma unroll
      for (int kx = 0; kx < 3; ++kx) {
        bf16x8 Af[4];
#pragma unroll
        for (int ct = 0; ct < 4; ++ct)
          Af[ct] = *(const bf16x8*)&s_w[(kx * 64 + ct * 16 + lx) * 40 + slot * 8];
        bf16x8 Bf[2][2];
#pragma unroll
        for (int b = 0; b < 2; ++b)
#pragma unroll
          for (int pg = 0; pg < 2; ++pg)
            Bf[b][pg] = *(const bf16x8*)&s_act[b * 7200 + ((wv * 2 + pg + ky) * 18 + lx + kx) * 40 + slot * 8];
#pragma unroll
        for (int ct = 0; ct < 4; ++ct)
#pragma unroll
          for (int b = 0; b < 2; ++b)
#pragma unroll
            for (int pg = 0; pg < 2; ++pg)
              acc[b][ct][pg] = __builtin_amdgcn_mfma_f32_16x16x32_bf16(Af[ct], Bf[b][pg], acc[b][ct][pg], 0, 0, 0);
      }
    }
  }
  const int ox = bx0 + lx;
  const int jact = j.act;
  if (j.outmode == 1) {
#pragma unroll
    for (int b = 0; b < 2; ++b) {          // UNROLLED: static acc indexing
      __syncthreads();
#pragma unroll
      for (int ct = 0; ct < 4; ++ct) {
        const int co0 = ct * 16 + slot * 4;
        const float b0 = j.bias[co0], b1 = j.bias[co0 + 1], b2 = j.bias[co0 + 2], b3 = j.bias[co0 + 3];
#pragma unroll
        for (int pg = 0; pg < 2; ++pg) {
          const int px = (wv * 2 + pg) * 16 + lx;
          *(u32*)&s_mem[px * 72 + co0]     = pk2bf(act_rt(acc[b][ct][pg][0] + b0, jact),
                                                   act_rt(acc[b][ct][pg][1] + b1, jact));
          *(u32*)&s_mem[px * 72 + co0 + 2] = pk2bf(act_rt(acc[b][ct][pg][2] + b2, jact),
                                                   act_rt(acc[b][ct][pg][3] + b3, jact));
        }
      }
      __syncthreads();
#pragma unroll 1
      for (int l = tid; l < 1024; l += TPB) {
        const int px = l >> 3, ch = (l & 7) * 8;
        const int row = px >> 4, col = px & 15;
        const uint4 v = *(const uint4*)&s_mem[px * 72 + ch];
        *(uint4*)&j.outb[(((size_t)b * HW + (size_t)(by0 + row) * Ww + bx0 + col) << 6) + ch] = v;
      }
    }
  } else if (j.outmode == 2) {
#pragma unroll
    for (int b = 0; b < 2; ++b) {          // UNROLLED
#pragma unroll
      for (int ct = 0; ct < 4; ++ct) {
        const int co0 = cb + ct * 16 + slot * 4;
#pragma unroll
        for (int r = 0; r < 4; ++r) {
          const int co = co0 + r;
          if (co < j.Cout) {
            const float bv = j.bias[co];
            u16* op = j.outb + ((size_t)b * j.Cout + co) * HW + (size_t)(by0 + wv * 2) * Ww + ox;
#pragma unroll
            for (int pg = 0; pg < 2; ++pg)
              op[pg * Ww] = f2bf(act_rt(acc[b][ct][pg][r] + bv, jact));
          }
        }
      }
    }
  } else {
#pragma unroll
    for (int b = 0; b < 2; ++b) {          // UNROLLED
#pragma unroll
      for (int ct = 0; ct < 4; ++ct) {
        const int co0 = cb + ct * 16 + slot * 4;
#pragma unroll
        for (int r = 0; r < 4; ++r) {
          const int co = co0 + r;
          if (co < j.Cout) {
            const float bv = j.bias[co];
            float* op = j.outf + ((size_t)b * j.Cout + co) * HW + (size_t)(by0 + wv * 2) * Ww + ox;
#pragma unroll
            for (int pg = 0; pg < 2; ++pg)
              op[pg * Ww] = act_rt(acc[b][ct][pg][r] + bv, jact);
          }
        }
      }
    }
  }
}

__global__ __launch_bounds__(TPB, 3)
void k_conv_b2_1(CJob A)
{
  __shared__ __align__(16) u16 s_mem[22080];
  conv_core_b2(A, (int)blockIdx.y << 6, s_mem);
}

__global__ __launch_bounds__(TPB, 3)
void k_conv_b2_2(CJob A, CJob B, int ny0)
{
  __shared__ __align__(16) u16 s_mem[22080];
  const bool isA = (int)blockIdx.y < ny0;
  const CJob j = isA ? A : B;            // by-value init (round-19 proven form)
  const int nbx = (j.h >> 3) * (j.h >> 4);
  if ((int)blockIdx.x >= nbx) return;
  const int cb = (isA ? blockIdx.y : blockIdx.y - ny0) << 6;
  conv_core_b2(j, cb, s_mem);
}

__global__ __launch_bounds__(TPB, 3)
void k_conv_b2_tri(CJob A0, CJob B0, CJob A1, CJob B1, CJob A2, CJob B2)
{
  __shared__ __align__(16) u16 s_mem[22080];
  const int lvl = blockIdx.y / 5, sub = blockIdx.y % 5;
  const CJob j = (lvl == 0) ? (sub == 0 ? A0 : B0)
               : (lvl == 1) ? (sub == 0 ? A1 : B1)
                            : (sub == 0 ? A2 : B2);   // nested-ternary init (round-19/20 proven)
  const int nbx = (j.h >> 3) * (j.h >> 4);
  if ((int)blockIdx.x >= nbx) return;
  const int cb = (sub == 0) ? 0 : ((sub - 1) << 6);
  conv_core_b2(j, cb, s_mem);
}

// ---------------------------------------------------------------------------
// Deformable conv (round-17 structure, unchanged)
// ---------------------------------------------------------------------------
struct DJob {
  const u16* xbf; const u16* off; const u16* mask;
  int maskC, maskBase;
  const float* wgt; const float* bias; float* out;
  int sigm, act;
};

__device__ __forceinline__ void dconv_core(const DJob j, int gs, int Hh, int Ww,
                                           u16 (*s_x)[40], float* s_w, float* s_b)
{
  const int b   = blockIdx.z;
  const int xt  = Ww >> 4;
  const int ty0 = (blockIdx.x / xt) << 3;
  const int tx0 = (blockIdx.x % xt) << 4;
  const int tid = threadIdx.x;
  const int HW  = Hh * Ww;

  for (int i = tid; i < 2304; i += TPB) {
    int o = i & 7, c = (i >> 3) & 7, k = (i >> 6) % 9, gl = i / 576;
    s_w[i] = j.wgt[(((size_t)((gs * 4 + gl) * 8 + o)) * 8 + c) * 9 + k];
  }
  if (tid < 32) s_b[tid] = j.bias[gs * 32 + tid];
  {
    const u16* xb = j.xbf + (size_t)b * HW * 64 + gs * 32;
#pragma unroll 1
    for (int i = tid; i < 960; i += TPB) {
      int px = i >> 2, q = i & 3;
      int r = px / 20, cx = px - r * 20;
      int gy = ty0 - 2 + r, gx = tx0 - 2 + cx;
      uint4 v = make_uint4(0u, 0u, 0u, 0u);
      if ((unsigned)gy < (unsigned)Hh && (unsigned)gx < (unsigned)Ww)
        v = *(const uint4*)&xb[(size_t)(gy * Ww + gx) * 64 + q * 8];
      *(uint4*)&s_x[px][q * 8] = v;
    }
  }
  __syncthreads();

  const int pin = tid & 127;
  const int ghalf = tid >> 7;
  const int py_ = pin >> 4, px_ = pin & 15;
  const int gy = ty0 + py_, gx = tx0 + px_;
  const int p  = gy * Ww + gx;
  const int sigm = j.sigm, act = j.act;

#pragma unroll
  for (int jj = 0; jj < 2; ++jj) {
    const int gl = ghalf * 2 + jj;
    const int g  = gs * 4 + gl;
    const u16* ob = j.off  + ((size_t)b * 216 + g * 18) * HW + p;
    const u16* mb = j.mask + ((size_t)b * j.maskC + j.maskBase + g * 9) * HW + p;
    const u16* xg = j.xbf  + (size_t)b * HW * 64 + g * 8;
    float*     og = j.out  + ((size_t)b * 64 + g * 8) * HW + p;
    const float* wg = &s_w[gl * 9 * 64];

    float acc[8];
#pragma unroll
    for (int o = 0; o < 8; ++o) acc[o] = s_b[gl * 8 + o];

#pragma unroll
    for (int k = 0; k < 9; ++k) {
      const float oyk = bf2f(ob[(size_t)(2 * k) * HW]);
      const float oxk = bf2f(ob[(size_t)(2 * k + 1) * HW]);
      float m = bf2f(mb[(size_t)k * HW]);
      if (sigm) m = 1.f / (1.f + expf(-m));
      const float py = (float)(gy + k / 3 - 1) + oyk;
      const float px = (float)(gx + k % 3 - 1) + oxk;
      const float y0f = floorf(py), x0f = floorf(px);
      const float fy = py - y0f, fx = px - x0f;
      const int y0 = (int)y0f, x0 = (int)x0f;
      const int y1 = y0 + 1, x1 = x0 + 1;
      const float vy0 = (y0 >= 0 && y0 < Hh) ? 1.f : 0.f;
      const float vy1 = (y1 >= 0 && y1 < Hh) ? 1.f : 0.f;
      const float vx0 = (x0 >= 0 && x0 < Ww) ? 1.f : 0.f;
      const float vx1 = (x1 >= 0 && x1 < Ww) ? 1.f : 0.f;
      const float w00 = (1.f - fy) * (1.f - fx) * vy0 * vx0 * m;
      const float w01 = (1.f - fy) * fx * vy0 * vx1 * m;
      const float w10 = fy * (1.f - fx) * vy1 * vx0 * m;
      const float w11 = fy * fx * vy1 * vx1 * m;
      const float* wk = &wg[k * 64];
      const int ly = y0 - ty0 + 2, lxw = x0 - tx0 + 2;
      if ((unsigned)ly < 11u && (unsigned)lxw < 19u) {
        const u16* base = &s_x[ly * 20 + lxw][gl * 8];
        const bf16x8 c00 = *(const bf16x8*)base;
        const bf16x8 c01 = *(const bf16x8*)(base + 40);
        const bf16x8 c10 = *(const bf16x8*)(base + 800);
        const bf16x8 c11 = *(const bf16x8*)(base + 840);
#pragma unroll
        for (int c = 0; c < 8; ++c) {
          const float s = w00 * (float)c00[c] + w01 * (float)c01[c]
                        + w10 * (float)c10[c] + w11 * (float)c11[c];
          const float4 wv0 = *(const float4*)&wk[c * 8];
          const float4 wv1 = *(const float4*)&wk[c * 8 + 4];
          acc[0] = fmaf(s, wv0.x, acc[0]); acc[1] = fmaf(s, wv0.y, acc[1]);
          acc[2] = fmaf(s, wv0.z, acc[2]); acc[3] = fmaf(s, wv0.w, acc[3]);
          acc[4] = fmaf(s, wv1.x, acc[4]); acc[5] = fmaf(s, wv1.y, acc[5]);
          acc[6] = fmaf(s, wv1.z, acc[6]); acc[7] = fmaf(s, wv1.w, acc[7]);
        }
      } else {
        const int cy0 = min(max(y0, 0), Hh - 1), cy1 = min(max(y1, 0), Hh - 1);
        const int cx0 = min(max(x0, 0), Ww - 1), cx1 = min(max(x1, 0), Ww - 1);
        const int i00 = (cy0 * Ww + cx0) * 64, i01 = (cy0 * Ww + cx1) * 64;
        const int i10 = (cy1 * Ww + cx0) * 64, i11 = (cy1 * Ww + cx1) * 64;
#pragma unroll
        for (int c = 0; c < 8; ++c) {
          const float s = w00 * bf2f(xg[i00 + c]) + w01 * bf2f(xg[i01 + c])
                        + w10 * bf2f(xg[i10 + c]) + w11 * bf2f(xg[i11 + c]);
          const float4 wv0 = *(const float4*)&wk[c * 8];
          const float4 wv1 = *(const float4*)&wk[c * 8 + 4];
          acc[0] = fmaf(s, wv0.x, acc[0]); acc[1] = fmaf(s, wv0.y, acc[1]);
          acc[2] = fmaf(s, wv0.z, acc[2]); acc[3] = fmaf(s, wv0.w, acc[3]);
          acc[4] = fmaf(s, wv1.x, acc[4]); acc[5] = fmaf(s, wv1.y, acc[5]);
          acc[6] = fmaf(s, wv1.z, acc[6]); acc[7] = fmaf(s, wv1.w, acc[7]);
        }
      }
    }
#pragma unroll
    for (int o = 0; o < 8; ++o) {
      float v = acc[o];
      if (act) v = v >= 0.f ? v : 0.1f * v;
      og[(size_t)o * HW] = v;
    }
  }
}

__global__ __launch_bounds__(TPB, 4)
void k_dconv_one(DJob j, int Hh, int Ww)
{
  __shared__ __align__(16) u16 s_x[240][40];
  __shared__ __align__(16) float s_w[4 * 9 * 64];
  __shared__ float s_b[32];
  dconv_core(j, blockIdx.y, Hh, Ww, s_x, s_w, s_b);
}

__global__ __launch_bounds__(TPB, 4)
void k_dconv_dual(DJob a, DJob b, int Hh, int Ww)
{
  __shared__ __align__(16) u16 s_x[240][40];
  __shared__ __align__(16) float s_w[4 * 9 * 64];
  __shared__ float s_b[32];
  const DJob j = (blockIdx.y & 1) ? b : a;
  dconv_core(j, blockIdx.y >> 1, Hh, Ww, s_x, s_w, s_b);
}

// ---------------------------------------------------------------------------
// host helpers
// ---------------------------------------------------------------------------
static CJob mkcjob(const void* i1, const void* i2, int c1, int c2, int m1, int m2,
                   const u16* w, const float* bias, float* outf, u16* outb,
                   int outmode, int act, int Cout, int h)
{
  CJob j; j.in1 = i1; j.in2 = i2; j.c1 = c1; j.c2 = c2; j.m1 = m1; j.m2 = m2;
  j.w = w; j.bias = bias; j.outf = outf; j.outb = outb; j.outmode = outmode;
  j.act = act; j.Cout = Cout; j.Coutpad = ((Cout + 63) / 64) * 64; j.h = h;
  return j;
}

static void conv1(hipStream_t st, CJob a)
{
  dim3 grid((a.h / 8) * (a.h / 16), a.Coutpad / 64, 1);
  k_conv_b2_1<<<grid, TPB, 0, st>>>(a);
}

static void conv2(hipStream_t st, CJob a, CJob b)
{
  int ny0 = a.Coutpad / 64, ny1 = b.Coutpad / 64;
  int nbx0 = (a.h / 8) * (a.h / 16), nbx1 = (b.h / 8) * (b.h / 16);
  dim3 grid(max(nbx0, nbx1), ny0 + ny1, 1);
  k_conv_b2_2<<<grid, TPB, 0, st>>>(a, b, ny0);
}

static DJob mkdjob(const u16* xbf, const u16* off, const u16* mask, int maskC, int maskBase,
                   const float* w, const float* b, float* out, int sigm, int act)
{
  DJob j; j.xbf = xbf; j.off = off; j.mask = mask; j.maskC = maskC; j.maskBase = maskBase;
  j.wgt = w; j.bias = b; j.out = out; j.sigm = sigm; j.act = act;
  return j;
}

static void dconv_dual(hipStream_t st, DJob a, DJob b, int h, int wd)
{
  dim3 grid((h / 8) * (wd / 16), 4, 2);
  k_dconv_dual<<<grid, TPB, 0, st>>>(a, b, h, wd);
}

static void dconv_one(hipStream_t st, DJob a, int h, int wd)
{
  dim3 grid((h / 8) * (wd / 16), 2, 2);
  k_dconv_one<<<grid, TPB, 0, st>>>(a, h, wd);
}

extern "C" void kernel_launch(void* const* d_in, const int* in_sizes, int n_in,
                              void* d_out, int out_size, void* d_ws, size_t ws_size,
                              hipStream_t stream)
{
  const float* const* in = (const float* const*)d_in;

  const int HW0 = 192 * 192, HW1 = 96 * 96, HW2 = 48 * 48;
  const size_t N0 = (size_t)2 * HW0 * 64, N1 = (size_t)2 * HW1 * 64, N2 = (size_t)2 * HW2 * 64;

  // ---- workspace layout ----
  u16* p = (u16*)d_ws;
  u16* nrf0b = p; p += N0;
  u16* rf0b  = p; p += N0;
  u16* swf0b = p; p += N0;
  u16* nrf1b = p; p += N1;
  u16* rf1b  = p; p += N1;
  u16* swf1b = p; p += N1;
  u16* nrf2b = p; p += N2;
  u16* rf2b  = p; p += N2;
  u16* swf2b = p; p += N2;
  u16* A0bf  = p; p += N0;
  u16* A1bf  = p; p += N1;
  u16* A2bf  = p; p += N2;
  u16* OM0   = p; p += (size_t)2 * 216 * HW0;
  u16* OM1   = p; p += (size_t)2 * 216 * HW1;
  u16* OM2   = p; p += (size_t)2 * 216 * HW2;
  u16* EM    = p; p += (size_t)2 * 72 * HW0;
  u16* OF0bf = p; p += N0;
  u16* DN0bf = p; p += N0;
  p = (u16*)(((uintptr_t)p + 15) & ~(uintptr_t)15);
  float* XD   = (float*)p;
  float* DN1  = XD + (size_t)2 * 64 * HW0;
  u16* wp = (u16*)(DN1 + (size_t)2 * 64 * HW1);

  float* dout = (float*)d_out;
  const size_t L0 = (size_t)2 * 64 * HW0;
  float* out0 = dout;
  float* sh0  = dout + L0;
  float* sh1  = sh0  + L0;
  float* sh2  = sh1  + L0 / 4;
  // d_out dead-region aliases:
  u16*   Bbf   = (u16*)out0;                                 // overwritten by final dconv
  u16*   OF1bf = (u16*)sh0;                                  // dead before dual0 writes sh0
  u16*   OF2bf = OF1bf + N1;
  float* DN2   = (float*)(OF2bf + N2);

  // ---- input conversion ----
  {
    ToBfArgs ta;
    const float* srcs[9] = {in[0], in[1], in[2], in[3], in[4], in[5], in[6], in[7], in[8]};
    u16* dsts[9] = {nrf0b, rf0b, swf0b, nrf1b, rf1b, swf1b, nrf2b, rf2b, swf2b};
    const int hws[9] = {HW0, HW0, HW0, HW1, HW1, HW1, HW2, HW2, HW2};
    for (int i = 0; i < 9; ++i) { ta.src[i] = srcs[i]; ta.dst[i] = dsts[i]; ta.hw[i] = hws[i]; }
    int maxtot = 2 * HW0 * 8;
    k_tobf_all<<<dim3((maxtot + TPB - 1) / TPB, 9), TPB, 0, stream>>>(ta);
  }

  // ---- weight prep ----
  struct { int arg, cin, cout; } plist[22] = {
    {9,128,64},{11,64,64},{13,64,216},{15,128,64},{17,64,72},
    {21,128,64},{23,64,64},{25,64,216},{27,128,64},{29,64,72},
    {33,128,64},{35,64,64},{37,64,216},{39,128,64},{41,64,72},
    {45,128,64},{47,128,64},{49,128,64},{51,128,64},
    {53,128,64},{55,64,64},{57,64,216}};
  WPrepArgs wa;
  u16* wptr[22];
  int maxtot = 0;
  for (int i = 0; i < 22; ++i) {
    int cin = plist[i].cin, cout = plist[i].cout;
    int cpad = ((cout + 63) / 64) * 64;
    int tot = (cin / 32) * 9 * cpad * 40;
    wa.src[i] = in[plist[i].arg]; wa.dst[i] = wp;
    wa.cin[i] = cin; wa.cout[i] = cout; wa.coutpad[i] = cpad; wa.total[i] = tot;
    wptr[i] = wp; wp += tot;
    if (tot > maxtot) maxtot = tot;
  }
  k_wprep_all<<<dim3((maxtot + TPB - 1) / TPB, 22), TPB, 0, stream>>>(wa);

  u16* w_ocf0 = wptr[0];  u16* w_ocl0 = wptr[1];  u16* w_com0 = wptr[2];
  u16* w_em10 = wptr[3];  u16* w_em20 = wptr[4];
  u16* w_ocf1 = wptr[5];  u16* w_ocl1 = wptr[6];  u16* w_com1 = wptr[7];
  u16* w_em11 = wptr[8];  u16* w_em21 = wptr[9];
  u16* w_ocf2 = wptr[10]; u16* w_ocl2 = wptr[11]; u16* w_com2 = wptr[12];
  u16* w_em12 = wptr[13]; u16* w_em22 = wptr[14];
  u16* w_occ0 = wptr[15]; u16* w_fcc0 = wptr[16];
  u16* w_occ1 = wptr[17]; u16* w_fcc1 = wptr[18];
  u16* w_cas1 = wptr[19]; u16* w_cas2 = wptr[20]; u16* w_casc = wptr[21];

  const int h2 = 48, h1 = 96, h0 = 192;

  // ---- tri-level mega-pair (b2): all ocf_i + com_i ----
  {
    CJob a0 = mkcjob(nrf0b, rf0b,  64, 64, 1, 1, w_ocf0, in[10], nullptr, A0bf, 1, 1, 64,  h0);
    CJob b0 = mkcjob(swf0b, nullptr,64, 0, 1, 1, w_com0, in[14], nullptr, OM0,  2, 0, 216, h0);
    CJob a1 = mkcjob(nrf1b, rf1b,  64, 64, 1, 1, w_ocf1, in[22], nullptr, A1bf, 1, 1, 64,  h1);
    CJob b1 = mkcjob(swf1b, nullptr,64, 0, 1, 1, w_com1, in[26], nullptr, OM1,  2, 0, 216, h1);
    CJob a2 = mkcjob(nrf2b, rf2b,  64, 64, 1, 1, w_ocf2, in[34], nullptr, A2bf, 1, 1, 64,  h2);
    CJob b2 = mkcjob(swf2b, nullptr,64, 0, 1, 1, w_com2, in[38], nullptr, OM2,  2, 0, 216, h2);
    dim3 grid(288, 15, 1);
    k_conv_b2_tri<<<grid, TPB, 0, stream>>>(a0, b0, a1, b1, a2, b2);
  }

  // ocl2 (48²)
  conv1(stream, mkcjob(A2bf, nullptr, 64, 0, 1, 1, w_ocl2, in[36], nullptr, OF2bf, 1, 1, 64, h2));
  // p1: em12(48) + occ1(96, fused chlast up2)
  conv2(stream,
    mkcjob(OF2bf, swf2b, 64, 64, 1, 1, w_em12, in[40], nullptr, A2bf, 1, 1, 64, h2),
    mkcjob(A1bf,  OF2bf, 64, 64, 1, 3, w_occ1, in[50], nullptr, Bbf,  1, 1, 64, h1));
  // p2: em22(48, sigmoid->EM planar) + ocl1(96)
  conv2(stream,
    mkcjob(A2bf, nullptr, 64, 0, 1, 1, w_em22, in[42], nullptr, EM,    2, 2, 72, h2),
    mkcjob(Bbf,  nullptr, 64, 0, 1, 1, w_ocl1, in[24], nullptr, OF1bf, 1, 1, 64, h1));
  // dual2: sh2 + xd2
  dconv_dual(stream,
             mkdjob(OF2bf, OM2, EM,  72, 0,   in[43], in[44], sh2, 0, 0),
             mkdjob(nrf2b, OM2, OM2, 216, 144, in[43], in[44], DN2, 1, 1), h2, h2);
  // p3: em11(96) + occ0(192, fused chlast up2)
  conv2(stream,
    mkcjob(OF1bf, swf1b, 64, 64, 1, 1, w_em11, in[28], nullptr, A1bf, 1, 1, 64, h1),
    mkcjob(A0bf,  OF1bf, 64, 64, 1, 3, w_occ0, in[46], nullptr, Bbf,  1, 1, 64, h0));
  // p4: em21(96, sigmoid->EM) + ocl0(192)
  conv2(stream,
    mkcjob(A1bf, nullptr, 64, 0, 1, 1, w_em21, in[30], nullptr, EM,    2, 2, 72, h1),
    mkcjob(Bbf,  nullptr, 64, 0, 1, 1, w_ocl0, in[12], nullptr, OF0bf, 1, 1, 64, h0));
  // dual1: sh1 + xd1
  dconv_dual(stream,
             mkdjob(OF1bf, OM1, EM,  72, 0,   in[31], in[32], sh1, 0, 0),
             mkdjob(nrf1b, OM1, OM1, 216, 144, in[31], in[32], XD, 1, 0), h1, h1);
  // p5: em10(192) + fcc1(96, fp32 + fp32-up2 -> fp32)
  conv2(stream,
    mkcjob(OF0bf, swf0b, 64, 64, 1, 1, w_em10, in[16], nullptr, Bbf, 1, 1, 64, h0),
    mkcjob(XD,    DN2,   64, 64, 0, 4, w_fcc1, in[52], DN1, nullptr, 0, 1, 64, h1));
  // em20 (192, sigmoid->EM)
  conv1(stream, mkcjob(Bbf, nullptr, 64, 0, 1, 1, w_em20, in[18], nullptr, EM, 2, 2, 72, h0));
  // dual0: sh0 + xd0
  dconv_dual(stream,
             mkdjob(OF0bf, OM0, EM,  72, 0,   in[19], in[20], sh0, 0, 0),
             mkdjob(nrf0b, OM0, OM0, 216, 144, in[19], in[20], XD, 1, 0), h0, h0);
  // fcc0 (fp32 + fp32-up2 -> chlast)
  conv1(stream, mkcjob(XD, DN1, 64, 64, 0, 4, w_fcc0, in[48], nullptr, DN0bf, 1, 0, 64, h0));
  // cascade
  conv1(stream, mkcjob(DN0bf, rf0b, 64, 64, 1, 1, w_cas1, in[54], nullptr, A0bf, 1, 1, 64, h0));
  conv1(stream, mkcjob(A0bf, nullptr, 64, 0, 1, 1, w_cas2, in[56], nullptr, Bbf, 1, 1, 64, h0));
  conv1(stream, mkcjob(Bbf, nullptr, 64, 0, 1, 1, w_casc, in[58], nullptr, OM0, 2, 0, 216, h0));
  dconv_one(stream,
            mkdjob(DN0bf, OM0, OM0, 216, 144, in[59], in[60], out0, 1, 1), h0, h0);
}

// Round 24
// 616.287 us; speedup vs baseline: 2.7247x; 1.1860x over previous
//
#include <hip/hip_runtime.h>
#include <cstddef>
#include <cstdint>

#define TPB 256

typedef unsigned int u32;
typedef unsigned short u16;
typedef __bf16 bf16x8 __attribute__((ext_vector_type(8)));
typedef float f32x4 __attribute__((ext_vector_type(4)));

template<int ACT>
__device__ __forceinline__ float act_f(float v) {
  if (ACT == 1) return v >= 0.f ? v : 0.1f * v;
  if (ACT == 2) return 1.f / (1.f + expf(-v));
  return v;
}
__device__ __forceinline__ float act_rt(float v, int a) {
  if (a == 1) return v >= 0.f ? v : 0.1f * v;
  if (a == 2) return 1.f / (1.f + expf(-v));
  return v;
}

__device__ __forceinline__ u16 f2bf(float f) {
  __bf16 h = (__bf16)f;
  return __builtin_bit_cast(u16, h);
}
__device__ __forceinline__ float bf2f(u16 h) {
  return __uint_as_float(((u32)h) << 16);
}
__device__ __forceinline__ u32 pk2bf(float a, float b) {
  return (u32)f2bf(a) | ((u32)f2bf(b) << 16);
}

// ---------------------------------------------------------------------------
// Weight prep (one launch, 22 convs)
// ---------------------------------------------------------------------------
struct WPrepArgs {
  const float* src[22];
  u16* dst[22];
  int cin[22], cout[22], coutpad[22], total[22];
};

__global__ void k_wprep_all(WPrepArgs a)
{
  const int seg = blockIdx.y;
  const int idx = blockIdx.x * TPB + threadIdx.x;
  if (idx >= a.total[seg]) return;
  const int Cin = a.cin[seg], Cout = a.cout[seg], Coutpad = a.coutpad[seg];
  int kk = idx % 40; int t = idx / 40;
  int co = t % Coutpad; t /= Coutpad;
  int tap = t % 9; int kc = t / 9;
  u16 v = 0;
  if (kk < 32 && co < Cout)
    v = f2bf(a.src[seg][((size_t)co * Cin + kc * 32 + kk) * 9 + tap]);
  a.dst[seg][idx] = v;
}

// ---------------------------------------------------------------------------
// Input prep
// ---------------------------------------------------------------------------
struct ToBfArgs {
  const float* src[9];
  u16* dst[9];
  int hw[9];
};

__global__ void k_tobf_all(ToBfArgs a)
{
  const int seg = blockIdx.y;
  const int hw = a.hw[seg];
  const int total = 2 * hw * 8;
  int idx = blockIdx.x * TPB + threadIdx.x;
  if (idx >= total) return;
  const int g8 = idx & 7;
  int t = idx >> 3;
  const int pos = t % hw, b = t / hw;
  const float* s = a.src[seg] + ((size_t)b * 64 + g8 * 8) * hw + pos;
  u32 w0 = pk2bf(s[0], s[(size_t)hw]);
  u32 w1 = pk2bf(s[(size_t)2 * hw], s[(size_t)3 * hw]);
  u32 w2 = pk2bf(s[(size_t)4 * hw], s[(size_t)5 * hw]);
  u32 w3 = pk2bf(s[(size_t)6 * hw], s[(size_t)7 * hw]);
  *(uint4*)&a.dst[seg][((size_t)b * hw + pos) * 64 + g8 * 8] = make_uint4(w0, w1, w2, w3);
}

// ---------------------------------------------------------------------------
// Shared staging helper. modes: 0 fp32 planar | 1 chlast | 3 chlast half-res
// up2 | 4 fp32 planar half-res up2
// ---------------------------------------------------------------------------
__device__ __forceinline__ void stage_act(u16* s_act, int NPOS, int mode,
                                          const void* in1v, int c1,
                                          const void* in2v, int c2,
                                          bool use1, int kc, int nk1,
                                          int b, int by0, int bx0, int Hh, int Ww, int tid)
{
  const int HW = Hh * Ww;
  if (mode == 0) {
    const float* sp = use1
      ? (const float*)in1v + ((size_t)b * c1 + (kc << 5)) * HW
      : (const float*)in2v + ((size_t)b * c2 + ((kc - nk1) << 5)) * HW;
#pragma unroll 1
    for (int u = tid; u < NPOS; u += TPB) {
      int y = u / 18, x = u - y * 18;
      int gy = by0 - 1 + y, gx = bx0 - 1 + x;
      bool inb = ((unsigned)gy < (unsigned)Hh) & ((unsigned)gx < (unsigned)Ww);
      const float msk = inb ? 1.f : 0.f;
      const size_t poff = inb ? ((size_t)gy * Ww + gx) : 0;
      const float* s0 = sp + poff;
      u16* dp = &s_act[u * 40];
#pragma unroll
      for (int c8 = 0; c8 < 4; ++c8) {
        u32 hb[4];
#pragma unroll
        for (int j = 0; j < 4; ++j)
          hb[j] = pk2bf(s0[(size_t)(c8 * 8 + 2 * j) * HW] * msk,
                        s0[(size_t)(c8 * 8 + 2 * j + 1) * HW] * msk);
        *(uint4*)&dp[c8 * 8] = make_uint4(hb[0], hb[1], hb[2], hb[3]);
      }
    }
  } else if (mode == 3) {
    const u16* b2 = (const u16*)in2v;
    const int hh = Hh >> 1, hw = Ww >> 1;
    const int cofs = (kc - nk1) << 5;
#pragma unroll 1
    for (int u = tid; u < NPOS; u += TPB) {
      int y = u / 18, x = u - y * 18;
      int gy = by0 - 1 + y, gx = bx0 - 1 + x;
      u16* dp = &s_act[u * 40];
      if ((unsigned)gy < (unsigned)Hh && (unsigned)gx < (unsigned)Ww) {
        int iy0, iy1, ix0, ix1; float wy0, wy1, wx0, wx1;
        if (gy & 1) { iy0 = gy >> 1; iy1 = min(iy0 + 1, hh - 1); wy0 = 0.75f; wy1 = 0.25f; }
        else        { iy1 = gy >> 1; iy0 = max(iy1 - 1, 0);      wy0 = 0.25f; wy1 = 0.75f; }
        if (gx & 1) { ix0 = gx >> 1; ix1 = min(ix0 + 1, hw - 1); wx0 = 0.75f; wx1 = 0.25f; }
        else        { ix1 = gx >> 1; ix0 = max(ix1 - 1, 0);      wx0 = 0.25f; wx1 = 0.75f; }
        const u16* pb = b2 + (size_t)b * hh * hw * 64 + cofs;
#pragma unroll
        for (int q = 0; q < 4; ++q) {
          const bf16x8 a00 = *(const bf16x8*)&pb[(size_t)(iy0 * hw + ix0) * 64 + q * 8];
          const bf16x8 a01 = *(const bf16x8*)&pb[(size_t)(iy0 * hw + ix1) * 64 + q * 8];
          const bf16x8 a10 = *(const bf16x8*)&pb[(size_t)(iy1 * hw + ix0) * 64 + q * 8];
          const bf16x8 a11 = *(const bf16x8*)&pb[(size_t)(iy1 * hw + ix1) * 64 + q * 8];
          u32 r[4];
#pragma unroll
          for (int j = 0; j < 4; ++j) {
            float v0 = wy0 * (wx0 * (float)a00[2 * j] + wx1 * (float)a01[2 * j])
                     + wy1 * (wx0 * (float)a10[2 * j] + wx1 * (float)a11[2 * j]);
            float v1 = wy0 * (wx0 * (float)a00[2 * j + 1] + wx1 * (float)a01[2 * j + 1])
                     + wy1 * (wx0 * (float)a10[2 * j + 1] + wx1 * (float)a11[2 * j + 1]);
            r[j] = pk2bf(v0, v1);
          }
          *(uint4*)&dp[q * 8] = make_uint4(r[0], r[1], r[2], r[3]);
        }
      } else {
#pragma unroll
        for (int q = 0; q < 4; ++q)
          *(uint4*)&dp[q * 8] = make_uint4(0u, 0u, 0u, 0u);
      }
    }
  } else if (mode == 4) {
    const float* f2 = (const float*)in2v;
    const int hh = Hh >> 1, hw = Ww >> 1;
    const int cofs = (kc - nk1) << 5;
    const int hhw = hh * hw;
#pragma unroll 1
    for (int u = tid; u < NPOS; u += TPB) {
      int y = u / 18, x = u - y * 18;
      int gy = by0 - 1 + y, gx = bx0 - 1 + x;
      u16* dp = &s_act[u * 40];
      if ((unsigned)gy < (unsigned)Hh && (unsigned)gx < (unsigned)Ww) {
        int iy0, iy1, ix0, ix1; float wy0, wy1, wx0, wx1;
        if (gy & 1) { iy0 = gy >> 1; iy1 = min(iy0 + 1, hh - 1); wy0 = 0.75f; wy1 = 0.25f; }
        else        { iy1 = gy >> 1; iy0 = max(iy1 - 1, 0);      wy0 = 0.25f; wy1 = 0.75f; }
        if (gx & 1) { ix0 = gx >> 1; ix1 = min(ix0 + 1, hw - 1); wx0 = 0.75f; wx1 = 0.25f; }
        else        { ix1 = gx >> 1; ix0 = max(ix1 - 1, 0);      wx0 = 0.25f; wx1 = 0.75f; }
        const float* pb = f2 + ((size_t)b * 64 + cofs) * hhw;
        const int i00 = iy0 * hw + ix0, i01 = iy0 * hw + ix1;
        const int i10 = iy1 * hw + ix0, i11 = iy1 * hw + ix1;
#pragma unroll
        for (int q = 0; q < 4; ++q) {
          u32 r[4];
#pragma unroll
          for (int j = 0; j < 4; ++j) {
            const float* p0 = pb + (size_t)(q * 8 + 2 * j) * hhw;
            const float* p1 = pb + (size_t)(q * 8 + 2 * j + 1) * hhw;
            float v0 = wy0 * (wx0 * p0[i00] + wx1 * p0[i01])
                     + wy1 * (wx0 * p0[i10] + wx1 * p0[i11]);
            float v1 = wy0 * (wx0 * p1[i00] + wx1 * p1[i01])
                     + wy1 * (wx0 * p1[i10] + wx1 * p1[i11]);
            r[j] = pk2bf(v0, v1);
          }
          *(uint4*)&dp[q * 8] = make_uint4(r[0], r[1], r[2], r[3]);
        }
      } else {
#pragma unroll
        for (int q = 0; q < 4; ++q)
          *(uint4*)&dp[q * 8] = make_uint4(0u, 0u, 0u, 0u);
      }
    }
  } else {
    const u16* src; int cofs, cst;
    if (use1) { src = (const u16*)in1v + (size_t)b * HW * c1; cofs = kc << 5; cst = c1; }
    else      { src = (const u16*)in2v + (size_t)b * HW * c2; cofs = (kc - nk1) << 5; cst = c2; }
#pragma unroll 1
    for (int i = tid; i < NPOS * 4; i += TPB) {
      int u = i >> 2, q = i & 3;
      int y = u / 18, x = u - y * 18;
      int gy = by0 - 1 + y, gx = bx0 - 1 + x;
      uint4 v = make_uint4(0u, 0u, 0u, 0u);
      if ((unsigned)gy < (unsigned)Hh && (unsigned)gx < (unsigned)Ww)
        v = *(const uint4*)&src[(size_t)(gy * Ww + gx) * cst + cofs + q * 8];
      *(uint4*)&s_act[u * 40 + q * 8] = v;
    }
  }
}

// ---------------------------------------------------------------------------
// 3x3 conv via MFMA bf16 (templated single-job)
// ---------------------------------------------------------------------------
template<int ACT, int M1, int M2, int OUTBF, int TH>
__global__ __launch_bounds__(TPB, (TH == 8 ? 4 : 3))
void k_conv(const void* __restrict__ in1v, int c1,
            const void* __restrict__ in2v, int c2,
            const u16* __restrict__ wbuf, const float* __restrict__ bias,
            float* __restrict__ outf, u16* __restrict__ outb,
            int Cout, int Coutpad, int Hh, int Ww)
{
  constexpr int NPOS = (TH + 2) * 18;
  constexpr int NPG  = TH / 4;
  __shared__ __align__(16) u16 s_mem[NPOS * 40 + 3 * 64 * 40];
  u16* s_act = s_mem;
  u16* s_w   = s_mem + NPOS * 40;
  const int nkc = (c1 + c2) >> 5, nk1 = c1 >> 5;
  const int b   = blockIdx.z;
  const int cb  = blockIdx.y << 6;
  const int xt  = Ww >> 4;
  const int by0 = (blockIdx.x / xt) * TH;
  const int bx0 = (blockIdx.x % xt) << 4;
  const int tid = threadIdx.x;
  const int lx = tid & 15, slot = (tid >> 4) & 3, wv = tid >> 6;
  const int HW = Hh * Ww;

  f32x4 acc[4][NPG];
#pragma unroll
  for (int i = 0; i < 4; ++i)
#pragma unroll
    for (int j = 0; j < NPG; ++j) acc[i][j] = (f32x4){0.f, 0.f, 0.f, 0.f};

#pragma unroll 1
  for (int kc = 0; kc < nkc; ++kc) {
    __syncthreads();
    const bool use1 = kc < nk1;
    stage_act(s_act, NPOS, use1 ? M1 : M2, in1v, c1, in2v, c2, use1, kc, nk1,
              b, by0, bx0, Hh, Ww, tid);
#pragma unroll 1
    for (int ky = 0; ky < 3; ++ky) {
      __syncthreads();
      {
        const size_t base = ((size_t)(kc * 9 + ky * 3) * Coutpad + cb) * 40;
        const size_t tapstride = (size_t)Coutpad * 40;
#pragma unroll 1
        for (int i = tid; i < 960; i += TPB) {
          int kxl = i / 320, j = i - kxl * 320;
          const uint4 v = *(const uint4*)&wbuf[base + (size_t)kxl * tapstride + j * 8];
          *(uint4*)&s_w[kxl * 2560 + j * 8] = v;
        }
      }
      __syncthreads();
#pragma unroll
      for (int kx = 0; kx < 3; ++kx) {
        bf16x8 Af[4], Bf[NPG];
#pragma unroll
        for (int ct = 0; ct < 4; ++ct)
          Af[ct] = *(const bf16x8*)&s_w[(kx * 64 + ct * 16 + lx) * 40 + slot * 8];
#pragma unroll
        for (int pg = 0; pg < NPG; ++pg)
          Bf[pg] = *(const bf16x8*)&s_act[((wv * NPG + pg + ky) * 18 + lx + kx) * 40 + slot * 8];
#pragma unroll
        for (int ct = 0; ct < 4; ++ct)
#pragma unroll
          for (int pg = 0; pg < NPG; ++pg)
            acc[ct][pg] = __builtin_amdgcn_mfma_f32_16x16x32_bf16(Af[ct], Bf[pg], acc[ct][pg], 0, 0, 0);
      }
    }
  }
  const int ox = bx0 + lx;
  if (OUTBF == 1) {
    __syncthreads();
#pragma unroll
    for (int ct = 0; ct < 4; ++ct) {
      const int co0 = ct * 16 + slot * 4;
      const float b0 = bias[co0], b1 = bias[co0 + 1], b2 = bias[co0 + 2], b3 = bias[co0 + 3];
#pragma unroll
      for (int pg = 0; pg < NPG; ++pg) {
        const int px = (wv * NPG + pg) * 16 + lx;
        *(u32*)&s_mem[px * 72 + co0]     = pk2bf(act_f<ACT>(acc[ct][pg][0] + b0),
                                                 act_f<ACT>(acc[ct][pg][1] + b1));
        *(u32*)&s_mem[px * 72 + co0 + 2] = pk2bf(act_f<ACT>(acc[ct][pg][2] + b2),
                                                 act_f<ACT>(acc[ct][pg][3] + b3));
      }
    }
    __syncthreads();
#pragma unroll 1
    for (int l = tid; l < TH * 16 * 8; l += TPB) {
      const int px = l >> 3, ch = (l & 7) * 8;
      const int row = px >> 4, col = px & 15;
      const uint4 v = *(const uint4*)&s_mem[px * 72 + ch];
      *(uint4*)&outb[(((size_t)b * HW + (size_t)(by0 + row) * Ww + bx0 + col) << 6) + ch] = v;
    }
  } else if (OUTBF == 2) {
#pragma unroll
    for (int ct = 0; ct < 4; ++ct) {
      const int co0 = cb + ct * 16 + slot * 4;
#pragma unroll
      for (int r = 0; r < 4; ++r) {
        const int co = co0 + r;
        if (co < Cout) {
          const float bv = bias[co];
          u16* op = outb + ((size_t)b * Cout + co) * HW + (size_t)(by0 + wv * NPG) * Ww + ox;
#pragma unroll
          for (int pg = 0; pg < NPG; ++pg)
            op[pg * Ww] = f2bf(act_f<ACT>(acc[ct][pg][r] + bv));
        }
      }
    }
  } else {
#pragma unroll
    for (int ct = 0; ct < 4; ++ct) {
      const int co0 = cb + ct * 16 + slot * 4;
#pragma unroll
      for (int r = 0; r < 4; ++r) {
        const int co = co0 + r;
        if (co < Cout) {
          const float bv = bias[co];
          float* op = outf + ((size_t)b * Cout + co) * HW + (size_t)(by0 + wv * NPG) * Ww + ox;
#pragma unroll
          for (int pg = 0; pg < NPG; ++pg)
            op[pg * Ww] = act_f<ACT>(acc[ct][pg][r] + bv);
        }
      }
    }
  }
}

// ---------------------------------------------------------------------------
// Runtime 2-job conv kernel (TH=8): blockIdx.y < ny0 -> job A, else job B.
// ---------------------------------------------------------------------------
struct CJob {
  const void* in1; const void* in2; int c1, c2, m1, m2;
  const u16* w; const float* bias;
  float* outf; u16* outb; int outmode, act, Cout, Coutpad, h;
};

__global__ __launch_bounds__(TPB, 4)
void k_conv_jobs(CJob A, CJob B, int ny0)
{
  constexpr int TH = 8, NPOS = 180, NPG = 2;
  __shared__ __align__(16) u16 s_mem[NPOS * 40 + 3 * 64 * 40];
  u16* s_act = s_mem;
  u16* s_w   = s_mem + NPOS * 40;
  const bool isA = (int)blockIdx.y < ny0;
  const CJob j = isA ? A : B;
  const int cb = (isA ? blockIdx.y : blockIdx.y - ny0) << 6;
  const int Hh = j.h, Ww = j.h;
  const int xt = Ww >> 4;
  const int nbx = (Hh >> 3) * xt;
  if ((int)blockIdx.x >= nbx) return;
  const int c1 = j.c1, c2 = j.c2;
  const int nkc = (c1 + c2) >> 5, nk1 = c1 >> 5;
  const int b   = blockIdx.z;
  const int by0 = (blockIdx.x / xt) * TH;
  const int bx0 = (blockIdx.x % xt) << 4;
  const int tid = threadIdx.x;
  const int lx = tid & 15, slot = (tid >> 4) & 3, wv = tid >> 6;
  const int HW = Hh * Ww;

  f32x4 acc[4][NPG];
#pragma unroll
  for (int i = 0; i < 4; ++i)
#pragma unroll
    for (int jj = 0; jj < NPG; ++jj) acc[i][jj] = (f32x4){0.f, 0.f, 0.f, 0.f};

#pragma unroll 1
  for (int kc = 0; kc < nkc; ++kc) {
    __syncthreads();
    const bool use1 = kc < nk1;
    stage_act(s_act, NPOS, use1 ? j.m1 : j.m2, j.in1, c1, j.in2, c2, use1, kc, nk1,
              b, by0, bx0, Hh, Ww, tid);
#pragma unroll 1
    for (int ky = 0; ky < 3; ++ky) {
      __syncthreads();
      {
        const size_t base = ((size_t)(kc * 9 + ky * 3) * j.Coutpad + cb) * 40;
        const size_t tapstride = (size_t)j.Coutpad * 40;
#pragma unroll 1
        for (int i = tid; i < 960; i += TPB) {
          int kxl = i / 320, jj = i - kxl * 320;
          const uint4 v = *(const uint4*)&j.w[base + (size_t)kxl * tapstride + jj * 8];
          *(uint4*)&s_w[kxl * 2560 + jj * 8] = v;
        }
      }
      __syncthreads();
#pragma unroll
      for (int kx = 0; kx < 3; ++kx) {
        bf16x8 Af[4], Bf[NPG];
#pragma unroll
        for (int ct = 0; ct < 4; ++ct)
          Af[ct] = *(const bf16x8*)&s_w[(kx * 64 + ct * 16 + lx) * 40 + slot * 8];
#pragma unroll
        for (int pg = 0; pg < NPG; ++pg)
          Bf[pg] = *(const bf16x8*)&s_act[((wv * NPG + pg + ky) * 18 + lx + kx) * 40 + slot * 8];
#pragma unroll
        for (int ct = 0; ct < 4; ++ct)
#pragma unroll
          for (int pg = 0; pg < NPG; ++pg)
            acc[ct][pg] = __builtin_amdgcn_mfma_f32_16x16x32_bf16(Af[ct], Bf[pg], acc[ct][pg], 0, 0, 0);
      }
    }
  }
  const int ox = bx0 + lx;
  const int jact = j.act;
  if (j.outmode == 1) {
    __syncthreads();
#pragma unroll
    for (int ct = 0; ct < 4; ++ct) {
      const int co0 = ct * 16 + slot * 4;
      const float b0 = j.bias[co0], b1 = j.bias[co0 + 1], b2 = j.bias[co0 + 2], b3 = j.bias[co0 + 3];
#pragma unroll
      for (int pg = 0; pg < NPG; ++pg) {
        const int px = (wv * NPG + pg) * 16 + lx;
        *(u32*)&s_mem[px * 72 + co0]     = pk2bf(act_rt(acc[ct][pg][0] + b0, jact),
                                                 act_rt(acc[ct][pg][1] + b1, jact));
        *(u32*)&s_mem[px * 72 + co0 + 2] = pk2bf(act_rt(acc[ct][pg][2] + b2, jact),
                                                 act_rt(acc[ct][pg][3] + b3, jact));
      }
    }
    __syncthreads();
#pragma unroll 1
    for (int l = tid; l < TH * 16 * 8; l += TPB) {
      const int px = l >> 3, ch = (l & 7) * 8;
      const int row = px >> 4, col = px & 15;
      const uint4 v = *(const uint4*)&s_mem[px * 72 + ch];
      *(uint4*)&j.outb[(((size_t)b * HW + (size_t)(by0 + row) * Ww + bx0 + col) << 6) + ch] = v;
    }
  } else if (j.outmode == 2) {
#pragma unroll
    for (int ct = 0; ct < 4; ++ct) {
      const int co0 = cb + ct * 16 + slot * 4;
#pragma unroll
      for (int r = 0; r < 4; ++r) {
        const int co = co0 + r;
        if (co < j.Cout) {
          const float bv = j.bias[co];
          u16* op = j.outb + ((size_t)b * j.Cout + co) * HW + (size_t)(by0 + wv * NPG) * Ww + ox;
#pragma unroll
          for (int pg = 0; pg < NPG; ++pg)
            op[pg * Ww] = f2bf(act_rt(acc[ct][pg][r] + bv, jact));
        }
      }
    }
  } else {
#pragma unroll
    for (int ct = 0; ct < 4; ++ct) {
      const int co0 = cb + ct * 16 + slot * 4;
#pragma unroll
      for (int r = 0; r < 4; ++r) {
        const int co = co0 + r;
        if (co < j.Cout) {
          const float bv = j.bias[co];
          float* op = j.outf + ((size_t)b * j.Cout + co) * HW + (size_t)(by0 + wv * NPG) * Ww + ox;
#pragma unroll
          for (int pg = 0; pg < NPG; ++pg)
            op[pg * Ww] = act_rt(acc[ct][pg][r] + bv, jact);
        }
      }
    }
  }
}

// ---------------------------------------------------------------------------
// Tri-level mega-pair, TH=8: blockIdx.y = lvl*5 + sub; sub==0 -> ocf (chlast,
// lrelu); sub 1..4 -> com (bf16 planar, Cout=216). All chlast-in.
// ---------------------------------------------------------------------------
struct PairJob {
  const u16* in1; const u16* in2; int c1, c2;
  const u16* w; const float* bias;
  u16* outb; int Cout, Coutpad, act, chlast, h;
};

__global__ __launch_bounds__(TPB, 4)
void k_conv_tri(PairJob a0, PairJob b0, PairJob a1, PairJob b1, PairJob a2, PairJob b2)
{
  constexpr int TH = 8, NPOS = 180, NPG = 2;
  __shared__ __align__(16) u16 s_mem[NPOS * 40 + 3 * 64 * 40];
  u16* s_act = s_mem;
  u16* s_w   = s_mem + NPOS * 40;
  const int lvl = blockIdx.y / 5, sub = blockIdx.y % 5;
  const PairJob j = (lvl == 0) ? (sub == 0 ? a0 : b0)
                  : (lvl == 1) ? (sub == 0 ? a1 : b1)
                               : (sub == 0 ? a2 : b2);
  const int Hh = j.h, Ww = j.h;
  const int xt = Ww >> 4;
  const int nbx = (Hh >> 3) * xt;
  if ((int)blockIdx.x >= nbx) return;
  const int cb = (sub == 0) ? 0 : ((sub - 1) << 6);
  const int c1 = j.c1, c2 = j.c2;
  const int nkc = (c1 + c2) >> 5, nk1 = c1 >> 5;
  const int b   = blockIdx.z;
  const int by0 = (blockIdx.x / xt) * TH;
  const int bx0 = (blockIdx.x % xt) << 4;
  const int tid = threadIdx.x;
  const int lx = tid & 15, slot = (tid >> 4) & 3, wv = tid >> 6;
  const int HW = Hh * Ww;

  f32x4 acc[4][NPG];
#pragma unroll
  for (int i = 0; i < 4; ++i)
#pragma unroll
    for (int jj = 0; jj < NPG; ++jj) acc[i][jj] = (f32x4){0.f, 0.f, 0.f, 0.f};

#pragma unroll 1
  for (int kc = 0; kc < nkc; ++kc) {
    __syncthreads();
    {
      const u16* src; int cofs, cst;
      if (kc < nk1) { src = j.in1 + (size_t)b * HW * c1; cofs = kc << 5; cst = c1; }
      else          { src = j.in2 + (size_t)b * HW * c2; cofs = (kc - nk1) << 5; cst = c2; }
#pragma unroll 1
      for (int i = tid; i < NPOS * 4; i += TPB) {
        int u = i >> 2, q = i & 3;
        int y = u / 18, x = u - y * 18;
        int gy = by0 - 1 + y, gx = bx0 - 1 + x;
        uint4 v = make_uint4(0u, 0u, 0u, 0u);
        if ((unsigned)gy < (unsigned)Hh && (unsigned)gx < (unsigned)Ww)
          v = *(const uint4*)&src[(size_t)(gy * Ww + gx) * cst + cofs + q * 8];
        *(uint4*)&s_act[u * 40 + q * 8] = v;
      }
    }
#pragma unroll 1
    for (int ky = 0; ky < 3; ++ky) {
      __syncthreads();
      {
        const size_t base = ((size_t)(kc * 9 + ky * 3) * j.Coutpad + cb) * 40;
        const size_t tapstride = (size_t)j.Coutpad * 40;
#pragma unroll 1
        for (int i = tid; i < 960; i += TPB) {
          int kxl = i / 320, jj = i - kxl * 320;
          const uint4 v = *(const uint4*)&j.w[base + (size_t)kxl * tapstride + jj * 8];
          *(uint4*)&s_w[kxl * 2560 + jj * 8] = v;
        }
      }
      __syncthreads();
#pragma unroll
      for (int kx = 0; kx < 3; ++kx) {
        bf16x8 Af[4], Bf[NPG];
#pragma unroll
        for (int ct = 0; ct < 4; ++ct)
          Af[ct] = *(const bf16x8*)&s_w[(kx * 64 + ct * 16 + lx) * 40 + slot * 8];
#pragma unroll
        for (int pg = 0; pg < NPG; ++pg)
          Bf[pg] = *(const bf16x8*)&s_act[((wv * NPG + pg + ky) * 18 + lx + kx) * 40 + slot * 8];
#pragma unroll
        for (int ct = 0; ct < 4; ++ct)
#pragma unroll
          for (int pg = 0; pg < NPG; ++pg)
            acc[ct][pg] = __builtin_amdgcn_mfma_f32_16x16x32_bf16(Af[ct], Bf[pg], acc[ct][pg], 0, 0, 0);
      }
    }
  }
  const int ox = bx0 + lx;
  const int jact = j.act;
  if (j.chlast) {
    __syncthreads();
#pragma unroll
    for (int ct = 0; ct < 4; ++ct) {
      const int co0 = ct * 16 + slot * 4;
      const float b0 = j.bias[co0], b1 = j.bias[co0 + 1], b2 = j.bias[co0 + 2], b3 = j.bias[co0 + 3];
#pragma unroll
      for (int pg = 0; pg < NPG; ++pg) {
        const int px = (wv * NPG + pg) * 16 + lx;
        float v0 = acc[ct][pg][0] + b0, v1 = acc[ct][pg][1] + b1;
        float v2 = acc[ct][pg][2] + b2, v3 = acc[ct][pg][3] + b3;
        if (jact) { v0 = v0 >= 0.f ? v0 : 0.1f * v0; v1 = v1 >= 0.f ? v1 : 0.1f * v1;
                    v2 = v2 >= 0.f ? v2 : 0.1f * v2; v3 = v3 >= 0.f ? v3 : 0.1f * v3; }
        *(u32*)&s_mem[px * 72 + co0]     = pk2bf(v0, v1);
        *(u32*)&s_mem[px * 72 + co0 + 2] = pk2bf(v2, v3);
      }
    }
    __syncthreads();
#pragma unroll 1
    for (int l = tid; l < TH * 16 * 8; l += TPB) {
      const int px = l >> 3, ch = (l & 7) * 8;
      const int row = px >> 4, col = px & 15;
      const uint4 v = *(const uint4*)&s_mem[px * 72 + ch];
      *(uint4*)&j.outb[(((size_t)b * HW + (size_t)(by0 + row) * Ww + bx0 + col) << 6) + ch] = v;
    }
  } else {
#pragma unroll
    for (int ct = 0; ct < 4; ++ct) {
      const int co0 = cb + ct * 16 + slot * 4;
#pragma unroll
      for (int r = 0; r < 4; ++r) {
        const int co = co0 + r;
        if (co < j.Cout) {
          const float bv = j.bias[co];
          u16* op = j.outb + ((size_t)b * j.Cout + co) * HW + (size_t)(by0 + wv * NPG) * Ww + ox;
#pragma unroll
          for (int pg = 0; pg < NPG; ++pg) {
            float v = acc[ct][pg][r] + bv;
            if (jact) v = v >= 0.f ? v : 0.1f * v;
            op[pg * Ww] = f2bf(v);
          }
        }
      }
    }
  }
}

// ---------------------------------------------------------------------------
// Deformable conv (round-17 structure)
// ---------------------------------------------------------------------------
struct DJob {
  const u16* xbf; const u16* off; const u16* mask;
  int maskC, maskBase;
  const float* wgt; const float* bias; float* out;
  int sigm, act;
};

__device__ __forceinline__ void dconv_core(const DJob& j, int gs, int Hh, int Ww,
                                           u16 (*s_x)[40], float* s_w, float* s_b)
{
  const int b   = blockIdx.z;
  const int xt  = Ww >> 4;
  const int ty0 = (blockIdx.x / xt) << 3;
  const int tx0 = (blockIdx.x % xt) << 4;
  const int tid = threadIdx.x;
  const int HW  = Hh * Ww;

  for (int i = tid; i < 2304; i += TPB) {
    int o = i & 7, c = (i >> 3) & 7, k = (i >> 6) % 9, gl = i / 576;
    s_w[i] = j.wgt[(((size_t)((gs * 4 + gl) * 8 + o)) * 8 + c) * 9 + k];
  }
  if (tid < 32) s_b[tid] = j.bias[gs * 32 + tid];
  {
    const u16* xb = j.xbf + (size_t)b * HW * 64 + gs * 32;
#pragma unroll 1
    for (int i = tid; i < 960; i += TPB) {
      int px = i >> 2, q = i & 3;
      int r = px / 20, cx = px - r * 20;
      int gy = ty0 - 2 + r, gx = tx0 - 2 + cx;
      uint4 v = make_uint4(0u, 0u, 0u, 0u);
      if ((unsigned)gy < (unsigned)Hh && (unsigned)gx < (unsigned)Ww)
        v = *(const uint4*)&xb[(size_t)(gy * Ww + gx) * 64 + q * 8];
      *(uint4*)&s_x[px][q * 8] = v;
    }
  }
  __syncthreads();

  const int pin = tid & 127;
  const int ghalf = tid >> 7;
  const int py_ = pin >> 4, px_ = pin & 15;
  const int gy = ty0 + py_, gx = tx0 + px_;
  const int p  = gy * Ww + gx;
  const int sigm = j.sigm, act = j.act;

#pragma unroll
  for (int jj = 0; jj < 2; ++jj) {
    const int gl = ghalf * 2 + jj;
    const int g  = gs * 4 + gl;
    const u16* ob = j.off  + ((size_t)b * 216 + g * 18) * HW + p;
    const u16* mb = j.mask + ((size_t)b * j.maskC + j.maskBase + g * 9) * HW + p;
    const u16* xg = j.xbf  + (size_t)b * HW * 64 + g * 8;
    float*     og = j.out  + ((size_t)b * 64 + g * 8) * HW + p;
    const float* wg = &s_w[gl * 9 * 64];

    float acc[8];
#pragma unroll
    for (int o = 0; o < 8; ++o) acc[o] = s_b[gl * 8 + o];

#pragma unroll
    for (int k = 0; k < 9; ++k) {
      const float oyk = bf2f(ob[(size_t)(2 * k) * HW]);
      const float oxk = bf2f(ob[(size_t)(2 * k + 1) * HW]);
      float m = bf2f(mb[(size_t)k * HW]);
      if (sigm) m = 1.f / (1.f + expf(-m));
      const float py = (float)(gy + k / 3 - 1) + oyk;
      const float px = (float)(gx + k % 3 - 1) + oxk;
      const float y0f = floorf(py), x0f = floorf(px);
      const float fy = py - y0f, fx = px - x0f;
      const int y0 = (int)y0f, x0 = (int)x0f;
      const int y1 = y0 + 1, x1 = x0 + 1;
      const float vy0 = (y0 >= 0 && y0 < Hh) ? 1.f : 0.f;
      const float vy1 = (y1 >= 0 && y1 < Hh) ? 1.f : 0.f;
      const float vx0 = (x0 >= 0 && x0 < Ww) ? 1.f : 0.f;
      const float vx1 = (x1 >= 0 && x1 < Ww) ? 1.f : 0.f;
      const float w00 = (1.f - fy) * (1.f - fx) * vy0 * vx0 * m;
      const float w01 = (1.f - fy) * fx * vy0 * vx1 * m;
      const float w10 = fy * (1.f - fx) * vy1 * vx0 * m;
      const float w11 = fy * fx * vy1 * vx1 * m;
      const float* wk = &wg[k * 64];
      const int ly = y0 - ty0 + 2, lxw = x0 - tx0 + 2;
      if ((unsigned)ly < 11u && (unsigned)lxw < 19u) {
        const u16* base = &s_x[ly * 20 + lxw][gl * 8];
        const bf16x8 c00 = *(const bf16x8*)base;
        const bf16x8 c01 = *(const bf16x8*)(base + 40);
        const bf16x8 c10 = *(const bf16x8*)(base + 800);
        const bf16x8 c11 = *(const bf16x8*)(base + 840);
#pragma unroll
        for (int c = 0; c < 8; ++c) {
          const float s = w00 * (float)c00[c] + w01 * (float)c01[c]
                        + w10 * (float)c10[c] + w11 * (float)c11[c];
          const float4 wv0 = *(const float4*)&wk[c * 8];
          const float4 wv1 = *(const float4*)&wk[c * 8 + 4];
          acc[0] = fmaf(s, wv0.x, acc[0]); acc[1] = fmaf(s, wv0.y, acc[1]);
          acc[2] = fmaf(s, wv0.z, acc[2]); acc[3] = fmaf(s, wv0.w, acc[3]);
          acc[4] = fmaf(s, wv1.x, acc[4]); acc[5] = fmaf(s, wv1.y, acc[5]);
          acc[6] = fmaf(s, wv1.z, acc[6]); acc[7] = fmaf(s, wv1.w, acc[7]);
        }
      } else {
        const int cy0 = min(max(y0, 0), Hh - 1), cy1 = min(max(y1, 0), Hh - 1);
        const int cx0 = min(max(x0, 0), Ww - 1), cx1 = min(max(x1, 0), Ww - 1);
        const int i00 = (cy0 * Ww + cx0) * 64, i01 = (cy0 * Ww + cx1) * 64;
        const int i10 = (cy1 * Ww + cx0) * 64, i11 = (cy1 * Ww + cx1) * 64;
#pragma unroll
        for (int c = 0; c < 8; ++c) {
          const float s = w00 * bf2f(xg[i00 + c]) + w01 * bf2f(xg[i01 + c])
                        + w10 * bf2f(xg[i10 + c]) + w11 * bf2f(xg[i11 + c]);
          const float4 wv0 = *(const float4*)&wk[c * 8];
          const float4 wv1 = *(const float4*)&wk[c * 8 + 4];
          acc[0] = fmaf(s, wv0.x, acc[0]); acc[1] = fmaf(s, wv0.y, acc[1]);
          acc[2] = fmaf(s, wv0.z, acc[2]); acc[3] = fmaf(s, wv0.w, acc[3]);
          acc[4] = fmaf(s, wv1.x, acc[4]); acc[5] = fmaf(s, wv1.y, acc[5]);
          acc[6] = fmaf(s, wv1.z, acc[6]); acc[7] = fmaf(s, wv1.w, acc[7]);
        }
      }
    }
#pragma unroll
    for (int o = 0; o < 8; ++o) {
      float v = acc[o];
      if (act) v = v >= 0.f ? v : 0.1f * v;
      og[(size_t)o * HW] = v;
    }
  }
}

__global__ __launch_bounds__(TPB, 4)
void k_dconv_one(DJob j, int Hh, int Ww)
{
  __shared__ __align__(16) u16 s_x[240][40];
  __shared__ __align__(16) float s_w[4 * 9 * 64];
  __shared__ float s_b[32];
  dconv_core(j, blockIdx.y, Hh, Ww, s_x, s_w, s_b);
}

__global__ __launch_bounds__(TPB, 4)
void k_dconv_dual(DJob a, DJob b, int Hh, int Ww)
{
  __shared__ __align__(16) u16 s_x[240][40];
  __shared__ __align__(16) float s_w[4 * 9 * 64];
  __shared__ float s_b[32];
  const DJob& j = (blockIdx.y & 1) ? b : a;
  dconv_core(j, blockIdx.y >> 1, Hh, Ww, s_x, s_w, s_b);
}

// ---------------------------------------------------------------------------
// host helpers
// ---------------------------------------------------------------------------
static void conv3(hipStream_t st, int variant,
                  const void* in1, int c1, const void* in2, int c2,
                  const u16* wbuf, const float* bias, float* outf, u16* outb,
                  int Cout, int h, int wd)
{
  int cocols = (Cout + 63) / 64, Coutpad = cocols * 64;
  bool th8 = (h >= 96);
  int TH = th8 ? 8 : 16;
  dim3 grid((h / TH) * (wd / 16), cocols, 2);
  if (th8) {
    switch (variant) {
      case 0: k_conv<1,1,1,1,8><<<grid, TPB, 0, st>>>(in1, c1, in2, c2, wbuf, bias, outf, outb, Cout, Coutpad, h, wd); break;
      case 3: k_conv<0,1,1,2,8><<<grid, TPB, 0, st>>>(in1, c1, in2, c2, wbuf, bias, outf, outb, Cout, Coutpad, h, wd); break;
      case 4: k_conv<2,1,1,2,8><<<grid, TPB, 0, st>>>(in1, c1, in2, c2, wbuf, bias, outf, outb, Cout, Coutpad, h, wd); break;
      case 6: k_conv<0,0,4,1,8><<<grid, TPB, 0, st>>>(in1, c1, in2, c2, wbuf, bias, outf, outb, Cout, Coutpad, h, wd); break;
      default: k_conv<1,0,4,0,8><<<grid, TPB, 0, st>>>(in1, c1, in2, c2, wbuf, bias, outf, outb, Cout, Coutpad, h, wd); break;
    }
  } else {
    switch (variant) {
      case 0: k_conv<1,1,1,1,16><<<grid, TPB, 0, st>>>(in1, c1, in2, c2, wbuf, bias, outf, outb, Cout, Coutpad, h, wd); break;
      case 3: k_conv<0,1,1,2,16><<<grid, TPB, 0, st>>>(in1, c1, in2, c2, wbuf, bias, outf, outb, Cout, Coutpad, h, wd); break;
      case 4: k_conv<2,1,1,2,16><<<grid, TPB, 0, st>>>(in1, c1, in2, c2, wbuf, bias, outf, outb, Cout, Coutpad, h, wd); break;
      case 6: k_conv<0,0,4,1,16><<<grid, TPB, 0, st>>>(in1, c1, in2, c2, wbuf, bias, outf, outb, Cout, Coutpad, h, wd); break;
      default: k_conv<1,0,4,0,16><<<grid, TPB, 0, st>>>(in1, c1, in2, c2, wbuf, bias, outf, outb, Cout, Coutpad, h, wd); break;
    }
  }
}

static CJob mkcjob(const void* i1, const void* i2, int c1, int c2, int m1, int m2,
                   const u16* w, const float* bias, float* outf, u16* outb,
                   int outmode, int act, int Cout, int h)
{
  CJob j; j.in1 = i1; j.in2 = i2; j.c1 = c1; j.c2 = c2; j.m1 = m1; j.m2 = m2;
  j.w = w; j.bias = bias; j.outf = outf; j.outb = outb; j.outmode = outmode;
  j.act = act; j.Cout = Cout; j.Coutpad = ((Cout + 63) / 64) * 64; j.h = h;
  return j;
}

static void jobs_launch(hipStream_t st, CJob a, CJob b)
{
  int ny0 = a.Coutpad / 64, ny1 = b.Coutpad / 64;
  int nbx0 = (a.h / 8) * (a.h / 16), nbx1 = (b.h / 8) * (b.h / 16);
  dim3 grid(max(nbx0, nbx1), ny0 + ny1, 2);
  k_conv_jobs<<<grid, TPB, 0, st>>>(a, b, ny0);
}

static PairJob mkpair(const u16* i1, const u16* i2, int c1, int c2, const u16* w,
                      const float* bias, u16* outb, int Cout, int Cpad,
                      int act, int chlast, int h)
{
  PairJob p; p.in1 = i1; p.in2 = i2; p.c1 = c1; p.c2 = c2; p.w = w; p.bias = bias;
  p.outb = outb; p.Cout = Cout; p.Coutpad = Cpad; p.act = act; p.chlast = chlast; p.h = h;
  return p;
}

static DJob mkdjob(const u16* xbf, const u16* off, const u16* mask, int maskC, int maskBase,
                   const float* w, const float* b, float* out, int sigm, int act)
{
  DJob j; j.xbf = xbf; j.off = off; j.mask = mask; j.maskC = maskC; j.maskBase = maskBase;
  j.wgt = w; j.bias = b; j.out = out; j.sigm = sigm; j.act = act;
  return j;
}

static void dconv_dual(hipStream_t st, DJob a, DJob b, int h, int wd)
{
  dim3 grid((h / 8) * (wd / 16), 4, 2);
  k_dconv_dual<<<grid, TPB, 0, st>>>(a, b, h, wd);
}

static void dconv_one(hipStream_t st, DJob a, int h, int wd)
{
  dim3 grid((h / 8) * (wd / 16), 2, 2);
  k_dconv_one<<<grid, TPB, 0, st>>>(a, h, wd);
}

extern "C" void kernel_launch(void* const* d_in, const int* in_sizes, int n_in,
                              void* d_out, int out_size, void* d_ws, size_t ws_size,
                              hipStream_t stream)
{
  const float* const* in = (const float* const*)d_in;

  const int HW0 = 192 * 192, HW1 = 96 * 96, HW2 = 48 * 48;
  const size_t N0 = (size_t)2 * HW0 * 64, N1 = (size_t)2 * HW1 * 64, N2 = (size_t)2 * HW2 * 64;

  // ---- workspace layout ----
  u16* p = (u16*)d_ws;
  u16* nrf0b = p; p += N0;
  u16* rf0b  = p; p += N0;
  u16* swf0b = p; p += N0;
  u16* nrf1b = p; p += N1;
  u16* rf1b  = p; p += N1;
  u16* swf1b = p; p += N1;
  u16* nrf2b = p; p += N2;
  u16* rf2b  = p; p += N2;
  u16* swf2b = p; p += N2;
  u16* A0bf  = p; p += N0;
  u16* A1bf  = p; p += N1;
  u16* A2bf  = p; p += N2;
  u16* OM0   = p; p += (size_t)2 * 216 * HW0;
  u16* OM1   = p; p += (size_t)2 * 216 * HW1;
  u16* OM2   = p; p += (size_t)2 * 216 * HW2;
  u16* EM    = p; p += (size_t)2 * 72 * HW0;
  u16* OF0bf = p; p += N0;
  u16* DN0bf = p; p += N0;
  p = (u16*)(((uintptr_t)p + 15) & ~(uintptr_t)15);
  float* XD   = (float*)p;
  float* DN1  = XD + (size_t)2 * 64 * HW0;
  u16* wp = (u16*)(DN1 + (size_t)2 * 64 * HW1);

  float* dout = (float*)d_out;
  const size_t L0 = (size_t)2 * 64 * HW0;
  float* out0 = dout;
  float* sh0  = dout + L0;
  float* sh1  = sh0  + L0;
  float* sh2  = sh1  + L0 / 4;
  // d_out dead-region aliases:
  u16*   Bbf   = (u16*)out0;                                 // overwritten by final dconv
  u16*   OF1bf = (u16*)sh0;                                  // dead before dual0 writes sh0
  u16*   OF2bf = OF1bf + N1;
  float* DN2   = (float*)(OF2bf + N2);

  // ---- input conversion ----
  {
    ToBfArgs ta;
    const float* srcs[9] = {in[0], in[1], in[2], in[3], in[4], in[5], in[6], in[7], in[8]};
    u16* dsts[9] = {nrf0b, rf0b, swf0b, nrf1b, rf1b, swf1b, nrf2b, rf2b, swf2b};
    const int hws[9] = {HW0, HW0, HW0, HW1, HW1, HW1, HW2, HW2, HW2};
    for (int i = 0; i < 9; ++i) { ta.src[i] = srcs[i]; ta.dst[i] = dsts[i]; ta.hw[i] = hws[i]; }
    int maxtot = 2 * HW0 * 8;
    k_tobf_all<<<dim3((maxtot + TPB - 1) / TPB, 9), TPB, 0, stream>>>(ta);
  }

  // ---- weight prep ----
  struct { int arg, cin, cout; } plist[22] = {
    {9,128,64},{11,64,64},{13,64,216},{15,128,64},{17,64,72},
    {21,128,64},{23,64,64},{25,64,216},{27,128,64},{29,64,72},
    {33,128,64},{35,64,64},{37,64,216},{39,128,64},{41,64,72},
    {45,128,64},{47,128,64},{49,128,64},{51,128,64},
    {53,128,64},{55,64,64},{57,64,216}};
  WPrepArgs wa;
  u16* wptr[22];
  int maxtot = 0;
  for (int i = 0; i < 22; ++i) {
    int cin = plist[i].cin, cout = plist[i].cout;
    int cpad = ((cout + 63) / 64) * 64;
    int tot = (cin / 32) * 9 * cpad * 40;
    wa.src[i] = in[plist[i].arg]; wa.dst[i] = wp;
    wa.cin[i] = cin; wa.cout[i] = cout; wa.coutpad[i] = cpad; wa.total[i] = tot;
    wptr[i] = wp; wp += tot;
    if (tot > maxtot) maxtot = tot;
  }
  k_wprep_all<<<dim3((maxtot + TPB - 1) / TPB, 22), TPB, 0, stream>>>(wa);

  u16* w_ocf0 = wptr[0];  u16* w_ocl0 = wptr[1];  u16* w_com0 = wptr[2];
  u16* w_em10 = wptr[3];  u16* w_em20 = wptr[4];
  u16* w_ocf1 = wptr[5];  u16* w_ocl1 = wptr[6];  u16* w_com1 = wptr[7];
  u16* w_em11 = wptr[8];  u16* w_em21 = wptr[9];
  u16* w_ocf2 = wptr[10]; u16* w_ocl2 = wptr[11]; u16* w_com2 = wptr[12];
  u16* w_em12 = wptr[13]; u16* w_em22 = wptr[14];
  u16* w_occ0 = wptr[15]; u16* w_fcc0 = wptr[16];
  u16* w_occ1 = wptr[17]; u16* w_fcc1 = wptr[18];
  u16* w_cas1 = wptr[19]; u16* w_cas2 = wptr[20]; u16* w_casc = wptr[21];

  const int h2 = 48, h1 = 96, h0 = 192;

  // ---- tri-level mega-pair (TH=8): all ocf_i + com_i ----
  {
    PairJob a0 = mkpair(nrf0b, rf0b, 64, 64, w_ocf0, in[10], A0bf, 64, 64, 1, 1, h0);
    PairJob b0 = mkpair(swf0b, nullptr, 64, 0, w_com0, in[14], OM0, 216, 256, 0, 0, h0);
    PairJob a1 = mkpair(nrf1b, rf1b, 64, 64, w_ocf1, in[22], A1bf, 64, 64, 1, 1, h1);
    PairJob b1 = mkpair(swf1b, nullptr, 64, 0, w_com1, in[26], OM1, 216, 256, 0, 0, h1);
    PairJob a2 = mkpair(nrf2b, rf2b, 64, 64, w_ocf2, in[34], A2bf, 64, 64, 1, 1, h2);
    PairJob b2 = mkpair(swf2b, nullptr, 64, 0, w_com2, in[38], OM2, 216, 256, 0, 0, h2);
    dim3 grid(288, 15, 2);
    k_conv_tri<<<grid, TPB, 0, stream>>>(a0, b0, a1, b1, a2, b2);
  }

  // ocl2 (48²)
  conv3(stream, 0, A2bf, 64, nullptr, 0, w_ocl2, in[36], nullptr, OF2bf, 64, h2, h2);
  // p1: em12(48) + occ1(96, fused chlast up2)
  jobs_launch(stream,
    mkcjob(OF2bf, swf2b, 64, 64, 1, 1, w_em12, in[40], nullptr, A2bf, 1, 1, 64, h2),
    mkcjob(A1bf,  OF2bf, 64, 64, 1, 3, w_occ1, in[50], nullptr, Bbf,  1, 1, 64, h1));
  // p2: em22(48, sigmoid->EM planar) + ocl1(96)
  jobs_launch(stream,
    mkcjob(A2bf, nullptr, 64, 0, 1, 1, w_em22, in[42], nullptr, EM,    2, 2, 72, h2),
    mkcjob(Bbf,  nullptr, 64, 0, 1, 1, w_ocl1, in[24], nullptr, OF1bf, 1, 1, 64, h1));
  // dual2: sh2 + xd2
  dconv_dual(stream,
             mkdjob(OF2bf, OM2, EM,  72, 0,   in[43], in[44], sh2, 0, 0),
             mkdjob(nrf2b, OM2, OM2, 216, 144, in[43], in[44], DN2, 1, 1), h2, h2);
  // p3: em11(96) + occ0(192, fused chlast up2)
  jobs_launch(stream,
    mkcjob(OF1bf, swf1b, 64, 64, 1, 1, w_em11, in[28], nullptr, A1bf, 1, 1, 64, h1),
    mkcjob(A0bf,  OF1bf, 64, 64, 1, 3, w_occ0, in[46], nullptr, Bbf,  1, 1, 64, h0));
  // p4: em21(96, sigmoid->EM) + ocl0(192)
  jobs_launch(stream,
    mkcjob(A1bf, nullptr, 64, 0, 1, 1, w_em21, in[30], nullptr, EM,    2, 2, 72, h1),
    mkcjob(Bbf,  nullptr, 64, 0, 1, 1, w_ocl0, in[12], nullptr, OF0bf, 1, 1, 64, h0));
  // dual1: sh1 + xd1
  dconv_dual(stream,
             mkdjob(OF1bf, OM1, EM,  72, 0,   in[31], in[32], sh1, 0, 0),
             mkdjob(nrf1b, OM1, OM1, 216, 144, in[31], in[32], XD, 1, 0), h1, h1);
  // p5: em10(192) + fcc1(96, fp32 + fp32-up2 -> fp32)
  jobs_launch(stream,
    mkcjob(OF0bf, swf0b, 64, 64, 1, 1, w_em10, in[16], nullptr, Bbf, 1, 1, 64, h0),
    mkcjob(XD,    DN2,   64, 64, 0, 4, w_fcc1, in[52], DN1, nullptr, 0, 1, 64, h1));
  // em20 (192, sigmoid->EM)
  conv3(stream, 4, Bbf, 64, nullptr, 0, w_em20, in[18], nullptr, EM, 72, h0, h0);
  // dual0: sh0 + xd0
  dconv_dual(stream,
             mkdjob(OF0bf, OM0, EM,  72, 0,   in[19], in[20], sh0, 0, 0),
             mkdjob(nrf0b, OM0, OM0, 216, 144, in[19], in[20], XD, 1, 0), h0, h0);
  // fcc0 (fp32 + fp32-up2 -> chlast)
  conv3(stream, 6, XD, 64, DN1, 64, w_fcc0, in[48], nullptr, DN0bf, 64, h0, h0);
  // cascade
  conv3(stream, 0, DN0bf, 64, rf0b, 64,  w_cas1, in[54], nullptr, A0bf, 64, h0, h0);
  conv3(stream, 0, A0bf,  64, nullptr,0, w_cas2, in[56], nullptr, Bbf,  64, h0, h0);
  conv3(stream, 3, Bbf,   64, nullptr,0, w_casc, in[58], nullptr, OM0, 216, h0, h0);
  dconv_one(stream,
            mkdjob(DN0bf, OM0, OM0, 216, 144, in[59], in[60], out0, 1, 1), h0, h0);
}

// Round 25
// 566.315 us; speedup vs baseline: 2.9652x; 1.0882x over previous
//
#include <hip/hip_runtime.h>
#include <cstddef>
#include <cstdint>

#define TPB 256

typedef unsigned int u32;
typedef unsigned short u16;
typedef __bf16 bf16x8 __attribute__((ext_vector_type(8)));
typedef float f32x4 __attribute__((ext_vector_type(4)));

template<int ACT>
__device__ __forceinline__ float act_f(float v) {
  if (ACT == 1) return v >= 0.f ? v : 0.1f * v;
  if (ACT == 2) return 1.f / (1.f + expf(-v));
  return v;
}
__device__ __forceinline__ float act_rt(float v, int a) {
  if (a == 1) return v >= 0.f ? v : 0.1f * v;
  if (a == 2) return 1.f / (1.f + expf(-v));
  return v;
}

__device__ __forceinline__ u16 f2bf(float f) {
  __bf16 h = (__bf16)f;
  return __builtin_bit_cast(u16, h);
}
__device__ __forceinline__ float bf2f(u16 h) {
  return __uint_as_float(((u32)h) << 16);
}
__device__ __forceinline__ u32 pk2bf(float a, float b) {
  return (u32)f2bf(a) | ((u32)f2bf(b) << 16);
}

// ---------------------------------------------------------------------------
// Weight prefetch regs (T14 async-STAGE: issue loads early, ds_write late).
// ---------------------------------------------------------------------------
struct WReg { uint4 v[4]; };

__device__ __forceinline__ WReg wload(const u16* __restrict__ w, size_t base,
                                      size_t tapstride, int tid)
{
  WReg r;
#pragma unroll
  for (int k = 0; k < 4; ++k) {
    const int i = tid + k * TPB;
    if (i < 960) {
      const int kxl = i / 320, jj = i - kxl * 320;
      r.v[k] = *(const uint4*)&w[base + (size_t)kxl * tapstride + jj * 8];
    }
  }
  return r;
}

__device__ __forceinline__ void wstore(u16* s_w, const WReg& r, int tid)
{
#pragma unroll
  for (int k = 0; k < 4; ++k) {
    const int i = tid + k * TPB;
    if (i < 960) {
      const int kxl = i / 320, jj = i - kxl * 320;
      *(uint4*)&s_w[kxl * 2560 + jj * 8] = r.v[k];
    }
  }
}

// ---------------------------------------------------------------------------
// Weight prep (one launch, 22 convs)
// ---------------------------------------------------------------------------
struct WPrepArgs {
  const float* src[22];
  u16* dst[22];
  int cin[22], cout[22], coutpad[22], total[22];
};

__global__ void k_wprep_all(WPrepArgs a)
{
  const int seg = blockIdx.y;
  const int idx = blockIdx.x * TPB + threadIdx.x;
  if (idx >= a.total[seg]) return;
  const int Cin = a.cin[seg], Cout = a.cout[seg], Coutpad = a.coutpad[seg];
  int kk = idx % 40; int t = idx / 40;
  int co = t % Coutpad; t /= Coutpad;
  int tap = t % 9; int kc = t / 9;
  u16 v = 0;
  if (kk < 32 && co < Cout)
    v = f2bf(a.src[seg][((size_t)co * Cin + kc * 32 + kk) * 9 + tap]);
  a.dst[seg][idx] = v;
}

// ---------------------------------------------------------------------------
// Input prep
// ---------------------------------------------------------------------------
struct ToBfArgs {
  const float* src[9];
  u16* dst[9];
  int hw[9];
};

__global__ void k_tobf_all(ToBfArgs a)
{
  const int seg = blockIdx.y;
  const int hw = a.hw[seg];
  const int total = 2 * hw * 8;
  int idx = blockIdx.x * TPB + threadIdx.x;
  if (idx >= total) return;
  const int g8 = idx & 7;
  int t = idx >> 3;
  const int pos = t % hw, b = t / hw;
  const float* s = a.src[seg] + ((size_t)b * 64 + g8 * 8) * hw + pos;
  u32 w0 = pk2bf(s[0], s[(size_t)hw]);
  u32 w1 = pk2bf(s[(size_t)2 * hw], s[(size_t)3 * hw]);
  u32 w2 = pk2bf(s[(size_t)4 * hw], s[(size_t)5 * hw]);
  u32 w3 = pk2bf(s[(size_t)6 * hw], s[(size_t)7 * hw]);
  *(uint4*)&a.dst[seg][((size_t)b * hw + pos) * 64 + g8 * 8] = make_uint4(w0, w1, w2, w3);
}

// ---------------------------------------------------------------------------
// Shared staging helper. modes: 0 fp32 planar | 1 chlast | 3 chlast half-res
// up2 | 4 fp32 planar half-res up2
// ---------------------------------------------------------------------------
__device__ __forceinline__ void stage_act(u16* s_act, int NPOS, int mode,
                                          const void* in1v, int c1,
                                          const void* in2v, int c2,
                                          bool use1, int kc, int nk1,
                                          int b, int by0, int bx0, int Hh, int Ww, int tid)
{
  const int HW = Hh * Ww;
  if (mode == 0) {
    const float* sp = use1
      ? (const float*)in1v + ((size_t)b * c1 + (kc << 5)) * HW
      : (const float*)in2v + ((size_t)b * c2 + ((kc - nk1) << 5)) * HW;
#pragma unroll 1
    for (int u = tid; u < NPOS; u += TPB) {
      int y = u / 18, x = u - y * 18;
      int gy = by0 - 1 + y, gx = bx0 - 1 + x;
      bool inb = ((unsigned)gy < (unsigned)Hh) & ((unsigned)gx < (unsigned)Ww);
      const float msk = inb ? 1.f : 0.f;
      const size_t poff = inb ? ((size_t)gy * Ww + gx) : 0;
      const float* s0 = sp + poff;
      u16* dp = &s_act[u * 40];
#pragma unroll
      for (int c8 = 0; c8 < 4; ++c8) {
        u32 hb[4];
#pragma unroll
        for (int j = 0; j < 4; ++j)
          hb[j] = pk2bf(s0[(size_t)(c8 * 8 + 2 * j) * HW] * msk,
                        s0[(size_t)(c8 * 8 + 2 * j + 1) * HW] * msk);
        *(uint4*)&dp[c8 * 8] = make_uint4(hb[0], hb[1], hb[2], hb[3]);
      }
    }
  } else if (mode == 3) {
    const u16* b2 = (const u16*)in2v;
    const int hh = Hh >> 1, hw = Ww >> 1;
    const int cofs = (kc - nk1) << 5;
#pragma unroll 1
    for (int u = tid; u < NPOS; u += TPB) {
      int y = u / 18, x = u - y * 18;
      int gy = by0 - 1 + y, gx = bx0 - 1 + x;
      u16* dp = &s_act[u * 40];
      if ((unsigned)gy < (unsigned)Hh && (unsigned)gx < (unsigned)Ww) {
        int iy0, iy1, ix0, ix1; float wy0, wy1, wx0, wx1;
        if (gy & 1) { iy0 = gy >> 1; iy1 = min(iy0 + 1, hh - 1); wy0 = 0.75f; wy1 = 0.25f; }
        else        { iy1 = gy >> 1; iy0 = max(iy1 - 1, 0);      wy0 = 0.25f; wy1 = 0.75f; }
        if (gx & 1) { ix0 = gx >> 1; ix1 = min(ix0 + 1, hw - 1); wx0 = 0.75f; wx1 = 0.25f; }
        else        { ix1 = gx >> 1; ix0 = max(ix1 - 1, 0);      wx0 = 0.25f; wx1 = 0.75f; }
        const u16* pb = b2 + (size_t)b * hh * hw * 64 + cofs;
#pragma unroll
        for (int q = 0; q < 4; ++q) {
          const bf16x8 a00 = *(const bf16x8*)&pb[(size_t)(iy0 * hw + ix0) * 64 + q * 8];
          const bf16x8 a01 = *(const bf16x8*)&pb[(size_t)(iy0 * hw + ix1) * 64 + q * 8];
          const bf16x8 a10 = *(const bf16x8*)&pb[(size_t)(iy1 * hw + ix0) * 64 + q * 8];
          const bf16x8 a11 = *(const bf16x8*)&pb[(size_t)(iy1 * hw + ix1) * 64 + q * 8];
          u32 r[4];
#pragma unroll
          for (int j = 0; j < 4; ++j) {
            float v0 = wy0 * (wx0 * (float)a00[2 * j] + wx1 * (float)a01[2 * j])
                     + wy1 * (wx0 * (float)a10[2 * j] + wx1 * (float)a11[2 * j]);
            float v1 = wy0 * (wx0 * (float)a00[2 * j + 1] + wx1 * (float)a01[2 * j + 1])
                     + wy1 * (wx0 * (float)a10[2 * j + 1] + wx1 * (float)a11[2 * j + 1]);
            r[j] = pk2bf(v0, v1);
          }
          *(uint4*)&dp[q * 8] = make_uint4(r[0], r[1], r[2], r[3]);
        }
      } else {
#pragma unroll
        for (int q = 0; q < 4; ++q)
          *(uint4*)&dp[q * 8] = make_uint4(0u, 0u, 0u, 0u);
      }
    }
  } else if (mode == 4) {
    const float* f2 = (const float*)in2v;
    const int hh = Hh >> 1, hw = Ww >> 1;
    const int cofs = (kc - nk1) << 5;
    const int hhw = hh * hw;
#pragma unroll 1
    for (int u = tid; u < NPOS; u += TPB) {
      int y = u / 18, x = u - y * 18;
      int gy = by0 - 1 + y, gx = bx0 - 1 + x;
      u16* dp = &s_act[u * 40];
      if ((unsigned)gy < (unsigned)Hh && (unsigned)gx < (unsigned)Ww) {
        int iy0, iy1, ix0, ix1; float wy0, wy1, wx0, wx1;
        if (gy & 1) { iy0 = gy >> 1; iy1 = min(iy0 + 1, hh - 1); wy0 = 0.75f; wy1 = 0.25f; }
        else        { iy1 = gy >> 1; iy0 = max(iy1 - 1, 0);      wy0 = 0.25f; wy1 = 0.75f; }
        if (gx & 1) { ix0 = gx >> 1; ix1 = min(ix0 + 1, hw - 1); wx0 = 0.75f; wx1 = 0.25f; }
        else        { ix1 = gx >> 1; ix0 = max(ix1 - 1, 0);      wx0 = 0.25f; wx1 = 0.75f; }
        const float* pb = f2 + ((size_t)b * 64 + cofs) * hhw;
        const int i00 = iy0 * hw + ix0, i01 = iy0 * hw + ix1;
        const int i10 = iy1 * hw + ix0, i11 = iy1 * hw + ix1;
#pragma unroll
        for (int q = 0; q < 4; ++q) {
          u32 r[4];
#pragma unroll
          for (int j = 0; j < 4; ++j) {
            const float* p0 = pb + (size_t)(q * 8 + 2 * j) * hhw;
            const float* p1 = pb + (size_t)(q * 8 + 2 * j + 1) * hhw;
            float v0 = wy0 * (wx0 * p0[i00] + wx1 * p0[i01])
                     + wy1 * (wx0 * p0[i10] + wx1 * p0[i11]);
            float v1 = wy0 * (wx0 * p1[i00] + wx1 * p1[i01])
                     + wy1 * (wx0 * p1[i10] + wx1 * p1[i11]);
            r[j] = pk2bf(v0, v1);
          }
          *(uint4*)&dp[q * 8] = make_uint4(r[0], r[1], r[2], r[3]);
        }
      } else {
#pragma unroll
        for (int q = 0; q < 4; ++q)
          *(uint4*)&dp[q * 8] = make_uint4(0u, 0u, 0u, 0u);
      }
    }
  } else {
    const u16* src; int cofs, cst;
    if (use1) { src = (const u16*)in1v + (size_t)b * HW * c1; cofs = kc << 5; cst = c1; }
    else      { src = (const u16*)in2v + (size_t)b * HW * c2; cofs = (kc - nk1) << 5; cst = c2; }
#pragma unroll 1
    for (int i = tid; i < NPOS * 4; i += TPB) {
      int u = i >> 2, q = i & 3;
      int y = u / 18, x = u - y * 18;
      int gy = by0 - 1 + y, gx = bx0 - 1 + x;
      uint4 v = make_uint4(0u, 0u, 0u, 0u);
      if ((unsigned)gy < (unsigned)Hh && (unsigned)gx < (unsigned)Ww)
        v = *(const uint4*)&src[(size_t)(gy * Ww + gx) * cst + cofs + q * 8];
      *(uint4*)&s_act[u * 40 + q * 8] = v;
    }
  }
}

// ---------------------------------------------------------------------------
// 3x3 conv via MFMA bf16 (templated single-job), weight-prefetch pipeline:
// phase p = (kc,ky); loads for p+1 issued before MFMA of p (T14 split).
// ---------------------------------------------------------------------------
template<int ACT, int M1, int M2, int OUTBF, int TH>
__global__ __launch_bounds__(TPB, (TH == 8 ? 4 : 3))
void k_conv(const void* __restrict__ in1v, int c1,
            const void* __restrict__ in2v, int c2,
            const u16* __restrict__ wbuf, const float* __restrict__ bias,
            float* __restrict__ outf, u16* __restrict__ outb,
            int Cout, int Coutpad, int Hh, int Ww)
{
  constexpr int NPOS = (TH + 2) * 18;
  constexpr int NPG  = TH / 4;
  __shared__ __align__(16) u16 s_mem[NPOS * 40 + 3 * 64 * 40];
  u16* s_act = s_mem;
  u16* s_w   = s_mem + NPOS * 40;
  const int nkc = (c1 + c2) >> 5, nk1 = c1 >> 5;
  const int b   = blockIdx.z;
  const int cb  = blockIdx.y << 6;
  const int xt  = Ww >> 4;
  const int by0 = (blockIdx.x / xt) * TH;
  const int bx0 = (blockIdx.x % xt) << 4;
  const int tid = threadIdx.x;
  const int lx = tid & 15, slot = (tid >> 4) & 3, wv = tid >> 6;
  const int HW = Hh * Ww;

  f32x4 acc[4][NPG];
#pragma unroll
  for (int i = 0; i < 4; ++i)
#pragma unroll
    for (int j = 0; j < NPG; ++j) acc[i][j] = (f32x4){0.f, 0.f, 0.f, 0.f};

  const size_t tapstride = (size_t)Coutpad * 40;
  const int P = nkc * 3;
  // prologue: act(kc=0) + w(phase 0)
  stage_act(s_act, NPOS, (0 < nk1 ? M1 : M2), in1v, c1, in2v, c2, 0 < nk1, 0, nk1,
            b, by0, bx0, Hh, Ww, tid);
  WReg r = wload(wbuf, ((size_t)0 * Coutpad + cb) * 40, tapstride, tid);
  wstore(s_w, r, tid);
  __syncthreads();

#pragma unroll 1
  for (int p = 0; p < P; ++p) {
    const int kc = p / 3, ky = p - kc * 3;
    if (p + 1 < P) {
      const int kcn = (p + 1) / 3, kyn = (p + 1) - kcn * 3;
      r = wload(wbuf, ((size_t)(kcn * 9 + kyn * 3) * Coutpad + cb) * 40, tapstride, tid);
    }
#pragma unroll
    for (int kx = 0; kx < 3; ++kx) {
      bf16x8 Af[4], Bf[NPG];
#pragma unroll
      for (int ct = 0; ct < 4; ++ct)
        Af[ct] = *(const bf16x8*)&s_w[(kx * 64 + ct * 16 + lx) * 40 + slot * 8];
#pragma unroll
      for (int pg = 0; pg < NPG; ++pg)
        Bf[pg] = *(const bf16x8*)&s_act[((wv * NPG + pg + ky) * 18 + lx + kx) * 40 + slot * 8];
#pragma unroll
      for (int ct = 0; ct < 4; ++ct)
#pragma unroll
        for (int pg = 0; pg < NPG; ++pg)
          acc[ct][pg] = __builtin_amdgcn_mfma_f32_16x16x32_bf16(Af[ct], Bf[pg], acc[ct][pg], 0, 0, 0);
    }
    __syncthreads();
    if (p + 1 < P) {
      if (ky == 2) {
        const int k2 = kc + 1;
        stage_act(s_act, NPOS, (k2 < nk1 ? M1 : M2), in1v, c1, in2v, c2, k2 < nk1, k2, nk1,
                  b, by0, bx0, Hh, Ww, tid);
      }
      wstore(s_w, r, tid);
      __syncthreads();
    }
  }
  const int ox = bx0 + lx;
  if (OUTBF == 1) {
    __syncthreads();
#pragma unroll
    for (int ct = 0; ct < 4; ++ct) {
      const int co0 = ct * 16 + slot * 4;
      const float b0 = bias[co0], b1 = bias[co0 + 1], b2 = bias[co0 + 2], b3 = bias[co0 + 3];
#pragma unroll
      for (int pg = 0; pg < NPG; ++pg) {
        const int px = (wv * NPG + pg) * 16 + lx;
        *(u32*)&s_mem[px * 72 + co0]     = pk2bf(act_f<ACT>(acc[ct][pg][0] + b0),
                                                 act_f<ACT>(acc[ct][pg][1] + b1));
        *(u32*)&s_mem[px * 72 + co0 + 2] = pk2bf(act_f<ACT>(acc[ct][pg][2] + b2),
                                                 act_f<ACT>(acc[ct][pg][3] + b3));
      }
    }
    __syncthreads();
#pragma unroll 1
    for (int l = tid; l < TH * 16 * 8; l += TPB) {
      const int px = l >> 3, ch = (l & 7) * 8;
      const int row = px >> 4, col = px & 15;
      const uint4 v = *(const uint4*)&s_mem[px * 72 + ch];
      *(uint4*)&outb[(((size_t)b * HW + (size_t)(by0 + row) * Ww + bx0 + col) << 6) + ch] = v;
    }
  } else if (OUTBF == 2) {
#pragma unroll
    for (int ct = 0; ct < 4; ++ct) {
      const int co0 = cb + ct * 16 + slot * 4;
#pragma unroll
      for (int r2 = 0; r2 < 4; ++r2) {
        const int co = co0 + r2;
        if (co < Cout) {
          const float bv = bias[co];
          u16* op = outb + ((size_t)b * Cout + co) * HW + (size_t)(by0 + wv * NPG) * Ww + ox;
#pragma unroll
          for (int pg = 0; pg < NPG; ++pg)
            op[pg * Ww] = f2bf(act_f<ACT>(acc[ct][pg][r2] + bv));
        }
      }
    }
  } else {
#pragma unroll
    for (int ct = 0; ct < 4; ++ct) {
      const int co0 = cb + ct * 16 + slot * 4;
#pragma unroll
      for (int r2 = 0; r2 < 4; ++r2) {
        const int co = co0 + r2;
        if (co < Cout) {
          const float bv = bias[co];
          float* op = outf + ((size_t)b * Cout + co) * HW + (size_t)(by0 + wv * NPG) * Ww + ox;
#pragma unroll
          for (int pg = 0; pg < NPG; ++pg)
            op[pg * Ww] = act_f<ACT>(acc[ct][pg][r2] + bv);
        }
      }
    }
  }
}

// ---------------------------------------------------------------------------
// Runtime 2-job conv kernel (TH=8), weight-prefetch pipeline.
// ---------------------------------------------------------------------------
struct CJob {
  const void* in1; const void* in2; int c1, c2, m1, m2;
  const u16* w; const float* bias;
  float* outf; u16* outb; int outmode, act, Cout, Coutpad, h;
};

__global__ __launch_bounds__(TPB, 4)
void k_conv_jobs(CJob A, CJob B, int ny0)
{
  constexpr int TH = 8, NPOS = 180, NPG = 2;
  __shared__ __align__(16) u16 s_mem[NPOS * 40 + 3 * 64 * 40];
  u16* s_act = s_mem;
  u16* s_w   = s_mem + NPOS * 40;
  const bool isA = (int)blockIdx.y < ny0;
  const CJob j = isA ? A : B;
  const int cb = (isA ? blockIdx.y : blockIdx.y - ny0) << 6;
  const int Hh = j.h, Ww = j.h;
  const int xt = Ww >> 4;
  const int nbx = (Hh >> 3) * xt;
  if ((int)blockIdx.x >= nbx) return;
  const int c1 = j.c1, c2 = j.c2;
  const int nkc = (c1 + c2) >> 5, nk1 = c1 >> 5;
  const int b   = blockIdx.z;
  const int by0 = (blockIdx.x / xt) * TH;
  const int bx0 = (blockIdx.x % xt) << 4;
  const int tid = threadIdx.x;
  const int lx = tid & 15, slot = (tid >> 4) & 3, wv = tid >> 6;
  const int HW = Hh * Ww;

  f32x4 acc[4][NPG];
#pragma unroll
  for (int i = 0; i < 4; ++i)
#pragma unroll
    for (int jj = 0; jj < NPG; ++jj) acc[i][jj] = (f32x4){0.f, 0.f, 0.f, 0.f};

  const size_t tapstride = (size_t)j.Coutpad * 40;
  const int P = nkc * 3;
  stage_act(s_act, NPOS, (0 < nk1 ? j.m1 : j.m2), j.in1, c1, j.in2, c2, 0 < nk1, 0, nk1,
            b, by0, bx0, Hh, Ww, tid);
  WReg r = wload(j.w, ((size_t)0 * j.Coutpad + cb) * 40, tapstride, tid);
  wstore(s_w, r, tid);
  __syncthreads();

#pragma unroll 1
  for (int p = 0; p < P; ++p) {
    const int kc = p / 3, ky = p - kc * 3;
    if (p + 1 < P) {
      const int kcn = (p + 1) / 3, kyn = (p + 1) - kcn * 3;
      r = wload(j.w, ((size_t)(kcn * 9 + kyn * 3) * j.Coutpad + cb) * 40, tapstride, tid);
    }
#pragma unroll
    for (int kx = 0; kx < 3; ++kx) {
      bf16x8 Af[4], Bf[NPG];
#pragma unroll
      for (int ct = 0; ct < 4; ++ct)
        Af[ct] = *(const bf16x8*)&s_w[(kx * 64 + ct * 16 + lx) * 40 + slot * 8];
#pragma unroll
      for (int pg = 0; pg < NPG; ++pg)
        Bf[pg] = *(const bf16x8*)&s_act[((wv * NPG + pg + ky) * 18 + lx + kx) * 40 + slot * 8];
#pragma unroll
      for (int ct = 0; ct < 4; ++ct)
#pragma unroll
        for (int pg = 0; pg < NPG; ++pg)
          acc[ct][pg] = __builtin_amdgcn_mfma_f32_16x16x32_bf16(Af[ct], Bf[pg], acc[ct][pg], 0, 0, 0);
    }
    __syncthreads();
    if (p + 1 < P) {
      if (ky == 2) {
        const int k2 = kc + 1;
        stage_act(s_act, NPOS, (k2 < nk1 ? j.m1 : j.m2), j.in1, c1, j.in2, c2, k2 < nk1, k2, nk1,
                  b, by0, bx0, Hh, Ww, tid);
      }
      wstore(s_w, r, tid);
      __syncthreads();
    }
  }
  const int ox = bx0 + lx;
  const int jact = j.act;
  if (j.outmode == 1) {
    __syncthreads();
#pragma unroll
    for (int ct = 0; ct < 4; ++ct) {
      const int co0 = ct * 16 + slot * 4;
      const float b0 = j.bias[co0], b1 = j.bias[co0 + 1], b2 = j.bias[co0 + 2], b3 = j.bias[co0 + 3];
#pragma unroll
      for (int pg = 0; pg < NPG; ++pg) {
        const int px = (wv * NPG + pg) * 16 + lx;
        *(u32*)&s_mem[px * 72 + co0]     = pk2bf(act_rt(acc[ct][pg][0] + b0, jact),
                                                 act_rt(acc[ct][pg][1] + b1, jact));
        *(u32*)&s_mem[px * 72 + co0 + 2] = pk2bf(act_rt(acc[ct][pg][2] + b2, jact),
                                                 act_rt(acc[ct][pg][3] + b3, jact));
      }
    }
    __syncthreads();
#pragma unroll 1
    for (int l = tid; l < TH * 16 * 8; l += TPB) {
      const int px = l >> 3, ch = (l & 7) * 8;
      const int row = px >> 4, col = px & 15;
      const uint4 v = *(const uint4*)&s_mem[px * 72 + ch];
      *(uint4*)&j.outb[(((size_t)b * HW + (size_t)(by0 + row) * Ww + bx0 + col) << 6) + ch] = v;
    }
  } else if (j.outmode == 2) {
#pragma unroll
    for (int ct = 0; ct < 4; ++ct) {
      const int co0 = cb + ct * 16 + slot * 4;
#pragma unroll
      for (int r2 = 0; r2 < 4; ++r2) {
        const int co = co0 + r2;
        if (co < j.Cout) {
          const float bv = j.bias[co];
          u16* op = j.outb + ((size_t)b * j.Cout + co) * HW + (size_t)(by0 + wv * NPG) * Ww + ox;
#pragma unroll
          for (int pg = 0; pg < NPG; ++pg)
            op[pg * Ww] = f2bf(act_rt(acc[ct][pg][r2] + bv, jact));
        }
      }
    }
  } else {
#pragma unroll
    for (int ct = 0; ct < 4; ++ct) {
      const int co0 = cb + ct * 16 + slot * 4;
#pragma unroll
      for (int r2 = 0; r2 < 4; ++r2) {
        const int co = co0 + r2;
        if (co < j.Cout) {
          const float bv = j.bias[co];
          float* op = j.outf + ((size_t)b * j.Cout + co) * HW + (size_t)(by0 + wv * NPG) * Ww + ox;
#pragma unroll
          for (int pg = 0; pg < NPG; ++pg)
            op[pg * Ww] = act_rt(acc[ct][pg][r2] + bv, jact);
        }
      }
    }
  }
}

// ---------------------------------------------------------------------------
// Tri-level mega-pair, TH=8, weight-prefetch pipeline. All chlast-in.
// ---------------------------------------------------------------------------
struct PairJob {
  const u16* in1; const u16* in2; int c1, c2;
  const u16* w; const float* bias;
  u16* outb; int Cout, Coutpad, act, chlast, h;
};

__device__ __forceinline__ void stage_chlast(u16* s_act, const PairJob& j, int kc, int nk1,
                                             int b, int by0, int bx0, int Hh, int Ww, int tid)
{
  constexpr int NPOS = 180;
  const int HW = Hh * Ww;
  const u16* src; int cofs, cst;
  if (kc < nk1) { src = j.in1 + (size_t)b * HW * j.c1; cofs = kc << 5; cst = j.c1; }
  else          { src = j.in2 + (size_t)b * HW * j.c2; cofs = (kc - nk1) << 5; cst = j.c2; }
#pragma unroll 1
  for (int i = tid; i < NPOS * 4; i += TPB) {
    int u = i >> 2, q = i & 3;
    int y = u / 18, x = u - y * 18;
    int gy = by0 - 1 + y, gx = bx0 - 1 + x;
    uint4 v = make_uint4(0u, 0u, 0u, 0u);
    if ((unsigned)gy < (unsigned)Hh && (unsigned)gx < (unsigned)Ww)
      v = *(const uint4*)&src[(size_t)(gy * Ww + gx) * cst + cofs + q * 8];
    *(uint4*)&s_act[u * 40 + q * 8] = v;
  }
}

__global__ __launch_bounds__(TPB, 4)
void k_conv_tri(PairJob a0, PairJob b0, PairJob a1, PairJob b1, PairJob a2, PairJob b2)
{
  constexpr int TH = 8, NPOS = 180, NPG = 2;
  __shared__ __align__(16) u16 s_mem[NPOS * 40 + 3 * 64 * 40];
  u16* s_act = s_mem;
  u16* s_w   = s_mem + NPOS * 40;
  const int lvl = blockIdx.y / 5, sub = blockIdx.y % 5;
  const PairJob j = (lvl == 0) ? (sub == 0 ? a0 : b0)
                  : (lvl == 1) ? (sub == 0 ? a1 : b1)
                               : (sub == 0 ? a2 : b2);
  const int Hh = j.h, Ww = j.h;
  const int xt = Ww >> 4;
  const int nbx = (Hh >> 3) * xt;
  if ((int)blockIdx.x >= nbx) return;
  const int cb = (sub == 0) ? 0 : ((sub - 1) << 6);
  const int c1 = j.c1, c2 = j.c2;
  const int nkc = (c1 + c2) >> 5, nk1 = c1 >> 5;
  const int b   = blockIdx.z;
  const int by0 = (blockIdx.x / xt) * TH;
  const int bx0 = (blockIdx.x % xt) << 4;
  const int tid = threadIdx.x;
  const int lx = tid & 15, slot = (tid >> 4) & 3, wv = tid >> 6;
  const int HW = Hh * Ww;

  f32x4 acc[4][NPG];
#pragma unroll
  for (int i = 0; i < 4; ++i)
#pragma unroll
    for (int jj = 0; jj < NPG; ++jj) acc[i][jj] = (f32x4){0.f, 0.f, 0.f, 0.f};

  const size_t tapstride = (size_t)j.Coutpad * 40;
  const int P = nkc * 3;
  stage_chlast(s_act, j, 0, nk1, b, by0, bx0, Hh, Ww, tid);
  WReg r = wload(j.w, ((size_t)0 * j.Coutpad + cb) * 40, tapstride, tid);
  wstore(s_w, r, tid);
  __syncthreads();

#pragma unroll 1
  for (int p = 0; p < P; ++p) {
    const int kc = p / 3, ky = p - kc * 3;
    if (p + 1 < P) {
      const int kcn = (p + 1) / 3, kyn = (p + 1) - kcn * 3;
      r = wload(j.w, ((size_t)(kcn * 9 + kyn * 3) * j.Coutpad + cb) * 40, tapstride, tid);
    }
#pragma unroll
    for (int kx = 0; kx < 3; ++kx) {
      bf16x8 Af[4], Bf[NPG];
#pragma unroll
      for (int ct = 0; ct < 4; ++ct)
        Af[ct] = *(const bf16x8*)&s_w[(kx * 64 + ct * 16 + lx) * 40 + slot * 8];
#pragma unroll
      for (int pg = 0; pg < NPG; ++pg)
        Bf[pg] = *(const bf16x8*)&s_act[((wv * NPG + pg + ky) * 18 + lx + kx) * 40 + slot * 8];
#pragma unroll
      for (int ct = 0; ct < 4; ++ct)
#pragma unroll
        for (int pg = 0; pg < NPG; ++pg)
          acc[ct][pg] = __builtin_amdgcn_mfma_f32_16x16x32_bf16(Af[ct], Bf[pg], acc[ct][pg], 0, 0, 0);
    }
    __syncthreads();
    if (p + 1 < P) {
      if (ky == 2)
        stage_chlast(s_act, j, kc + 1, nk1, b, by0, bx0, Hh, Ww, tid);
      wstore(s_w, r, tid);
      __syncthreads();
    }
  }
  const int ox = bx0 + lx;
  const int jact = j.act;
  if (j.chlast) {
    __syncthreads();
#pragma unroll
    for (int ct = 0; ct < 4; ++ct) {
      const int co0 = ct * 16 + slot * 4;
      const float b0 = j.bias[co0], b1 = j.bias[co0 + 1], b2 = j.bias[co0 + 2], b3 = j.bias[co0 + 3];
#pragma unroll
      for (int pg = 0; pg < NPG; ++pg) {
        const int px = (wv * NPG + pg) * 16 + lx;
        float v0 = acc[ct][pg][0] + b0, v1 = acc[ct][pg][1] + b1;
        float v2 = acc[ct][pg][2] + b2, v3 = acc[ct][pg][3] + b3;
        if (jact) { v0 = v0 >= 0.f ? v0 : 0.1f * v0; v1 = v1 >= 0.f ? v1 : 0.1f * v1;
                    v2 = v2 >= 0.f ? v2 : 0.1f * v2; v3 = v3 >= 0.f ? v3 : 0.1f * v3; }
        *(u32*)&s_mem[px * 72 + co0]     = pk2bf(v0, v1);
        *(u32*)&s_mem[px * 72 + co0 + 2] = pk2bf(v2, v3);
      }
    }
    __syncthreads();
#pragma unroll 1
    for (int l = tid; l < TH * 16 * 8; l += TPB) {
      const int px = l >> 3, ch = (l & 7) * 8;
      const int row = px >> 4, col = px & 15;
      const uint4 v = *(const uint4*)&s_mem[px * 72 + ch];
      *(uint4*)&j.outb[(((size_t)b * HW + (size_t)(by0 + row) * Ww + bx0 + col) << 6) + ch] = v;
    }
  } else {
#pragma unroll
    for (int ct = 0; ct < 4; ++ct) {
      const int co0 = cb + ct * 16 + slot * 4;
#pragma unroll
      for (int r2 = 0; r2 < 4; ++r2) {
        const int co = co0 + r2;
        if (co < j.Cout) {
          const float bv = j.bias[co];
          u16* op = j.outb + ((size_t)b * j.Cout + co) * HW + (size_t)(by0 + wv * NPG) * Ww + ox;
#pragma unroll
          for (int pg = 0; pg < NPG; ++pg) {
            float v = acc[ct][pg][r2] + bv;
            if (jact) v = v >= 0.f ? v : 0.1f * v;
            op[pg * Ww] = f2bf(v);
          }
        }
      }
    }
  }
}

// ---------------------------------------------------------------------------
// Deformable conv (round-17 structure, unchanged)
// ---------------------------------------------------------------------------
struct DJob {
  const u16* xbf; const u16* off; const u16* mask;
  int maskC, maskBase;
  const float* wgt; const float* bias; float* out;
  int sigm, act;
};

__device__ __forceinline__ void dconv_core(const DJob& j, int gs, int Hh, int Ww,
                                           u16 (*s_x)[40], float* s_w, float* s_b)
{
  const int b   = blockIdx.z;
  const int xt  = Ww >> 4;
  const int ty0 = (blockIdx.x / xt) << 3;
  const int tx0 = (blockIdx.x % xt) << 4;
  const int tid = threadIdx.x;
  const int HW  = Hh * Ww;

  for (int i = tid; i < 2304; i += TPB) {
    int o = i & 7, c = (i >> 3) & 7, k = (i >> 6) % 9, gl = i / 576;
    s_w[i] = j.wgt[(((size_t)((gs * 4 + gl) * 8 + o)) * 8 + c) * 9 + k];
  }
  if (tid < 32) s_b[tid] = j.bias[gs * 32 + tid];
  {
    const u16* xb = j.xbf + (size_t)b * HW * 64 + gs * 32;
#pragma unroll 1
    for (int i = tid; i < 960; i += TPB) {
      int px = i >> 2, q = i & 3;
      int r = px / 20, cx = px - r * 20;
      int gy = ty0 - 2 + r, gx = tx0 - 2 + cx;
      uint4 v = make_uint4(0u, 0u, 0u, 0u);
      if ((unsigned)gy < (unsigned)Hh && (unsigned)gx < (unsigned)Ww)
        v = *(const uint4*)&xb[(size_t)(gy * Ww + gx) * 64 + q * 8];
      *(uint4*)&s_x[px][q * 8] = v;
    }
  }
  __syncthreads();

  const int pin = tid & 127;
  const int ghalf = tid >> 7;
  const int py_ = pin >> 4, px_ = pin & 15;
  const int gy = ty0 + py_, gx = tx0 + px_;
  const int p  = gy * Ww + gx;
  const int sigm = j.sigm, act = j.act;

#pragma unroll
  for (int jj = 0; jj < 2; ++jj) {
    const int gl = ghalf * 2 + jj;
    const int g  = gs * 4 + gl;
    const u16* ob = j.off  + ((size_t)b * 216 + g * 18) * HW + p;
    const u16* mb = j.mask + ((size_t)b * j.maskC + j.maskBase + g * 9) * HW + p;
    const u16* xg = j.xbf  + (size_t)b * HW * 64 + g * 8;
    float*     og = j.out  + ((size_t)b * 64 + g * 8) * HW + p;
    const float* wg = &s_w[gl * 9 * 64];

    float acc[8];
#pragma unroll
    for (int o = 0; o < 8; ++o) acc[o] = s_b[gl * 8 + o];

#pragma unroll
    for (int k = 0; k < 9; ++k) {
      const float oyk = bf2f(ob[(size_t)(2 * k) * HW]);
      const float oxk = bf2f(ob[(size_t)(2 * k + 1) * HW]);
      float m = bf2f(mb[(size_t)k * HW]);
      if (sigm) m = 1.f / (1.f + expf(-m));
      const float py = (float)(gy + k / 3 - 1) + oyk;
      const float px = (float)(gx + k % 3 - 1) + oxk;
      const float y0f = floorf(py), x0f = floorf(px);
      const float fy = py - y0f, fx = px - x0f;
      const int y0 = (int)y0f, x0 = (int)x0f;
      const int y1 = y0 + 1, x1 = x0 + 1;
      const float vy0 = (y0 >= 0 && y0 < Hh) ? 1.f : 0.f;
      const float vy1 = (y1 >= 0 && y1 < Hh) ? 1.f : 0.f;
      const float vx0 = (x0 >= 0 && x0 < Ww) ? 1.f : 0.f;
      const float vx1 = (x1 >= 0 && x1 < Ww) ? 1.f : 0.f;
      const float w00 = (1.f - fy) * (1.f - fx) * vy0 * vx0 * m;
      const float w01 = (1.f - fy) * fx * vy0 * vx1 * m;
      const float w10 = fy * (1.f - fx) * vy1 * vx0 * m;
      const float w11 = fy * fx * vy1 * vx1 * m;
      const float* wk = &wg[k * 64];
      const int ly = y0 - ty0 + 2, lxw = x0 - tx0 + 2;
      if ((unsigned)ly < 11u && (unsigned)lxw < 19u) {
        const u16* base = &s_x[ly * 20 + lxw][gl * 8];
        const bf16x8 c00 = *(const bf16x8*)base;
        const bf16x8 c01 = *(const bf16x8*)(base + 40);
        const bf16x8 c10 = *(const bf16x8*)(base + 800);
        const bf16x8 c11 = *(const bf16x8*)(base + 840);
#pragma unroll
        for (int c = 0; c < 8; ++c) {
          const float s = w00 * (float)c00[c] + w01 * (float)c01[c]
                        + w10 * (float)c10[c] + w11 * (float)c11[c];
          const float4 wv0 = *(const float4*)&wk[c * 8];
          const float4 wv1 = *(const float4*)&wk[c * 8 + 4];
          acc[0] = fmaf(s, wv0.x, acc[0]); acc[1] = fmaf(s, wv0.y, acc[1]);
          acc[2] = fmaf(s, wv0.z, acc[2]); acc[3] = fmaf(s, wv0.w, acc[3]);
          acc[4] = fmaf(s, wv1.x, acc[4]); acc[5] = fmaf(s, wv1.y, acc[5]);
          acc[6] = fmaf(s, wv1.z, acc[6]); acc[7] = fmaf(s, wv1.w, acc[7]);
        }
      } else {
        const int cy0 = min(max(y0, 0), Hh - 1), cy1 = min(max(y1, 0), Hh - 1);
        const int cx0 = min(max(x0, 0), Ww - 1), cx1 = min(max(x1, 0), Ww - 1);
        const int i00 = (cy0 * Ww + cx0) * 64, i01 = (cy0 * Ww + cx1) * 64;
        const int i10 = (cy1 * Ww + cx0) * 64, i11 = (cy1 * Ww + cx1) * 64;
#pragma unroll
        for (int c = 0; c < 8; ++c) {
          const float s = w00 * bf2f(xg[i00 + c]) + w01 * bf2f(xg[i01 + c])
                        + w10 * bf2f(xg[i10 + c]) + w11 * bf2f(xg[i11 + c]);
          const float4 wv0 = *(const float4*)&wk[c * 8];
          const float4 wv1 = *(const float4*)&wk[c * 8 + 4];
          acc[0] = fmaf(s, wv0.x, acc[0]); acc[1] = fmaf(s, wv0.y, acc[1]);
          acc[2] = fmaf(s, wv0.z, acc[2]); acc[3] = fmaf(s, wv0.w, acc[3]);
          acc[4] = fmaf(s, wv1.x, acc[4]); acc[5] = fmaf(s, wv1.y, acc[5]);
          acc[6] = fmaf(s, wv1.z, acc[6]); acc[7] = fmaf(s, wv1.w, acc[7]);
        }
      }
    }
#pragma unroll
    for (int o = 0; o < 8; ++o) {
      float v = acc[o];
      if (act) v = v >= 0.f ? v : 0.1f * v;
      og[(size_t)o * HW] = v;
    }
  }
}

__global__ __launch_bounds__(TPB, 4)
void k_dconv_one(DJob j, int Hh, int Ww)
{
  __shared__ __align__(16) u16 s_x[240][40];
  __shared__ __align__(16) float s_w[4 * 9 * 64];
  __shared__ float s_b[32];
  dconv_core(j, blockIdx.y, Hh, Ww, s_x, s_w, s_b);
}

__global__ __launch_bounds__(TPB, 4)
void k_dconv_dual(DJob a, DJob b, int Hh, int Ww)
{
  __shared__ __align__(16) u16 s_x[240][40];
  __shared__ __align__(16) float s_w[4 * 9 * 64];
  __shared__ float s_b[32];
  const DJob& j = (blockIdx.y & 1) ? b : a;
  dconv_core(j, blockIdx.y >> 1, Hh, Ww, s_x, s_w, s_b);
}

// ---------------------------------------------------------------------------
// host helpers
// ---------------------------------------------------------------------------
static void conv3(hipStream_t st, int variant,
                  const void* in1, int c1, const void* in2, int c2,
                  const u16* wbuf, const float* bias, float* outf, u16* outb,
                  int Cout, int h, int wd)
{
  int cocols = (Cout + 63) / 64, Coutpad = cocols * 64;
  bool th8 = (h >= 96);
  int TH = th8 ? 8 : 16;
  dim3 grid((h / TH) * (wd / 16), cocols, 2);
  if (th8) {
    switch (variant) {
      case 0: k_conv<1,1,1,1,8><<<grid, TPB, 0, st>>>(in1, c1, in2, c2, wbuf, bias, outf, outb, Cout, Coutpad, h, wd); break;
      case 3: k_conv<0,1,1,2,8><<<grid, TPB, 0, st>>>(in1, c1, in2, c2, wbuf, bias, outf, outb, Cout, Coutpad, h, wd); break;
      case 4: k_conv<2,1,1,2,8><<<grid, TPB, 0, st>>>(in1, c1, in2, c2, wbuf, bias, outf, outb, Cout, Coutpad, h, wd); break;
      case 6: k_conv<0,0,4,1,8><<<grid, TPB, 0, st>>>(in1, c1, in2, c2, wbuf, bias, outf, outb, Cout, Coutpad, h, wd); break;
      default: k_conv<1,0,4,0,8><<<grid, TPB, 0, st>>>(in1, c1, in2, c2, wbuf, bias, outf, outb, Cout, Coutpad, h, wd); break;
    }
  } else {
    switch (variant) {
      case 0: k_conv<1,1,1,1,16><<<grid, TPB, 0, st>>>(in1, c1, in2, c2, wbuf, bias, outf, outb, Cout, Coutpad, h, wd); break;
      case 3: k_conv<0,1,1,2,16><<<grid, TPB, 0, st>>>(in1, c1, in2, c2, wbuf, bias, outf, outb, Cout, Coutpad, h, wd); break;
      case 4: k_conv<2,1,1,2,16><<<grid, TPB, 0, st>>>(in1, c1, in2, c2, wbuf, bias, outf, outb, Cout, Coutpad, h, wd); break;
      case 6: k_conv<0,0,4,1,16><<<grid, TPB, 0, st>>>(in1, c1, in2, c2, wbuf, bias, outf, outb, Cout, Coutpad, h, wd); break;
      default: k_conv<1,0,4,0,16><<<grid, TPB, 0, st>>>(in1, c1, in2, c2, wbuf, bias, outf, outb, Cout, Coutpad, h, wd); break;
    }
  }
}

static CJob mkcjob(const void* i1, const void* i2, int c1, int c2, int m1, int m2,
                   const u16* w, const float* bias, float* outf, u16* outb,
                   int outmode, int act, int Cout, int h)
{
  CJob j; j.in1 = i1; j.in2 = i2; j.c1 = c1; j.c2 = c2; j.m1 = m1; j.m2 = m2;
  j.w = w; j.bias = bias; j.outf = outf; j.outb = outb; j.outmode = outmode;
  j.act = act; j.Cout = Cout; j.Coutpad = ((Cout + 63) / 64) * 64; j.h = h;
  return j;
}

static void jobs_launch(hipStream_t st, CJob a, CJob b)
{
  int ny0 = a.Coutpad / 64, ny1 = b.Coutpad / 64;
  int nbx0 = (a.h / 8) * (a.h / 16), nbx1 = (b.h / 8) * (b.h / 16);
  dim3 grid(max(nbx0, nbx1), ny0 + ny1, 2);
  k_conv_jobs<<<grid, TPB, 0, st>>>(a, b, ny0);
}

static PairJob mkpair(const u16* i1, const u16* i2, int c1, int c2, const u16* w,
                      const float* bias, u16* outb, int Cout, int Cpad,
                      int act, int chlast, int h)
{
  PairJob p; p.in1 = i1; p.in2 = i2; p.c1 = c1; p.c2 = c2; p.w = w; p.bias = bias;
  p.outb = outb; p.Cout = Cout; p.Coutpad = Cpad; p.act = act; p.chlast = chlast; p.h = h;
  return p;
}

static DJob mkdjob(const u16* xbf, const u16* off, const u16* mask, int maskC, int maskBase,
                   const float* w, const float* b, float* out, int sigm, int act)
{
  DJob j; j.xbf = xbf; j.off = off; j.mask = mask; j.maskC = maskC; j.maskBase = maskBase;
  j.wgt = w; j.bias = b; j.out = out; j.sigm = sigm; j.act = act;
  return j;
}

static void dconv_dual(hipStream_t st, DJob a, DJob b, int h, int wd)
{
  dim3 grid((h / 8) * (wd / 16), 4, 2);
  k_dconv_dual<<<grid, TPB, 0, st>>>(a, b, h, wd);
}

static void dconv_one(hipStream_t st, DJob a, int h, int wd)
{
  dim3 grid((h / 8) * (wd / 16), 2, 2);
  k_dconv_one<<<grid, TPB, 0, st>>>(a, h, wd);
}

extern "C" void kernel_launch(void* const* d_in, const int* in_sizes, int n_in,
                              void* d_out, int out_size, void* d_ws, size_t ws_size,
                              hipStream_t stream)
{
  const float* const* in = (const float* const*)d_in;

  const int HW0 = 192 * 192, HW1 = 96 * 96, HW2 = 48 * 48;
  const size_t N0 = (size_t)2 * HW0 * 64, N1 = (size_t)2 * HW1 * 64, N2 = (size_t)2 * HW2 * 64;

  // ---- workspace layout ----
  u16* p = (u16*)d_ws;
  u16* nrf0b = p; p += N0;
  u16* rf0b  = p; p += N0;
  u16* swf0b = p; p += N0;
  u16* nrf1b = p; p += N1;
  u16* rf1b  = p; p += N1;
  u16* swf1b = p; p += N1;
  u16* nrf2b = p; p += N2;
  u16* rf2b  = p; p += N2;
  u16* swf2b = p; p += N2;
  u16* A0bf  = p; p += N0;
  u16* A1bf  = p; p += N1;
  u16* A2bf  = p; p += N2;
  u16* OM0   = p; p += (size_t)2 * 216 * HW0;
  u16* OM1   = p; p += (size_t)2 * 216 * HW1;
  u16* OM2   = p; p += (size_t)2 * 216 * HW2;
  u16* EM    = p; p += (size_t)2 * 72 * HW0;
  u16* OF0bf = p; p += N0;
  u16* DN0bf = p; p += N0;
  p = (u16*)(((uintptr_t)p + 15) & ~(uintptr_t)15);
  float* XD   = (float*)p;
  float* DN1  = XD + (size_t)2 * 64 * HW0;
  u16* wp = (u16*)(DN1 + (size_t)2 * 64 * HW1);

  float* dout = (float*)d_out;
  const size_t L0 = (size_t)2 * 64 * HW0;
  float* out0 = dout;
  float* sh0  = dout + L0;
  float* sh1  = sh0  + L0;
  float* sh2  = sh1  + L0 / 4;
  // d_out dead-region aliases:
  u16*   Bbf   = (u16*)out0;                                 // overwritten by final dconv
  u16*   OF1bf = (u16*)sh0;                                  // dead before dual0 writes sh0
  u16*   OF2bf = OF1bf + N1;
  float* DN2   = (float*)(OF2bf + N2);

  // ---- input conversion ----
  {
    ToBfArgs ta;
    const float* srcs[9] = {in[0], in[1], in[2], in[3], in[4], in[5], in[6], in[7], in[8]};
    u16* dsts[9] = {nrf0b, rf0b, swf0b, nrf1b, rf1b, swf1b, nrf2b, rf2b, swf2b};
    const int hws[9] = {HW0, HW0, HW0, HW1, HW1, HW1, HW2, HW2, HW2};
    for (int i = 0; i < 9; ++i) { ta.src[i] = srcs[i]; ta.dst[i] = dsts[i]; ta.hw[i] = hws[i]; }
    int maxtot = 2 * HW0 * 8;
    k_tobf_all<<<dim3((maxtot + TPB - 1) / TPB, 9), TPB, 0, stream>>>(ta);
  }

  // ---- weight prep ----
  struct { int arg, cin, cout; } plist[22] = {
    {9,128,64},{11,64,64},{13,64,216},{15,128,64},{17,64,72},
    {21,128,64},{23,64,64},{25,64,216},{27,128,64},{29,64,72},
    {33,128,64},{35,64,64},{37,64,216},{39,128,64},{41,64,72},
    {45,128,64},{47,128,64},{49,128,64},{51,128,64},
    {53,128,64},{55,64,64},{57,64,216}};
  WPrepArgs wa;
  u16* wptr[22];
  int maxtot = 0;
  for (int i = 0; i < 22; ++i) {
    int cin = plist[i].cin, cout = plist[i].cout;
    int cpad = ((cout + 63) / 64) * 64;
    int tot = (cin / 32) * 9 * cpad * 40;
    wa.src[i] = in[plist[i].arg]; wa.dst[i] = wp;
    wa.cin[i] = cin; wa.cout[i] = cout; wa.coutpad[i] = cpad; wa.total[i] = tot;
    wptr[i] = wp; wp += tot;
    if (tot > maxtot) maxtot = tot;
  }
  k_wprep_all<<<dim3((maxtot + TPB - 1) / TPB, 22), TPB, 0, stream>>>(wa);

  u16* w_ocf0 = wptr[0];  u16* w_ocl0 = wptr[1];  u16* w_com0 = wptr[2];
  u16* w_em10 = wptr[3];  u16* w_em20 = wptr[4];
  u16* w_ocf1 = wptr[5];  u16* w_ocl1 = wptr[6];  u16* w_com1 = wptr[7];
  u16* w_em11 = wptr[8];  u16* w_em21 = wptr[9];
  u16* w_ocf2 = wptr[10]; u16* w_ocl2 = wptr[11]; u16* w_com2 = wptr[12];
  u16* w_em12 = wptr[13]; u16* w_em22 = wptr[14];
  u16* w_occ0 = wptr[15]; u16* w_fcc0 = wptr[16];
  u16* w_occ1 = wptr[17]; u16* w_fcc1 = wptr[18];
  u16* w_cas1 = wptr[19]; u16* w_cas2 = wptr[20]; u16* w_casc = wptr[21];

  const int h2 = 48, h1 = 96, h0 = 192;

  // ---- tri-level mega-pair (TH=8): all ocf_i + com_i ----
  {
    PairJob a0 = mkpair(nrf0b, rf0b, 64, 64, w_ocf0, in[10], A0bf, 64, 64, 1, 1, h0);
    PairJob b0 = mkpair(swf0b, nullptr, 64, 0, w_com0, in[14], OM0, 216, 256, 0, 0, h0);
    PairJob a1 = mkpair(nrf1b, rf1b, 64, 64, w_ocf1, in[22], A1bf, 64, 64, 1, 1, h1);
    PairJob b1 = mkpair(swf1b, nullptr, 64, 0, w_com1, in[26], OM1, 216, 256, 0, 0, h1);
    PairJob a2 = mkpair(nrf2b, rf2b, 64, 64, w_ocf2, in[34], A2bf, 64, 64, 1, 1, h2);
    PairJob b2 = mkpair(swf2b, nullptr, 64, 0, w_com2, in[38], OM2, 216, 256, 0, 0, h2);
    dim3 grid(288, 15, 2);
    k_conv_tri<<<grid, TPB, 0, stream>>>(a0, b0, a1, b1, a2, b2);
  }

  // ocl2 (48²)
  conv3(stream, 0, A2bf, 64, nullptr, 0, w_ocl2, in[36], nullptr, OF2bf, 64, h2, h2);
  // p1: em12(48) + occ1(96, fused chlast up2)
  jobs_launch(stream,
    mkcjob(OF2bf, swf2b, 64, 64, 1, 1, w_em12, in[40], nullptr, A2bf, 1, 1, 64, h2),
    mkcjob(A1bf,  OF2bf, 64, 64, 1, 3, w_occ1, in[50], nullptr, Bbf,  1, 1, 64, h1));
  // p2: em22(48, sigmoid->EM planar) + ocl1(96)
  jobs_launch(stream,
    mkcjob(A2bf, nullptr, 64, 0, 1, 1, w_em22, in[42], nullptr, EM,    2, 2, 72, h2),
    mkcjob(Bbf,  nullptr, 64, 0, 1, 1, w_ocl1, in[24], nullptr, OF1bf, 1, 1, 64, h1));
  // dual2: sh2 + xd2
  dconv_dual(stream,
             mkdjob(OF2bf, OM2, EM,  72, 0,   in[43], in[44], sh2, 0, 0),
             mkdjob(nrf2b, OM2, OM2, 216, 144, in[43], in[44], DN2, 1, 1), h2, h2);
  // p3: em11(96) + occ0(192, fused chlast up2)
  jobs_launch(stream,
    mkcjob(OF1bf, swf1b, 64, 64, 1, 1, w_em11, in[28], nullptr, A1bf, 1, 1, 64, h1),
    mkcjob(A0bf,  OF1bf, 64, 64, 1, 3, w_occ0, in[46], nullptr, Bbf,  1, 1, 64, h0));
  // p4: em21(96, sigmoid->EM) + ocl0(192)
  jobs_launch(stream,
    mkcjob(A1bf, nullptr, 64, 0, 1, 1, w_em21, in[30], nullptr, EM,    2, 2, 72, h1),
    mkcjob(Bbf,  nullptr, 64, 0, 1, 1, w_ocl0, in[12], nullptr, OF0bf, 1, 1, 64, h0));
  // dual1: sh1 + xd1
  dconv_dual(stream,
             mkdjob(OF1bf, OM1, EM,  72, 0,   in[31], in[32], sh1, 0, 0),
             mkdjob(nrf1b, OM1, OM1, 216, 144, in[31], in[32], XD, 1, 0), h1, h1);
  // p5: em10(192) + fcc1(96, fp32 + fp32-up2 -> fp32)
  jobs_launch(stream,
    mkcjob(OF0bf, swf0b, 64, 64, 1, 1, w_em10, in[16], nullptr, Bbf, 1, 1, 64, h0),
    mkcjob(XD,    DN2,   64, 64, 0, 4, w_fcc1, in[52], DN1, nullptr, 0, 1, 64, h1));
  // em20 (192, sigmoid->EM)
  conv3(stream, 4, Bbf, 64, nullptr, 0, w_em20, in[18], nullptr, EM, 72, h0, h0);
  // dual0: sh0 + xd0
  dconv_dual(stream,
             mkdjob(OF0bf, OM0, EM,  72, 0,   in[19], in[20], sh0, 0, 0),
             mkdjob(nrf0b, OM0, OM0, 216, 144, in[19], in[20], XD, 1, 0), h0, h0);
  // fcc0 (fp32 + fp32-up2 -> chlast)
  conv3(stream, 6, XD, 64, DN1, 64, w_fcc0, in[48], nullptr, DN0bf, 64, h0, h0);
  // cascade
  conv3(stream, 0, DN0bf, 64, rf0b, 64,  w_cas1, in[54], nullptr, A0bf, 64, h0, h0);
  conv3(stream, 0, A0bf,  64, nullptr,0, w_cas2, in[56], nullptr, Bbf,  64, h0, h0);
  conv3(stream, 3, Bbf,   64, nullptr,0, w_casc, in[58], nullptr, OM0, 216, h0, h0);
  dconv_one(stream,
            mkdjob(DN0bf, OM0, OM0, 216, 144, in[59], in[60], out0, 1, 1), h0, h0);
}